// Round 1
// baseline (4359.259 us; speedup 1.0000x reference)
//
#include <hip/hip_runtime.h>
#include <hip/hip_bf16.h>

#define DEV __device__ __forceinline__

constexpr int Mn  = 30000;   // nodes (B=1)
constexpr int Tt  = 12;
constexpr int CIN = 16;
constexpr int Hh  = 64;
constexpr int Gg  = 192;     // 3H
constexpr int C2  = 128;     // 2H
constexpr int Ee  = 960000;  // edges per timestep (bidirectional)
constexpr int HC  = 128;
constexpr int Oo  = 12;
constexpr int KW  = 128;
constexpr int HP  = 72;      // padded h row stride (floats)
constexpr int WP  = 194;     // padded weight row stride (bf16): bank stride 97 (odd) -> conflict-free
constexpr int XSP = 36;      // padded xs inner stride (floats): 16B-aligned, 2-way max
constexpr int NB  = 235;     // 128-row buckets per t (235*128 >= 30000)
constexpr int EPB = 8192;    // edges per block for bcnt/part2
constexpr int BPT = 118;     // ceil(Ee/EPB)
constexpr int CHK = 21;      // chunks per t for power iteration (252 blocks total)
constexpr int RC  = 1429;    // rows per chunk (21*1429 >= 30000)
constexpr int NRND= 76;      // 75 power rounds + 1 Rayleigh round

DEV float bf2f(__hip_bfloat16 v){ return __bfloat162float(v); }
DEV __hip_bfloat16 f2bf(float v){ return __float2bfloat16(v); }
DEV float sigm(float x){ return __builtin_amdgcn_rcpf(1.f + __expf(-x)); }
DEV float tanh_f(float x){ return 1.f - 2.f*__builtin_amdgcn_rcpf(__expf(2.f*x) + 1.f); }

typedef short bfrag8 __attribute__((ext_vector_type(8)));
typedef float ffrag4 __attribute__((ext_vector_type(4)));

// ---------------------------------------------------------------- init
__global__ void k_init(float* nrm2, float* dotb, float* u0, int* bcnt, int* bfill, int* bar){
  int i = blockIdx.x*256 + threadIdx.x;
  if (i < Tt*Mn) u0[i] = 0.005773502691896258f;    // 1/sqrt(30000)
  if (i < 76*Tt) nrm2[i] = (i < Tt) ? 1.0f : 0.0f;
  if (i < Tt){ dotb[i] = 0.f; bar[i] = 0; }
  if (i < Tt*NB){ bcnt[i] = 0; bfill[i] = 0; }
}

// ---------------------------------------------------------------- stage 1: block-aggregated bucket histogram
__global__ __launch_bounds__(256) void k_bcnt(const int* __restrict__ ei, int* __restrict__ bcnt){
  __shared__ int h[NB];
  const int b = blockIdx.x;                 // 1416 = 8*177
  const int w = (b & 7)*177 + (b >> 3);
  const int t = w / BPT, ch = w - t*BPT;
  const int e0 = ch*EPB;
  const int tid = threadIdx.x;
  for (int i = tid; i < NB; i += 256) h[i] = 0;
  __syncthreads();
  #pragma unroll
  for (int i = 0; i < 32; ++i){
    int e = e0 + i*256 + tid;
    if (e < Ee){
      int r = ei[(size_t)(t*2)*Ee + e];
      atomicAdd(&h[r >> 7], 1);
    }
  }
  __syncthreads();
  for (int i = tid; i < NB; i += 256){
    int c = h[i];
    if (c > 0) atomicAdd(&bcnt[t*NB + i], c);
  }
}

// ---------------------------------------------------------------- stage 2: per-t exclusive scan of bucket counts
__global__ __launch_bounds__(256) void k_bscan(const int* __restrict__ bcnt, int* __restrict__ rpb){
  int t = blockIdx.x, tid = threadIdx.x;
  __shared__ int ps[256];
  int v = (tid < NB) ? bcnt[t*NB + tid] : 0;
  ps[tid] = v;
  __syncthreads();
  for (int o = 1; o < 256; o <<= 1){
    int x = (tid >= o) ? ps[tid-o] : 0;
    __syncthreads();
    ps[tid] += x;
    __syncthreads();
  }
  if (tid < NB) rpb[t*(NB+1) + tid] = ps[tid] - v;
  if (tid == 255) rpb[t*(NB+1) + NB] = ps[NB-1];
}

// ---------------------------------------------------------------- stage 3: partition edges into buckets (block-aggregated reservations)
__global__ __launch_bounds__(256) void k_part2(const int* __restrict__ ei, const int* __restrict__ rpb,
    int* __restrict__ bfill, unsigned* __restrict__ pair){
  __shared__ int hcnt[NB];
  __shared__ int hbase[NB];
  const int b = blockIdx.x;                 // 1416 = 8*177
  const int w = (b & 7)*177 + (b >> 3);
  const int t = w / BPT, ch = w - t*BPT;
  const int e0 = ch*EPB;
  const int tid = threadIdx.x;
  for (int i = tid; i < NB; i += 256) hcnt[i] = 0;
  __syncthreads();
  unsigned key[32];
  #pragma unroll
  for (int i = 0; i < 32; ++i){
    int e = e0 + i*256 + tid;
    unsigned k = 0xFFFFFFFFu;
    if (e < Ee){
      int r = ei[(size_t)(t*2)*Ee + e];
      int c = ei[(size_t)(t*2+1)*Ee + e];
      k = ((unsigned)r << 16) | (unsigned)c;
      atomicAdd(&hcnt[r >> 7], 1);
    }
    key[i] = k;
  }
  __syncthreads();
  for (int i = tid; i < NB; i += 256){
    int cnt = hcnt[i];
    int base = (cnt > 0) ? atomicAdd(&bfill[t*NB + i], cnt) : 0;
    hbase[i] = rpb[t*(NB+1) + i] + base;
  }
  __syncthreads();
  for (int i = tid; i < NB; i += 256) hcnt[i] = 0;
  __syncthreads();
  #pragma unroll
  for (int i = 0; i < 32; ++i){
    unsigned k = key[i];
    if (k != 0xFFFFFFFFu){
      int r = (int)(k >> 16);
      int bk = r >> 7;
      int pos = atomicAdd(&hcnt[bk], 1);
      pair[(size_t)t*Ee + hbase[bk] + pos] = ((unsigned)(r & 127) << 16) | (k & 0xFFFFu);
    }
  }
}

// ---------------------------------------------------------------- stage 4: per-bucket LDS counting sort -> col16, rp, deg
__global__ __launch_bounds__(256) void k_csr2(const int* __restrict__ rpb, const unsigned* __restrict__ pair,
    unsigned short* __restrict__ col16, int* __restrict__ rp, int* __restrict__ deg){
  __shared__ unsigned short cols_s[9216];
  __shared__ int lcnt[128], lfill[128];
  __shared__ int ps[256];
  const int blk = blockIdx.x;               // Tt*NB
  const int t = blk / NB, bk = blk - t*NB;
  const int r0 = bk << 7;
  const int nr = (r0 + 128 <= Mn) ? 128 : (Mn - r0);
  const int base = rpb[t*(NB+1) + bk];
  const int cnt  = rpb[t*(NB+1) + bk + 1] - base;
  const int tid = threadIdx.x;
  if (tid < 128) lcnt[tid] = 0;
  __syncthreads();
  for (int i = tid; i < cnt; i += 256){
    unsigned v = pair[(size_t)t*Ee + base + i];
    atomicAdd(&lcnt[v >> 16], 1);
  }
  __syncthreads();
  int v2 = (tid < 128) ? lcnt[tid] : 0;
  ps[tid] = v2;
  __syncthreads();
  for (int o = 1; o < 128; o <<= 1){
    int x = (tid >= o) ? ps[tid-o] : 0;
    __syncthreads();
    ps[tid] += x;
    __syncthreads();
  }
  if (tid < 128){
    int excl = ps[tid] - v2;
    lfill[tid] = excl;
    if (tid < nr){
      rp[t*(Mn+1) + r0 + tid] = base + excl;
      deg[t*Mn + r0 + tid] = v2;
    }
  }
  if (bk == NB-1 && tid == 0) rp[t*(Mn+1) + Mn] = base + cnt;
  __syncthreads();
  for (int i = tid; i < cnt; i += 256){
    unsigned v = pair[(size_t)t*Ee + base + i];
    int pos = atomicAdd(&lfill[v >> 16], 1);
    cols_s[pos] = (unsigned short)(v & 0xFFFFu);
  }
  __syncthreads();
  for (int i = tid; i < cnt; i += 256)
    col16[(size_t)t*Ee + base + i] = cols_s[i];
}

// ---------------------------------------------------------------- dinv
__global__ void k_dinv(const int* __restrict__ deg, float* __restrict__ dinv){
  int i = blockIdx.x*256 + threadIdx.x;
  if (i < Tt*Mn){ int d = deg[i]; dinv[i] = (d > 0) ? rsqrtf((float)d) : 0.f; }
}

// ---------------------------------------------------------------- GRU layer 0 (both dirs), writes y0 (T,M,128) bf16
__global__ __launch_bounds__(256) void k_gru0(
    const float* __restrict__ nf, const float* __restrict__ Wih, const float* __restrict__ Whh,
    const float* __restrict__ bih, const float* __restrict__ bhh, __hip_bfloat16* __restrict__ y0)
{
  __shared__ float xs[Tt][CIN][XSP];
  __shared__ __hip_bfloat16 wi[CIN][WP];
  __shared__ __hip_bfloat16 wh[Hh][WP];
  __shared__ float hb[32][HP];
  __shared__ float bi[Gg], bh[Gg];
  const int tid = threadIdx.x;
  const int m0  = blockIdx.x*32;
  for (int idx = tid; idx < Tt*32*CIN; idx += 256){
    int t = idx / (32*CIN); int rr = (idx / CIN) & 31; int k = idx & (CIN-1);
    int m = m0 + rr;
    xs[t][k][rr] = (m < Mn) ? nf[((size_t)t*Mn + m)*CIN + k] : 0.f;
  }
  const int jg = tid & 31, rg = tid >> 5;
  const int j0 = jg*2, rg4 = rg*4;
  for (int d = 0; d < 2; ++d){
    __syncthreads();
    for (int idx = tid; idx < Gg*CIN; idx += 256){
      int g = idx / CIN, k = idx & (CIN-1);
      wi[k][g] = f2bf(Wih[((size_t)d*Gg + g)*CIN + k]);
    }
    for (int idx = tid; idx < Gg*Hh; idx += 256){
      int g = idx >> 6, k = idx & 63;
      wh[k][g] = f2bf(Whh[((size_t)d*Gg + g)*Hh + k]);
    }
    if (tid < Gg){ bi[tid] = bih[d*Gg + tid]; bh[tid] = bhh[d*Gg + tid]; }
    for (int idx = tid; idx < 32*HP; idx += 256) ((float*)hb)[idx] = 0.f;
    __syncthreads();
    for (int step = 0; step < Tt; ++step){
      int t = d ? (Tt-1-step) : step;
      float ar[4][2], az[4][2], ai[4][2], ah[4][2];
      #pragma unroll
      for (int i = 0; i < 4; ++i){
        #pragma unroll
        for (int jj = 0; jj < 2; ++jj){
          int j = j0 + jj;
          ar[i][jj] = bi[j] + bh[j];
          az[i][jj] = bi[Hh+j] + bh[Hh+j];
          ai[i][jj] = bi[2*Hh+j];
          ah[i][jj] = bh[2*Hh+j];
        }
      }
      #pragma unroll
      for (int k = 0; k < CIN; ++k){
        float4 xv4 = *(const float4*)&xs[t][k][rg4];
        float xv[4] = {xv4.x, xv4.y, xv4.z, xv4.w};
        __hip_bfloat162 pr = *(const __hip_bfloat162*)&wi[k][j0];
        __hip_bfloat162 pz = *(const __hip_bfloat162*)&wi[k][Hh+j0];
        __hip_bfloat162 pn = *(const __hip_bfloat162*)&wi[k][2*Hh+j0];
        float wr[2] = {bf2f(pr.x), bf2f(pr.y)};
        float wz[2] = {bf2f(pz.x), bf2f(pz.y)};
        float wn[2] = {bf2f(pn.x), bf2f(pn.y)};
        #pragma unroll
        for (int i = 0; i < 4; ++i){
          #pragma unroll
          for (int jj = 0; jj < 2; ++jj){
            ar[i][jj] += xv[i]*wr[jj];
            az[i][jj] += xv[i]*wz[jj];
            ai[i][jj] += xv[i]*wn[jj];
          }
        }
      }
      #pragma unroll 4
      for (int k4 = 0; k4 < 16; ++k4){
        float4 h0 = *(const float4*)&hb[rg4+0][k4*4];
        float4 h1 = *(const float4*)&hb[rg4+1][k4*4];
        float4 h2 = *(const float4*)&hb[rg4+2][k4*4];
        float4 h3 = *(const float4*)&hb[rg4+3][k4*4];
        #pragma unroll
        for (int kk = 0; kk < 4; ++kk){
          int k = k4*4 + kk;
          float hv[4] = { ((const float*)&h0)[kk], ((const float*)&h1)[kk],
                          ((const float*)&h2)[kk], ((const float*)&h3)[kk] };
          __hip_bfloat162 pr = *(const __hip_bfloat162*)&wh[k][j0];
          __hip_bfloat162 pz = *(const __hip_bfloat162*)&wh[k][Hh+j0];
          __hip_bfloat162 pn = *(const __hip_bfloat162*)&wh[k][2*Hh+j0];
          float wr[2] = {bf2f(pr.x), bf2f(pr.y)};
          float wz[2] = {bf2f(pz.x), bf2f(pz.y)};
          float wn[2] = {bf2f(pn.x), bf2f(pn.y)};
          #pragma unroll
          for (int i = 0; i < 4; ++i){
            #pragma unroll
            for (int jj = 0; jj < 2; ++jj){
              ar[i][jj] += hv[i]*wr[jj];
              az[i][jj] += hv[i]*wz[jj];
              ah[i][jj] += hv[i]*wn[jj];
            }
          }
        }
      }
      __syncthreads();
      #pragma unroll
      for (int i = 0; i < 4; ++i){
        int r = rg4 + i; int m = m0 + r;
        float hn2[2];
        #pragma unroll
        for (int jj = 0; jj < 2; ++jj){
          float rr = sigm(ar[i][jj]);
          float zz = sigm(az[i][jj]);
          float nn = tanh_f(ai[i][jj] + rr*ah[i][jj]);
          float hv = hb[r][j0+jj];
          hn2[jj] = (1.f-zz)*nn + zz*hv;
          hb[r][j0+jj] = hn2[jj];
        }
        if (m < Mn){
          __hip_bfloat162 pk; pk.x = f2bf(hn2[0]); pk.y = f2bf(hn2[1]);
          *(__hip_bfloat162*)&y0[((size_t)t*Mn + m)*C2 + d*Hh + j0] = pk;
        }
      }
      __syncthreads();
    }
  }
}

// ---------------------------------------------------------------- convert layer-1 reverse weights to bf16
__global__ void k_wcvt(const float* __restrict__ W, __hip_bfloat16* __restrict__ Wbf){
  int i = blockIdx.x*256 + threadIdx.x;
  if (i < Gg*C2) Wbf[i] = f2bf(W[i]);
}

// ---------------------------------------------------------------- layer-1 input projection via MFMA
__global__ __launch_bounds__(256) void k_gi1m(const __hip_bfloat16* __restrict__ y0,
    const __hip_bfloat16* __restrict__ Wbf, const float* __restrict__ bih, __hip_bfloat16* __restrict__ gi)
{
  const int wid  = (blockIdx.x*256 + threadIdx.x) >> 6;
  const int lane = threadIdx.x & 63;
  const int SEGS = (Mn + 31)/32;
  if (wid >= Tt*SEGS) return;
  const int t = wid / SEGS, seg = wid - t*SEGS;
  const int m0 = seg*32;
  const int lr = lane & 15, lq = lane >> 4;
  const __hip_bfloat16* yb = y0 + (size_t)t*Mn*C2;

  ffrag4 acc[2][12];
  #pragma unroll
  for (int i = 0; i < 2; ++i){
    #pragma unroll
    for (int n = 0; n < 12; ++n) acc[i][n] = (ffrag4){0.f,0.f,0.f,0.f};
  }
  #pragma unroll
  for (int ks = 0; ks < 4; ++ks){
    const int ko = ks*32 + lq*8;
    bfrag8 a0 = *(const bfrag8*)(yb + (size_t)(m0 + lr     )*C2 + ko);
    bfrag8 a1 = *(const bfrag8*)(yb + (size_t)(m0 + 16 + lr)*C2 + ko);
    #pragma unroll
    for (int nt = 0; nt < 12; ++nt){
      bfrag8 b = *(const bfrag8*)(Wbf + (size_t)(nt*16 + lr)*C2 + ko);
      acc[0][nt] = __builtin_amdgcn_mfma_f32_16x16x32_bf16(a0, b, acc[0][nt], 0, 0, 0);
      acc[1][nt] = __builtin_amdgcn_mfma_f32_16x16x32_bf16(a1, b, acc[1][nt], 0, 0, 0);
    }
  }
  #pragma unroll
  for (int nt = 0; nt < 12; ++nt){
    int g = nt*16 + lr;
    float bb = bih[g];
    #pragma unroll
    for (int r = 0; r < 4; ++r){
      int mm0 = m0 + lq*4 + r;
      int mm1 = mm0 + 16;
      if (mm0 < Mn) gi[((size_t)t*Mn + mm0)*Gg + g] = f2bf(acc[0][nt][r] + bb);
      if (mm1 < Mn) gi[((size_t)t*Mn + mm1)*Gg + g] = f2bf(acc[1][nt][r] + bb);
    }
  }
}

// ---------------------------------------------------------------- GRU layer 1 (reverse only) + fused LayerNorm
__global__ __launch_bounds__(256) void k_gru1r(const __hip_bfloat16* __restrict__ gi,
    const float* __restrict__ Whh, const float* __restrict__ bhh,
    const float* __restrict__ lns, const float* __restrict__ lnb,
    __hip_bfloat16* __restrict__ xbt)
{
  __shared__ __hip_bfloat16 wh[Hh][WP];
  __shared__ float hb[32][HP];
  __shared__ float bh[Gg];
  __shared__ float sc[Hh], bs[Hh];
  const int tid = threadIdx.x;
  const int m0  = blockIdx.x*32;
  for (int idx = tid; idx < Gg*Hh; idx += 256){
    int g = idx >> 6, k = idx & 63;
    wh[k][g] = f2bf(Whh[(size_t)g*Hh + k]);
  }
  if (tid < Gg) bh[tid] = bhh[tid];
  if (tid < Hh){ sc[tid] = lns[tid]; bs[tid] = lnb[tid]; }
  for (int idx = tid; idx < 32*HP; idx += 256) ((float*)hb)[idx] = 0.f;
  __syncthreads();
  const int jg = tid & 31, rg = tid >> 5;
  const int j0 = jg*2, rg4 = rg*4;
  for (int step = 0; step < Tt; ++step){
    int t = Tt-1-step;
    float ar[4][2], az[4][2], ai[4][2], ah[4][2];
    #pragma unroll
    for (int i = 0; i < 4; ++i){
      int m = m0 + rg4 + i;
      int mc = (m < Mn) ? m : 0;
      const __hip_bfloat16* gp = gi + ((size_t)t*Mn + mc)*Gg;
      __hip_bfloat162 pr = *(const __hip_bfloat162*)&gp[j0];
      __hip_bfloat162 pz = *(const __hip_bfloat162*)&gp[Hh+j0];
      __hip_bfloat162 pn = *(const __hip_bfloat162*)&gp[2*Hh+j0];
      #pragma unroll
      for (int jj = 0; jj < 2; ++jj){
        int j = j0 + jj;
        float gr = jj ? bf2f(pr.y) : bf2f(pr.x);
        float gz = jj ? bf2f(pz.y) : bf2f(pz.x);
        float gn = jj ? bf2f(pn.y) : bf2f(pn.x);
        ar[i][jj] = gr + bh[j];
        az[i][jj] = gz + bh[Hh+j];
        ai[i][jj] = gn;
        ah[i][jj] = bh[2*Hh+j];
      }
    }
    #pragma unroll 4
    for (int k4 = 0; k4 < 16; ++k4){
      float4 h0 = *(const float4*)&hb[rg4+0][k4*4];
      float4 h1 = *(const float4*)&hb[rg4+1][k4*4];
      float4 h2 = *(const float4*)&hb[rg4+2][k4*4];
      float4 h3 = *(const float4*)&hb[rg4+3][k4*4];
      #pragma unroll
      for (int kk = 0; kk < 4; ++kk){
        int k = k4*4 + kk;
        float hv[4] = { ((const float*)&h0)[kk], ((const float*)&h1)[kk],
                        ((const float*)&h2)[kk], ((const float*)&h3)[kk] };
        __hip_bfloat162 pr = *(const __hip_bfloat162*)&wh[k][j0];
        __hip_bfloat162 pz = *(const __hip_bfloat162*)&wh[k][Hh+j0];
        __hip_bfloat162 pn = *(const __hip_bfloat162*)&wh[k][2*Hh+j0];
        float wr[2] = {bf2f(pr.x), bf2f(pr.y)};
        float wz[2] = {bf2f(pz.x), bf2f(pz.y)};
        float wn[2] = {bf2f(pn.x), bf2f(pn.y)};
        #pragma unroll
        for (int i = 0; i < 4; ++i){
          #pragma unroll
          for (int jj = 0; jj < 2; ++jj){
            ar[i][jj] += hv[i]*wr[jj];
            az[i][jj] += hv[i]*wz[jj];
            ah[i][jj] += hv[i]*wn[jj];
          }
        }
      }
    }
    __syncthreads();
    #pragma unroll
    for (int i = 0; i < 4; ++i){
      int r = rg4 + i;
      #pragma unroll
      for (int jj = 0; jj < 2; ++jj){
        float rr = sigm(ar[i][jj]);
        float zz = sigm(az[i][jj]);
        float nn = tanh_f(ai[i][jj] + rr*ah[i][jj]);
        float hv = hb[r][j0+jj];
        hb[r][j0+jj] = (1.f-zz)*nn + zz*hv;
      }
    }
    __syncthreads();
    {
      int r = tid >> 3, l = tid & 7;
      float vals[8];
      float s1 = 0.f, s2 = 0.f;
      #pragma unroll
      for (int q = 0; q < 8; ++q){ float v = hb[r][l + 8*q]; vals[q] = v; s1 += v; s2 += v*v; }
      #pragma unroll
      for (int off = 1; off <= 4; off <<= 1){ s1 += __shfl_xor(s1, off); s2 += __shfl_xor(s2, off); }
      float mu  = s1 * (1.f/64.f);
      float var = s2 * (1.f/64.f) - mu*mu;
      float rs  = rsqrtf(var + 1e-5f);
      int m = m0 + r;
      if (m < Mn){
        __hip_bfloat16* op = xbt + ((size_t)t*Mn + m)*Hh;
        #pragma unroll
        for (int q = 0; q < 8; ++q){ int j = l + 8*q; op[j] = f2bf((vals[q]-mu)*rs*sc[j] + bs[j]); }
      }
    }
    __syncthreads();
  }
}

// ---------------------------------------------------------------- fused power iteration: all 76 rounds in ONE kernel.
// 252 blocks, 120KB LDS -> 1 block/CU -> all co-resident (252 <= 256 CUs).
// Sync: 12 independent per-t spin barriers (21 arrivals each) -- a t-group
// only consumes data written by its own 21 blocks. Release/acquire via
// __threadfence() (agent-scope wbL2/inv) around the device-scope atomics.
// Per-row math is bit-identical to the validated multi-launch version.
__global__ __launch_bounds__(1024) void k_pitall(const int* __restrict__ rp,
    const unsigned short* __restrict__ col, float* __restrict__ uA, float* __restrict__ uB,
    float* __restrict__ nrm2, float* __restrict__ dotb, float* __restrict__ lamc,
    int* __restrict__ bar)
{
  __shared__ float u_s[Mn];                 // 120000 B
  __shared__ float redw[16];
  const int b = blockIdx.x;                 // Tt*CHK = 252
  const int t = b / CHK, ch = b - t*CHK;
  const int r0 = ch*RC;
  const int r1 = (r0 + RC < Mn) ? r0 + RC : Mn;
  const int tid = threadIdx.x;
  const unsigned short* cp = col + (size_t)t*Ee;
  // cache row ranges in registers once (each thread owns <=2 rows)
  const int m0r = r0 + tid;
  const int m1r = m0r + 1024;
  int rb0 = 0, re0 = 0, rb1 = 0, re1 = 0;
  {
    const int* rpt = rp + t*(Mn+1);
    if (m0r < r1){ rb0 = rpt[m0r]; re0 = rpt[m0r+1]; }
    if (m1r < r1){ rb1 = rpt[m1r]; re1 = rpt[m1r+1]; }
  }
  for (int r = 1; r <= NRND; ++r){
    const float* uin  = ((r-1) & 1) ? uB : uA;
    float*       uout = (r & 1)     ? uB : uA;
    const int fin = (r == NRND);
    const float* ut = uin + t*Mn;
    for (int i = tid; i < Mn/4; i += 1024) ((float4*)u_s)[i] = ((const float4*)ut)[i];
    __syncthreads();
    const float inv_s = fin ? 1.f : 1.f/(sqrtf(nrm2[(r-1)*Tt + t]) + 1e-12f);
    float local = 0.f;
    if (m0r < r1){
      float s = 0.f;
      int i = rb0;
      for (; i < re0 && (i & 3); ++i) s += u_s[cp[i]];
      for (; i + 4 <= re0; i += 4){
        ushort4 c4 = *(const ushort4*)(cp + i);
        s += (u_s[c4.x] + u_s[c4.y]) + (u_s[c4.z] + u_s[c4.w]);
      }
      for (; i < re0; ++i) s += u_s[cp[i]];
      float uv = u_s[m0r];
      float wv = (float)(re0 - rb0)*uv - s;
      if (!fin){ float o = inv_s*wv; uout[t*Mn + m0r] = o; local += o*o; }
      else local += uv*wv;
    }
    if (m1r < r1){
      float s = 0.f;
      int i = rb1;
      for (; i < re1 && (i & 3); ++i) s += u_s[cp[i]];
      for (; i + 4 <= re1; i += 4){
        ushort4 c4 = *(const ushort4*)(cp + i);
        s += (u_s[c4.x] + u_s[c4.y]) + (u_s[c4.z] + u_s[c4.w]);
      }
      for (; i < re1; ++i) s += u_s[cp[i]];
      float uv = u_s[m1r];
      float wv = (float)(re1 - rb1)*uv - s;
      if (!fin){ float o = inv_s*wv; uout[t*Mn + m1r] = o; local += o*o; }
      else local += uv*wv;
    }
    #pragma unroll
    for (int o2 = 1; o2 < 64; o2 <<= 1) local += __shfl_xor(local, o2);
    if ((tid & 63) == 0) redw[tid >> 6] = local;
    __syncthreads();
    if (tid == 0){
      float tot = 0.f;
      #pragma unroll
      for (int q = 0; q < 16; ++q) tot += redw[q];
      atomicAdd(fin ? &dotb[t] : &nrm2[r*Tt + t], tot);
      __threadfence();                       // release: flush uout stores + reduction out of XCD L2
      atomicAdd(&bar[t], 1);                 // arrive (device-scope)
      const int target = CHK*r;
      while (atomicAdd(&bar[t], 0) < target) __builtin_amdgcn_s_sleep(8);
      __threadfence();                       // acquire: invalidate L1/L2 before reading peers' data
    }
    __syncthreads();
  }
  // folded k_lamfin: one block per t
  if (ch == 0 && tid == 0){
    float nn = sqrtf(nrm2[75*Tt + t]) + 1e-12f;
    float lam = dotb[t] / (nn*nn);
    lamc[2*t+0] = -2.f/lam;
    lamc[2*t+1] =  2.f/lam - 1.f;
  }
}

// ---------------------------------------------------------------- Chebyshev SpMM (wave per row, lane = channel, XCD-swizzled)
__global__ __launch_bounds__(256) void k_cheb(const __hip_bfloat16* __restrict__ xin,
    const __hip_bfloat16* __restrict__ xb0, __hip_bfloat16* __restrict__ outp,
    const int* __restrict__ rp, const unsigned short* __restrict__ col,
    const float* __restrict__ dinv, const float* __restrict__ lamc, float s1, float s2)
{
  const int blk = blockIdx.x;               // 90000 = 8*11250
  const int w = (blk & 7)*11250 + (blk >> 3);
  const int gw = w*4 + (threadIdx.x >> 6);
  const int lane = threadIdx.x & 63;
  int t = gw / Mn, m = gw - t*Mn;
  float coef = lamc[2*t], diag = lamc[2*t+1];
  const __hip_bfloat16* xt = xin + (size_t)t*Mn*Hh;
  const float* dv = dinv + t*Mn;
  float acc = diag * bf2f(xt[(size_t)m*Hh + lane]);
  float cdm = coef * dv[m];
  int bgn = rp[t*(Mn+1)+m], end = rp[t*(Mn+1)+m+1];
  const unsigned short* cp = col + (size_t)t*Ee;
  int i = bgn;
  for (; i < end && (i & 3); ++i){ int c = cp[i]; acc += (cdm*dv[c])*bf2f(xt[(size_t)c*Hh + lane]); }
  for (; i + 4 <= end; i += 4){
    ushort4 c4 = *(const ushort4*)(cp + i);
    float w0 = cdm*dv[c4.x], w1 = cdm*dv[c4.y], w2 = cdm*dv[c4.z], w3 = cdm*dv[c4.w];
    acc += w0*bf2f(xt[(size_t)c4.x*Hh + lane]);
    acc += w1*bf2f(xt[(size_t)c4.y*Hh + lane]);
    acc += w2*bf2f(xt[(size_t)c4.z*Hh + lane]);
    acc += w3*bf2f(xt[(size_t)c4.w*Hh + lane]);
  }
  for (; i < end; ++i){ int c = cp[i]; acc += (cdm*dv[c])*bf2f(xt[(size_t)c*Hh + lane]); }
  float o = s1*acc;
  if (s2 != 0.f) o += s2*bf2f(xb0[(size_t)gw*Hh + lane]);
  outp[(size_t)gw*Hh + lane] = f2bf(o);
}

// ---------------------------------------------------------------- fold cheb_W into conv_W
__global__ void k_ww(const float* __restrict__ chebW, const float* __restrict__ chebb,
    const float* __restrict__ convW, const float* __restrict__ convb, float* __restrict__ WW, float* __restrict__ c0)
{
  int idx = blockIdx.x*256 + threadIdx.x;
  if (idx < 3*Tt*Hh*Oo){
    int oc = idx % Oo; int j = (idx/Oo) % Hh; int t = (idx/(Oo*Hh)) % Tt; int i = idx/(Oo*Hh*Tt);
    const float* cw = chebW + ((size_t)i*Hh + j)*HC + (HC-KW);
    const float* vw = convW + ((size_t)oc*Tt + t)*KW;
    float s = 0.f;
    for (int k = 0; k < KW; ++k) s += cw[k]*vw[k];
    WW[idx] = s;
  }
  if (blockIdx.x == 0 && threadIdx.x < Oo){
    int oc = threadIdx.x;
    float s = convb[oc];
    for (int t = 0; t < Tt; ++t){
      const float* vw = convW + ((size_t)oc*Tt + t)*KW;
      for (int k = 0; k < KW; ++k) s += chebb[(HC-KW)+k]*vw[k];
    }
    c0[oc] = s;
  }
}

// ---------------------------------------------------------------- fused cheb-GEMM + temporal conv + sigmoid
__global__ __launch_bounds__(256) void k_final(const __hip_bfloat16* __restrict__ tx0,
    const __hip_bfloat16* __restrict__ tx1, const __hip_bfloat16* __restrict__ tx2,
    const float* __restrict__ WW, const float* __restrict__ c0, float* __restrict__ outp)
{
  __shared__ float xs[64][65];
  __shared__ float ww[64][12];
  const int tid = threadIdx.x;
  const int n0 = blockIdx.x*64;
  const int n = tid & 63, ob = (tid >> 6)*3;
  float acc[3] = {0.f, 0.f, 0.f};
  for (int it = 0; it < 3*Tt; ++it){
    int ii = it / Tt, t = it % Tt;
    const __hip_bfloat16* tx = (ii == 0) ? tx0 : (ii == 1) ? tx1 : tx2;
    __syncthreads();
    for (int idx = tid; idx < 64*64; idx += 256){
      int mm = idx >> 6, j = idx & 63;
      int m = n0 + mm;
      xs[mm][j] = (m < Mn) ? bf2f(tx[((size_t)t*Mn + m)*Hh + j]) : 0.f;
    }
    for (int idx = tid; idx < 64*Oo; idx += 256)
      ((float*)ww)[idx] = WW[((size_t)(ii*Tt + t)*Hh)*Oo + idx];
    __syncthreads();
    #pragma unroll 8
    for (int j = 0; j < 64; ++j){
      float x = xs[n][j];
      acc[0] += x*ww[j][ob+0];
      acc[1] += x*ww[j][ob+1];
      acc[2] += x*ww[j][ob+2];
    }
  }
  int m = n0 + n;
  if (m < Mn){
    #pragma unroll
    for (int q = 0; q < 3; ++q) outp[(size_t)m*Oo + ob + q] = sigm(acc[q] + c0[ob+q]);
  }
}

// ================================================================ host
extern "C" void kernel_launch(void* const* d_in, const int* in_sizes, int n_in,
                              void* d_out, int out_size, void* d_ws, size_t ws_size,
                              hipStream_t stream)
{
  const float* nf    = (const float*)d_in[0];
  const int*   ei    = (const int*)d_in[1];
  const float* Wih0  = (const float*)d_in[2];
  const float* Whh0  = (const float*)d_in[3];
  const float* bih0  = (const float*)d_in[4];
  const float* bhh0  = (const float*)d_in[5];
  const float* Wih1  = (const float*)d_in[6];
  const float* Whh1  = (const float*)d_in[7];
  const float* bih1  = (const float*)d_in[8];
  const float* bhh1  = (const float*)d_in[9];
  const float* lns   = (const float*)d_in[10];
  const float* lnb   = (const float*)d_in[11];
  const float* chebW = (const float*)d_in[12];
  const float* chebb = (const float*)d_in[13];
  const float* convW = (const float*)d_in[14];
  const float* convb = (const float*)d_in[15];
  float* outp = (float*)d_out;

  char* base = (char*)d_ws;
  size_t off = 0;
  auto alloc = [&](size_t bytes)->char*{ char* p = base + off; off += (bytes + 255) & ~(size_t)255; return p; };

  __hip_bfloat16* y0  = (__hip_bfloat16*)alloc((size_t)Tt*Mn*C2*2);
  __hip_bfloat16* tx1 = y0;
  __hip_bfloat16* tx2 = y0 + (size_t)Tt*Mn*Hh;
  __hip_bfloat16* gi  = (__hip_bfloat16*)alloc((size_t)Tt*Mn*Gg*2);
  unsigned* pair = (unsigned*)gi;          // overlaps gi: pair dead before k_gi1m writes gi
  __hip_bfloat16* xbt = (__hip_bfloat16*)alloc((size_t)Tt*Mn*Hh*2);
  unsigned short* col16 = (unsigned short*)alloc((size_t)Tt*Ee*2);
  int*   deg  = (int*)alloc((size_t)Tt*Mn*4);
  int*   rp   = (int*)alloc((size_t)Tt*(Mn+1)*4);
  int*   bcnt = (int*)alloc((size_t)Tt*NB*4);
  int*   bfill= (int*)alloc((size_t)Tt*NB*4);
  int*   rpb  = (int*)alloc((size_t)Tt*(NB+1)*4);
  float* uA   = (float*)alloc((size_t)Tt*Mn*4);
  float* uB   = (float*)alloc((size_t)Tt*Mn*4);
  float* dinv = (float*)alloc((size_t)Tt*Mn*4);
  float* nrm2 = (float*)alloc((size_t)76*Tt*4);
  float* dotb = (float*)alloc((size_t)Tt*4);
  float* lamc = (float*)alloc((size_t)2*Tt*4);
  float* WW   = (float*)alloc((size_t)3*Tt*Hh*Oo*4);
  float* c0   = (float*)alloc((size_t)Oo*4);
  __hip_bfloat16* Wbf = (__hip_bfloat16*)alloc((size_t)Gg*C2*2);
  int*   bar  = (int*)alloc((size_t)Tt*4);
  (void)ws_size; (void)in_sizes; (void)n_in; (void)out_size;

  // CSR build: bucket histogram -> bucket scan -> partition -> per-bucket counting sort (emits rp+deg)
  k_init<<<(Tt*Mn + 255)/256, 256, 0, stream>>>(nrm2, dotb, uA, bcnt, bfill, bar);
  k_bcnt<<<Tt*BPT, 256, 0, stream>>>(ei, bcnt);
  k_bscan<<<Tt, 256, 0, stream>>>(bcnt, rpb);
  k_part2<<<Tt*BPT, 256, 0, stream>>>(ei, rpb, bfill, pair);
  k_csr2<<<Tt*NB, 256, 0, stream>>>(rpb, pair, col16, rp, deg);
  k_dinv<<<(Tt*Mn + 255)/256, 256, 0, stream>>>(deg, dinv);

  // GRU stack (layer-1 forward direction is dead code -> skipped)
  k_wcvt<<<(Gg*C2 + 255)/256, 256, 0, stream>>>(Wih1 + (size_t)Gg*C2, Wbf);
  k_gru0<<<(Mn + 31)/32, 256, 0, stream>>>(nf, Wih0, Whh0, bih0, bhh0, y0);
  {
    int waves = Tt*((Mn + 31)/32);
    k_gi1m<<<(waves + 3)/4, 256, 0, stream>>>(y0, Wbf, bih1 + Gg, gi);
  }
  k_gru1r<<<(Mn + 31)/32, 256, 0, stream>>>(gi, Whh1 + (size_t)Gg*Hh, bhh1 + Gg, lns, lnb, xbt);

  // power iteration: 75 rounds + 1 Rayleigh round, fused into ONE kernel with
  // per-t device barriers; lamfin folded in (saves 75 launches + drains)
  k_pitall<<<Tt*CHK, 1024, 0, stream>>>(rp, col16, uA, uB, nrm2, dotb, lamc, bar);

  // Chebyshev: tx1 = Lhat(x), tx2 = 2*Lhat(tx1) - x
  k_cheb<<<(Tt*Mn)/4, 256, 0, stream>>>(xbt, xbt, tx1, rp, col16, dinv, lamc, 1.f, 0.f);
  k_cheb<<<(Tt*Mn)/4, 256, 0, stream>>>(tx1, xbt, tx2, rp, col16, dinv, lamc, 2.f, -1.f);

  // folded cheb-GEMM + conv + sigmoid
  k_ww<<<(3*Tt*Hh*Oo + 255)/256, 256, 0, stream>>>(chebW, chebb, convW, convb, WW, c0);
  k_final<<<(Mn + 63)/64, 256, 0, stream>>>(xbt, tx1, tx2, WW, c0, outp);
}

// Round 2
// 3956.715 us; speedup vs baseline: 1.1017x; 1.1017x over previous
//
#include <hip/hip_runtime.h>
#include <hip/hip_bf16.h>

#define DEV __device__ __forceinline__

constexpr int Mn  = 30000;   // nodes (B=1)
constexpr int Tt  = 12;
constexpr int CIN = 16;
constexpr int Hh  = 64;
constexpr int Gg  = 192;     // 3H
constexpr int C2  = 128;     // 2H
constexpr int Ee  = 960000;  // edges per timestep (bidirectional)
constexpr int HC  = 128;
constexpr int Oo  = 12;
constexpr int KW  = 128;
constexpr int HP  = 72;      // padded h row stride (floats)
constexpr int WP  = 194;     // padded weight row stride (bf16): bank stride 97 (odd) -> conflict-free
constexpr int XSP = 36;      // padded xs inner stride (floats): 16B-aligned, 2-way max
constexpr int NB  = 235;     // 128-row buckets per t (235*128 >= 30000)
constexpr int EPB = 8192;    // edges per block for bcnt/part2
constexpr int BPT = 118;     // ceil(Ee/EPB)
constexpr int CHK = 21;      // chunks per t for power iteration (252 blocks total)
constexpr int RC  = 1429;    // rows per chunk (21*1429 >= 30000)
constexpr int NRND= 76;      // 75 power rounds + 1 Rayleigh round

DEV float bf2f(__hip_bfloat16 v){ return __bfloat162float(v); }
DEV __hip_bfloat16 f2bf(float v){ return __float2bfloat16(v); }
DEV float sigm(float x){ return __builtin_amdgcn_rcpf(1.f + __expf(-x)); }
DEV float tanh_f(float x){ return 1.f - 2.f*__builtin_amdgcn_rcpf(__expf(2.f*x) + 1.f); }

// agent-scope (device-coherent, sc1) accessors: bypass the non-coherent XCD L2,
// served by the die-level Infinity Cache -> cross-XCD coherent WITHOUT any
// cache-wide wb/inv fences.
DEV float aload_f(const float* p){ return __hip_atomic_load(p, __ATOMIC_RELAXED, __HIP_MEMORY_SCOPE_AGENT); }
DEV void  astore_f(float* p, float v){ __hip_atomic_store(p, v, __ATOMIC_RELAXED, __HIP_MEMORY_SCOPE_AGENT); }
DEV unsigned long long aload_u64(const unsigned long long* p){ return __hip_atomic_load(p, __ATOMIC_RELAXED, __HIP_MEMORY_SCOPE_AGENT); }
DEV int   aload_i(const int* p){ return __hip_atomic_load(p, __ATOMIC_RELAXED, __HIP_MEMORY_SCOPE_AGENT); }

typedef short bfrag8 __attribute__((ext_vector_type(8)));
typedef float ffrag4 __attribute__((ext_vector_type(4)));

// ---------------------------------------------------------------- init
__global__ void k_init(float* nrm2, float* dotb, float* u0, int* bcnt, int* bfill, int* bar){
  int i = blockIdx.x*256 + threadIdx.x;
  if (i < Tt*Mn) u0[i] = 0.005773502691896258f;    // 1/sqrt(30000)
  if (i < 76*Tt) nrm2[i] = (i < Tt) ? 1.0f : 0.0f;
  if (i < Tt){ dotb[i] = 0.f; bar[i] = 0; }
  if (i < Tt*NB){ bcnt[i] = 0; bfill[i] = 0; }
}

// ---------------------------------------------------------------- stage 1: block-aggregated bucket histogram
__global__ __launch_bounds__(256) void k_bcnt(const int* __restrict__ ei, int* __restrict__ bcnt){
  __shared__ int h[NB];
  const int b = blockIdx.x;                 // 1416 = 8*177
  const int w = (b & 7)*177 + (b >> 3);
  const int t = w / BPT, ch = w - t*BPT;
  const int e0 = ch*EPB;
  const int tid = threadIdx.x;
  for (int i = tid; i < NB; i += 256) h[i] = 0;
  __syncthreads();
  #pragma unroll
  for (int i = 0; i < 32; ++i){
    int e = e0 + i*256 + tid;
    if (e < Ee){
      int r = ei[(size_t)(t*2)*Ee + e];
      atomicAdd(&h[r >> 7], 1);
    }
  }
  __syncthreads();
  for (int i = tid; i < NB; i += 256){
    int c = h[i];
    if (c > 0) atomicAdd(&bcnt[t*NB + i], c);
  }
}

// ---------------------------------------------------------------- stage 2: per-t exclusive scan of bucket counts
__global__ __launch_bounds__(256) void k_bscan(const int* __restrict__ bcnt, int* __restrict__ rpb){
  int t = blockIdx.x, tid = threadIdx.x;
  __shared__ int ps[256];
  int v = (tid < NB) ? bcnt[t*NB + tid] : 0;
  ps[tid] = v;
  __syncthreads();
  for (int o = 1; o < 256; o <<= 1){
    int x = (tid >= o) ? ps[tid-o] : 0;
    __syncthreads();
    ps[tid] += x;
    __syncthreads();
  }
  if (tid < NB) rpb[t*(NB+1) + tid] = ps[tid] - v;
  if (tid == 255) rpb[t*(NB+1) + NB] = ps[NB-1];
}

// ---------------------------------------------------------------- stage 3: partition edges into buckets (block-aggregated reservations)
__global__ __launch_bounds__(256) void k_part2(const int* __restrict__ ei, const int* __restrict__ rpb,
    int* __restrict__ bfill, unsigned* __restrict__ pair){
  __shared__ int hcnt[NB];
  __shared__ int hbase[NB];
  const int b = blockIdx.x;                 // 1416 = 8*177
  const int w = (b & 7)*177 + (b >> 3);
  const int t = w / BPT, ch = w - t*BPT;
  const int e0 = ch*EPB;
  const int tid = threadIdx.x;
  for (int i = tid; i < NB; i += 256) hcnt[i] = 0;
  __syncthreads();
  unsigned key[32];
  #pragma unroll
  for (int i = 0; i < 32; ++i){
    int e = e0 + i*256 + tid;
    unsigned k = 0xFFFFFFFFu;
    if (e < Ee){
      int r = ei[(size_t)(t*2)*Ee + e];
      int c = ei[(size_t)(t*2+1)*Ee + e];
      k = ((unsigned)r << 16) | (unsigned)c;
      atomicAdd(&hcnt[r >> 7], 1);
    }
    key[i] = k;
  }
  __syncthreads();
  for (int i = tid; i < NB; i += 256){
    int cnt = hcnt[i];
    int base = (cnt > 0) ? atomicAdd(&bfill[t*NB + i], cnt) : 0;
    hbase[i] = rpb[t*(NB+1) + i] + base;
  }
  __syncthreads();
  for (int i = tid; i < NB; i += 256) hcnt[i] = 0;
  __syncthreads();
  #pragma unroll
  for (int i = 0; i < 32; ++i){
    unsigned k = key[i];
    if (k != 0xFFFFFFFFu){
      int r = (int)(k >> 16);
      int bk = r >> 7;
      int pos = atomicAdd(&hcnt[bk], 1);
      pair[(size_t)t*Ee + hbase[bk] + pos] = ((unsigned)(r & 127) << 16) | (k & 0xFFFFu);
    }
  }
}

// ---------------------------------------------------------------- stage 4: per-bucket LDS counting sort -> col16, rp, deg
__global__ __launch_bounds__(256) void k_csr2(const int* __restrict__ rpb, const unsigned* __restrict__ pair,
    unsigned short* __restrict__ col16, int* __restrict__ rp, int* __restrict__ deg){
  __shared__ unsigned short cols_s[9216];
  __shared__ int lcnt[128], lfill[128];
  __shared__ int ps[256];
  const int blk = blockIdx.x;               // Tt*NB
  const int t = blk / NB, bk = blk - t*NB;
  const int r0 = bk << 7;
  const int nr = (r0 + 128 <= Mn) ? 128 : (Mn - r0);
  const int base = rpb[t*(NB+1) + bk];
  const int cnt  = rpb[t*(NB+1) + bk + 1] - base;
  const int tid = threadIdx.x;
  if (tid < 128) lcnt[tid] = 0;
  __syncthreads();
  for (int i = tid; i < cnt; i += 256){
    unsigned v = pair[(size_t)t*Ee + base + i];
    atomicAdd(&lcnt[v >> 16], 1);
  }
  __syncthreads();
  int v2 = (tid < 128) ? lcnt[tid] : 0;
  ps[tid] = v2;
  __syncthreads();
  for (int o = 1; o < 128; o <<= 1){
    int x = (tid >= o) ? ps[tid-o] : 0;
    __syncthreads();
    ps[tid] += x;
    __syncthreads();
  }
  if (tid < 128){
    int excl = ps[tid] - v2;
    lfill[tid] = excl;
    if (tid < nr){
      rp[t*(Mn+1) + r0 + tid] = base + excl;
      deg[t*Mn + r0 + tid] = v2;
    }
  }
  if (bk == NB-1 && tid == 0) rp[t*(Mn+1) + Mn] = base + cnt;
  __syncthreads();
  for (int i = tid; i < cnt; i += 256){
    unsigned v = pair[(size_t)t*Ee + base + i];
    int pos = atomicAdd(&lfill[v >> 16], 1);
    cols_s[pos] = (unsigned short)(v & 0xFFFFu);
  }
  __syncthreads();
  for (int i = tid; i < cnt; i += 256)
    col16[(size_t)t*Ee + base + i] = cols_s[i];
}

// ---------------------------------------------------------------- dinv
__global__ void k_dinv(const int* __restrict__ deg, float* __restrict__ dinv){
  int i = blockIdx.x*256 + threadIdx.x;
  if (i < Tt*Mn){ int d = deg[i]; dinv[i] = (d > 0) ? rsqrtf((float)d) : 0.f; }
}

// ---------------------------------------------------------------- GRU layer 0 (both dirs), writes y0 (T,M,128) bf16
__global__ __launch_bounds__(256) void k_gru0(
    const float* __restrict__ nf, const float* __restrict__ Wih, const float* __restrict__ Whh,
    const float* __restrict__ bih, const float* __restrict__ bhh, __hip_bfloat16* __restrict__ y0)
{
  __shared__ float xs[Tt][CIN][XSP];
  __shared__ __hip_bfloat16 wi[CIN][WP];
  __shared__ __hip_bfloat16 wh[Hh][WP];
  __shared__ float hb[32][HP];
  __shared__ float bi[Gg], bh[Gg];
  const int tid = threadIdx.x;
  const int m0  = blockIdx.x*32;
  for (int idx = tid; idx < Tt*32*CIN; idx += 256){
    int t = idx / (32*CIN); int rr = (idx / CIN) & 31; int k = idx & (CIN-1);
    int m = m0 + rr;
    xs[t][k][rr] = (m < Mn) ? nf[((size_t)t*Mn + m)*CIN + k] : 0.f;
  }
  const int jg = tid & 31, rg = tid >> 5;
  const int j0 = jg*2, rg4 = rg*4;
  for (int d = 0; d < 2; ++d){
    __syncthreads();
    for (int idx = tid; idx < Gg*CIN; idx += 256){
      int g = idx / CIN, k = idx & (CIN-1);
      wi[k][g] = f2bf(Wih[((size_t)d*Gg + g)*CIN + k]);
    }
    for (int idx = tid; idx < Gg*Hh; idx += 256){
      int g = idx >> 6, k = idx & 63;
      wh[k][g] = f2bf(Whh[((size_t)d*Gg + g)*Hh + k]);
    }
    if (tid < Gg){ bi[tid] = bih[d*Gg + tid]; bh[tid] = bhh[d*Gg + tid]; }
    for (int idx = tid; idx < 32*HP; idx += 256) ((float*)hb)[idx] = 0.f;
    __syncthreads();
    for (int step = 0; step < Tt; ++step){
      int t = d ? (Tt-1-step) : step;
      float ar[4][2], az[4][2], ai[4][2], ah[4][2];
      #pragma unroll
      for (int i = 0; i < 4; ++i){
        #pragma unroll
        for (int jj = 0; jj < 2; ++jj){
          int j = j0 + jj;
          ar[i][jj] = bi[j] + bh[j];
          az[i][jj] = bi[Hh+j] + bh[Hh+j];
          ai[i][jj] = bi[2*Hh+j];
          ah[i][jj] = bh[2*Hh+j];
        }
      }
      #pragma unroll
      for (int k = 0; k < CIN; ++k){
        float4 xv4 = *(const float4*)&xs[t][k][rg4];
        float xv[4] = {xv4.x, xv4.y, xv4.z, xv4.w};
        __hip_bfloat162 pr = *(const __hip_bfloat162*)&wi[k][j0];
        __hip_bfloat162 pz = *(const __hip_bfloat162*)&wi[k][Hh+j0];
        __hip_bfloat162 pn = *(const __hip_bfloat162*)&wi[k][2*Hh+j0];
        float wr[2] = {bf2f(pr.x), bf2f(pr.y)};
        float wz[2] = {bf2f(pz.x), bf2f(pz.y)};
        float wn[2] = {bf2f(pn.x), bf2f(pn.y)};
        #pragma unroll
        for (int i = 0; i < 4; ++i){
          #pragma unroll
          for (int jj = 0; jj < 2; ++jj){
            ar[i][jj] += xv[i]*wr[jj];
            az[i][jj] += xv[i]*wz[jj];
            ai[i][jj] += xv[i]*wn[jj];
          }
        }
      }
      #pragma unroll 4
      for (int k4 = 0; k4 < 16; ++k4){
        float4 h0 = *(const float4*)&hb[rg4+0][k4*4];
        float4 h1 = *(const float4*)&hb[rg4+1][k4*4];
        float4 h2 = *(const float4*)&hb[rg4+2][k4*4];
        float4 h3 = *(const float4*)&hb[rg4+3][k4*4];
        #pragma unroll
        for (int kk = 0; kk < 4; ++kk){
          int k = k4*4 + kk;
          float hv[4] = { ((const float*)&h0)[kk], ((const float*)&h1)[kk],
                          ((const float*)&h2)[kk], ((const float*)&h3)[kk] };
          __hip_bfloat162 pr = *(const __hip_bfloat162*)&wh[k][j0];
          __hip_bfloat162 pz = *(const __hip_bfloat162*)&wh[k][Hh+j0];
          __hip_bfloat162 pn = *(const __hip_bfloat162*)&wh[k][2*Hh+j0];
          float wr[2] = {bf2f(pr.x), bf2f(pr.y)};
          float wz[2] = {bf2f(pz.x), bf2f(pz.y)};
          float wn[2] = {bf2f(pn.x), bf2f(pn.y)};
          #pragma unroll
          for (int i = 0; i < 4; ++i){
            #pragma unroll
            for (int jj = 0; jj < 2; ++jj){
              ar[i][jj] += hv[i]*wr[jj];
              az[i][jj] += hv[i]*wz[jj];
              ah[i][jj] += hv[i]*wn[jj];
            }
          }
        }
      }
      __syncthreads();
      #pragma unroll
      for (int i = 0; i < 4; ++i){
        int r = rg4 + i; int m = m0 + r;
        float hn2[2];
        #pragma unroll
        for (int jj = 0; jj < 2; ++jj){
          float rr = sigm(ar[i][jj]);
          float zz = sigm(az[i][jj]);
          float nn = tanh_f(ai[i][jj] + rr*ah[i][jj]);
          float hv = hb[r][j0+jj];
          hn2[jj] = (1.f-zz)*nn + zz*hv;
          hb[r][j0+jj] = hn2[jj];
        }
        if (m < Mn){
          __hip_bfloat162 pk; pk.x = f2bf(hn2[0]); pk.y = f2bf(hn2[1]);
          *(__hip_bfloat162*)&y0[((size_t)t*Mn + m)*C2 + d*Hh + j0] = pk;
        }
      }
      __syncthreads();
    }
  }
}

// ---------------------------------------------------------------- convert layer-1 reverse weights to bf16
__global__ void k_wcvt(const float* __restrict__ W, __hip_bfloat16* __restrict__ Wbf){
  int i = blockIdx.x*256 + threadIdx.x;
  if (i < Gg*C2) Wbf[i] = f2bf(W[i]);
}

// ---------------------------------------------------------------- layer-1 input projection via MFMA
__global__ __launch_bounds__(256) void k_gi1m(const __hip_bfloat16* __restrict__ y0,
    const __hip_bfloat16* __restrict__ Wbf, const float* __restrict__ bih, __hip_bfloat16* __restrict__ gi)
{
  const int wid  = (blockIdx.x*256 + threadIdx.x) >> 6;
  const int lane = threadIdx.x & 63;
  const int SEGS = (Mn + 31)/32;
  if (wid >= Tt*SEGS) return;
  const int t = wid / SEGS, seg = wid - t*SEGS;
  const int m0 = seg*32;
  const int lr = lane & 15, lq = lane >> 4;
  const __hip_bfloat16* yb = y0 + (size_t)t*Mn*C2;

  ffrag4 acc[2][12];
  #pragma unroll
  for (int i = 0; i < 2; ++i){
    #pragma unroll
    for (int n = 0; n < 12; ++n) acc[i][n] = (ffrag4){0.f,0.f,0.f,0.f};
  }
  #pragma unroll
  for (int ks = 0; ks < 4; ++ks){
    const int ko = ks*32 + lq*8;
    bfrag8 a0 = *(const bfrag8*)(yb + (size_t)(m0 + lr     )*C2 + ko);
    bfrag8 a1 = *(const bfrag8*)(yb + (size_t)(m0 + 16 + lr)*C2 + ko);
    #pragma unroll
    for (int nt = 0; nt < 12; ++nt){
      bfrag8 b = *(const bfrag8*)(Wbf + (size_t)(nt*16 + lr)*C2 + ko);
      acc[0][nt] = __builtin_amdgcn_mfma_f32_16x16x32_bf16(a0, b, acc[0][nt], 0, 0, 0);
      acc[1][nt] = __builtin_amdgcn_mfma_f32_16x16x32_bf16(a1, b, acc[1][nt], 0, 0, 0);
    }
  }
  #pragma unroll
  for (int nt = 0; nt < 12; ++nt){
    int g = nt*16 + lr;
    float bb = bih[g];
    #pragma unroll
    for (int r = 0; r < 4; ++r){
      int mm0 = m0 + lq*4 + r;
      int mm1 = mm0 + 16;
      if (mm0 < Mn) gi[((size_t)t*Mn + mm0)*Gg + g] = f2bf(acc[0][nt][r] + bb);
      if (mm1 < Mn) gi[((size_t)t*Mn + mm1)*Gg + g] = f2bf(acc[1][nt][r] + bb);
    }
  }
}

// ---------------------------------------------------------------- GRU layer 1 (reverse only) + fused LayerNorm
__global__ __launch_bounds__(256) void k_gru1r(const __hip_bfloat16* __restrict__ gi,
    const float* __restrict__ Whh, const float* __restrict__ bhh,
    const float* __restrict__ lns, const float* __restrict__ lnb,
    __hip_bfloat16* __restrict__ xbt)
{
  __shared__ __hip_bfloat16 wh[Hh][WP];
  __shared__ float hb[32][HP];
  __shared__ float bh[Gg];
  __shared__ float sc[Hh], bs[Hh];
  const int tid = threadIdx.x;
  const int m0  = blockIdx.x*32;
  for (int idx = tid; idx < Gg*Hh; idx += 256){
    int g = idx >> 6, k = idx & 63;
    wh[k][g] = f2bf(Whh[(size_t)g*Hh + k]);
  }
  if (tid < Gg) bh[tid] = bhh[tid];
  if (tid < Hh){ sc[tid] = lns[tid]; bs[tid] = lnb[tid]; }
  for (int idx = tid; idx < 32*HP; idx += 256) ((float*)hb)[idx] = 0.f;
  __syncthreads();
  const int jg = tid & 31, rg = tid >> 5;
  const int j0 = jg*2, rg4 = rg*4;
  for (int step = 0; step < Tt; ++step){
    int t = Tt-1-step;
    float ar[4][2], az[4][2], ai[4][2], ah[4][2];
    #pragma unroll
    for (int i = 0; i < 4; ++i){
      int m = m0 + rg4 + i;
      int mc = (m < Mn) ? m : 0;
      const __hip_bfloat16* gp = gi + ((size_t)t*Mn + mc)*Gg;
      __hip_bfloat162 pr = *(const __hip_bfloat162*)&gp[j0];
      __hip_bfloat162 pz = *(const __hip_bfloat162*)&gp[Hh+j0];
      __hip_bfloat162 pn = *(const __hip_bfloat162*)&gp[2*Hh+j0];
      #pragma unroll
      for (int jj = 0; jj < 2; ++jj){
        int j = j0 + jj;
        float gr = jj ? bf2f(pr.y) : bf2f(pr.x);
        float gz = jj ? bf2f(pz.y) : bf2f(pz.x);
        float gn = jj ? bf2f(pn.y) : bf2f(pn.x);
        ar[i][jj] = gr + bh[j];
        az[i][jj] = gz + bh[Hh+j];
        ai[i][jj] = gn;
        ah[i][jj] = bh[2*Hh+j];
      }
    }
    #pragma unroll 4
    for (int k4 = 0; k4 < 16; ++k4){
      float4 h0 = *(const float4*)&hb[rg4+0][k4*4];
      float4 h1 = *(const float4*)&hb[rg4+1][k4*4];
      float4 h2 = *(const float4*)&hb[rg4+2][k4*4];
      float4 h3 = *(const float4*)&hb[rg4+3][k4*4];
      #pragma unroll
      for (int kk = 0; kk < 4; ++kk){
        int k = k4*4 + kk;
        float hv[4] = { ((const float*)&h0)[kk], ((const float*)&h1)[kk],
                        ((const float*)&h2)[kk], ((const float*)&h3)[kk] };
        __hip_bfloat162 pr = *(const __hip_bfloat162*)&wh[k][j0];
        __hip_bfloat162 pz = *(const __hip_bfloat162*)&wh[k][Hh+j0];
        __hip_bfloat162 pn = *(const __hip_bfloat162*)&wh[k][2*Hh+j0];
        float wr[2] = {bf2f(pr.x), bf2f(pr.y)};
        float wz[2] = {bf2f(pz.x), bf2f(pz.y)};
        float wn[2] = {bf2f(pn.x), bf2f(pn.y)};
        #pragma unroll
        for (int i = 0; i < 4; ++i){
          #pragma unroll
          for (int jj = 0; jj < 2; ++jj){
            ar[i][jj] += hv[i]*wr[jj];
            az[i][jj] += hv[i]*wz[jj];
            ah[i][jj] += hv[i]*wn[jj];
          }
        }
      }
    }
    __syncthreads();
    #pragma unroll
    for (int i = 0; i < 4; ++i){
      int r = rg4 + i;
      #pragma unroll
      for (int jj = 0; jj < 2; ++jj){
        float rr = sigm(ar[i][jj]);
        float zz = sigm(az[i][jj]);
        float nn = tanh_f(ai[i][jj] + rr*ah[i][jj]);
        float hv = hb[r][j0+jj];
        hb[r][j0+jj] = (1.f-zz)*nn + zz*hv;
      }
    }
    __syncthreads();
    {
      int r = tid >> 3, l = tid & 7;
      float vals[8];
      float s1 = 0.f, s2 = 0.f;
      #pragma unroll
      for (int q = 0; q < 8; ++q){ float v = hb[r][l + 8*q]; vals[q] = v; s1 += v; s2 += v*v; }
      #pragma unroll
      for (int off = 1; off <= 4; off <<= 1){ s1 += __shfl_xor(s1, off); s2 += __shfl_xor(s2, off); }
      float mu  = s1 * (1.f/64.f);
      float var = s2 * (1.f/64.f) - mu*mu;
      float rs  = rsqrtf(var + 1e-5f);
      int m = m0 + r;
      if (m < Mn){
        __hip_bfloat16* op = xbt + ((size_t)t*Mn + m)*Hh;
        #pragma unroll
        for (int q = 0; q < 8; ++q){ int j = l + 8*q; op[j] = f2bf((vals[q]-mu)*rs*sc[j] + bs[j]); }
      }
    }
    __syncthreads();
  }
}

// ---------------------------------------------------------------- fused power iteration: all 76 rounds in ONE kernel.
// 252 blocks, 120KB LDS -> 1 block/CU -> all co-resident.
// NO cache-wide fences (the R1 __threadfence emitted buffer_wbl2/inv -> evicted
// the read-only col16/rp from L2 every round = the 2.4ms regression).
// Cross-XCD coherence handled ONLY for the data that needs it (u, nrm2, dotb,
// bar) via relaxed agent-scope (sc1) atomics served by the coherent L3.
// col16/rp stay plain cached loads -> L2-resident across all 76 rounds.
// Per-row math is bit-identical to the validated multi-launch version.
__global__ __launch_bounds__(1024) void k_pitall(const int* __restrict__ rp,
    const unsigned short* __restrict__ col, float* __restrict__ uA, float* __restrict__ uB,
    float* __restrict__ nrm2, float* __restrict__ dotb, float* __restrict__ lamc,
    int* __restrict__ bar)
{
  __shared__ alignas(16) float u_s[Mn];     // 120000 B
  __shared__ float redw[16];
  __shared__ float s_nrm;
  const int b = blockIdx.x;                 // Tt*CHK = 252
  const int t = b / CHK, ch = b - t*CHK;
  const int r0 = ch*RC;
  const int r1 = (r0 + RC < Mn) ? r0 + RC : Mn;
  const int tid = threadIdx.x;
  const unsigned short* cp = col + (size_t)t*Ee;
  // cache row ranges in registers once (each thread owns <=2 rows)
  const int m0r = r0 + tid;
  const int m1r = m0r + 1024;
  int rb0 = 0, re0 = 0, rb1 = 0, re1 = 0;
  {
    const int* rpt = rp + t*(Mn+1);
    if (m0r < r1){ rb0 = rpt[m0r]; re0 = rpt[m0r+1]; }
    if (m1r < r1){ rb1 = rpt[m1r]; re1 = rpt[m1r+1]; }
  }
  if (tid == 0) s_nrm = 1.0f;               // nrm2 round-0 seed (k_init wrote 1.0)
  for (int r = 1; r <= NRND; ++r){
    float* uinp  = ((r-1) & 1) ? uB : uA;
    float* uoutp = (r & 1)     ? uB : uA;
    const int fin = (r == NRND);
    // stage full u_t via agent-scope (sc1) 8B loads: coherent from L3, no fence
    const unsigned long long* up = (const unsigned long long*)(uinp + t*Mn);
    for (int i = tid; i < Mn/2; i += 1024)
      ((unsigned long long*)u_s)[i] = aload_u64(up + i);
    __syncthreads();                         // staging + s_nrm visible
    const float inv_s = fin ? 1.f : 1.f/(sqrtf(s_nrm) + 1e-12f);
    float local = 0.f;
    if (m0r < r1){
      float s = 0.f;
      int i = rb0;
      for (; i < re0 && (i & 3); ++i) s += u_s[cp[i]];
      for (; i + 4 <= re0; i += 4){
        ushort4 c4 = *(const ushort4*)(cp + i);
        s += (u_s[c4.x] + u_s[c4.y]) + (u_s[c4.z] + u_s[c4.w]);
      }
      for (; i < re0; ++i) s += u_s[cp[i]];
      float uv = u_s[m0r];
      float wv = (float)(re0 - rb0)*uv - s;
      if (!fin){ float o = inv_s*wv; astore_f(&uoutp[t*Mn + m0r], o); local += o*o; }
      else local += uv*wv;
    }
    if (m1r < r1){
      float s = 0.f;
      int i = rb1;
      for (; i < re1 && (i & 3); ++i) s += u_s[cp[i]];
      for (; i + 4 <= re1; i += 4){
        ushort4 c4 = *(const ushort4*)(cp + i);
        s += (u_s[c4.x] + u_s[c4.y]) + (u_s[c4.z] + u_s[c4.w]);
      }
      for (; i < re1; ++i) s += u_s[cp[i]];
      float uv = u_s[m1r];
      float wv = (float)(re1 - rb1)*uv - s;
      if (!fin){ float o = inv_s*wv; astore_f(&uoutp[t*Mn + m1r], o); local += o*o; }
      else local += uv*wv;
    }
    #pragma unroll
    for (int o2 = 1; o2 < 64; o2 <<= 1) local += __shfl_xor(local, o2);
    if ((tid & 63) == 0) redw[tid >> 6] = local;
    asm volatile("s_waitcnt vmcnt(0)" ::: "memory");  // own sc1 u-stores acked at L3
    __syncthreads();                                  // all threads' stores drained
    if (tid == 0){
      float tot = 0.f;
      #pragma unroll
      for (int q = 0; q < 16; ++q) tot += redw[q];
      atomicAdd(fin ? &dotb[t] : &nrm2[r*Tt + t], tot);
      asm volatile("s_waitcnt vmcnt(0)" ::: "memory"); // RMW acked before arrive
      __hip_atomic_fetch_add(&bar[t], 1, __ATOMIC_RELAXED, __HIP_MEMORY_SCOPE_AGENT);
      const int target = CHK*r;
      while (aload_i(&bar[t]) < target) __builtin_amdgcn_s_sleep(8);
      if (!fin) s_nrm = aload_f(&nrm2[r*Tt + t]);     // broadcast next round's norm
    }
    __syncthreads();
  }
  // folded k_lamfin: one block per t (after barrier 76: all contributions at L3)
  if (ch == 0 && tid == 0){
    float nn = sqrtf(aload_f(&nrm2[75*Tt + t])) + 1e-12f;
    float lam = aload_f(&dotb[t]) / (nn*nn);
    lamc[2*t+0] = -2.f/lam;
    lamc[2*t+1] =  2.f/lam - 1.f;
  }
}

// ---------------------------------------------------------------- Chebyshev SpMM (wave per row, lane = channel, XCD-swizzled)
__global__ __launch_bounds__(256) void k_cheb(const __hip_bfloat16* __restrict__ xin,
    const __hip_bfloat16* __restrict__ xb0, __hip_bfloat16* __restrict__ outp,
    const int* __restrict__ rp, const unsigned short* __restrict__ col,
    const float* __restrict__ dinv, const float* __restrict__ lamc, float s1, float s2)
{
  const int blk = blockIdx.x;               // 90000 = 8*11250
  const int w = (blk & 7)*11250 + (blk >> 3);
  const int gw = w*4 + (threadIdx.x >> 6);
  const int lane = threadIdx.x & 63;
  int t = gw / Mn, m = gw - t*Mn;
  float coef = lamc[2*t], diag = lamc[2*t+1];
  const __hip_bfloat16* xt = xin + (size_t)t*Mn*Hh;
  const float* dv = dinv + t*Mn;
  float acc = diag * bf2f(xt[(size_t)m*Hh + lane]);
  float cdm = coef * dv[m];
  int bgn = rp[t*(Mn+1)+m], end = rp[t*(Mn+1)+m+1];
  const unsigned short* cp = col + (size_t)t*Ee;
  int i = bgn;
  for (; i < end && (i & 3); ++i){ int c = cp[i]; acc += (cdm*dv[c])*bf2f(xt[(size_t)c*Hh + lane]); }
  for (; i + 4 <= end; i += 4){
    ushort4 c4 = *(const ushort4*)(cp + i);
    float w0 = cdm*dv[c4.x], w1 = cdm*dv[c4.y], w2 = cdm*dv[c4.z], w3 = cdm*dv[c4.w];
    acc += w0*bf2f(xt[(size_t)c4.x*Hh + lane]);
    acc += w1*bf2f(xt[(size_t)c4.y*Hh + lane]);
    acc += w2*bf2f(xt[(size_t)c4.z*Hh + lane]);
    acc += w3*bf2f(xt[(size_t)c4.w*Hh + lane]);
  }
  for (; i < end; ++i){ int c = cp[i]; acc += (cdm*dv[c])*bf2f(xt[(size_t)c*Hh + lane]); }
  float o = s1*acc;
  if (s2 != 0.f) o += s2*bf2f(xb0[(size_t)gw*Hh + lane]);
  outp[(size_t)gw*Hh + lane] = f2bf(o);
}

// ---------------------------------------------------------------- fold cheb_W into conv_W
__global__ void k_ww(const float* __restrict__ chebW, const float* __restrict__ chebb,
    const float* __restrict__ convW, const float* __restrict__ convb, float* __restrict__ WW, float* __restrict__ c0)
{
  int idx = blockIdx.x*256 + threadIdx.x;
  if (idx < 3*Tt*Hh*Oo){
    int oc = idx % Oo; int j = (idx/Oo) % Hh; int t = (idx/(Oo*Hh)) % Tt; int i = idx/(Oo*Hh*Tt);
    const float* cw = chebW + ((size_t)i*Hh + j)*HC + (HC-KW);
    const float* vw = convW + ((size_t)oc*Tt + t)*KW;
    float s = 0.f;
    for (int k = 0; k < KW; ++k) s += cw[k]*vw[k];
    WW[idx] = s;
  }
  if (blockIdx.x == 0 && threadIdx.x < Oo){
    int oc = threadIdx.x;
    float s = convb[oc];
    for (int t = 0; t < Tt; ++t){
      const float* vw = convW + ((size_t)oc*Tt + t)*KW;
      for (int k = 0; k < KW; ++k) s += chebb[(HC-KW)+k]*vw[k];
    }
    c0[oc] = s;
  }
}

// ---------------------------------------------------------------- fused cheb-GEMM + temporal conv + sigmoid
__global__ __launch_bounds__(256) void k_final(const __hip_bfloat16* __restrict__ tx0,
    const __hip_bfloat16* __restrict__ tx1, const __hip_bfloat16* __restrict__ tx2,
    const float* __restrict__ WW, const float* __restrict__ c0, float* __restrict__ outp)
{
  __shared__ float xs[64][65];
  __shared__ float ww[64][12];
  const int tid = threadIdx.x;
  const int n0 = blockIdx.x*64;
  const int n = tid & 63, ob = (tid >> 6)*3;
  float acc[3] = {0.f, 0.f, 0.f};
  for (int it = 0; it < 3*Tt; ++it){
    int ii = it / Tt, t = it % Tt;
    const __hip_bfloat16* tx = (ii == 0) ? tx0 : (ii == 1) ? tx1 : tx2;
    __syncthreads();
    for (int idx = tid; idx < 64*64; idx += 256){
      int mm = idx >> 6, j = idx & 63;
      int m = n0 + mm;
      xs[mm][j] = (m < Mn) ? bf2f(tx[((size_t)t*Mn + m)*Hh + j]) : 0.f;
    }
    for (int idx = tid; idx < 64*Oo; idx += 256)
      ((float*)ww)[idx] = WW[((size_t)(ii*Tt + t)*Hh)*Oo + idx];
    __syncthreads();
    #pragma unroll 8
    for (int j = 0; j < 64; ++j){
      float x = xs[n][j];
      acc[0] += x*ww[j][ob+0];
      acc[1] += x*ww[j][ob+1];
      acc[2] += x*ww[j][ob+2];
    }
  }
  int m = n0 + n;
  if (m < Mn){
    #pragma unroll
    for (int q = 0; q < 3; ++q) outp[(size_t)m*Oo + ob + q] = sigm(acc[q] + c0[ob+q]);
  }
}

// ================================================================ host
extern "C" void kernel_launch(void* const* d_in, const int* in_sizes, int n_in,
                              void* d_out, int out_size, void* d_ws, size_t ws_size,
                              hipStream_t stream)
{
  const float* nf    = (const float*)d_in[0];
  const int*   ei    = (const int*)d_in[1];
  const float* Wih0  = (const float*)d_in[2];
  const float* Whh0  = (const float*)d_in[3];
  const float* bih0  = (const float*)d_in[4];
  const float* bhh0  = (const float*)d_in[5];
  const float* Wih1  = (const float*)d_in[6];
  const float* Whh1  = (const float*)d_in[7];
  const float* bih1  = (const float*)d_in[8];
  const float* bhh1  = (const float*)d_in[9];
  const float* lns   = (const float*)d_in[10];
  const float* lnb   = (const float*)d_in[11];
  const float* chebW = (const float*)d_in[12];
  const float* chebb = (const float*)d_in[13];
  const float* convW = (const float*)d_in[14];
  const float* convb = (const float*)d_in[15];
  float* outp = (float*)d_out;

  char* base = (char*)d_ws;
  size_t off = 0;
  auto alloc = [&](size_t bytes)->char*{ char* p = base + off; off += (bytes + 255) & ~(size_t)255; return p; };

  __hip_bfloat16* y0  = (__hip_bfloat16*)alloc((size_t)Tt*Mn*C2*2);
  __hip_bfloat16* tx1 = y0;
  __hip_bfloat16* tx2 = y0 + (size_t)Tt*Mn*Hh;
  __hip_bfloat16* gi  = (__hip_bfloat16*)alloc((size_t)Tt*Mn*Gg*2);
  unsigned* pair = (unsigned*)gi;          // overlaps gi: pair dead before k_gi1m writes gi
  __hip_bfloat16* xbt = (__hip_bfloat16*)alloc((size_t)Tt*Mn*Hh*2);
  unsigned short* col16 = (unsigned short*)alloc((size_t)Tt*Ee*2);
  int*   deg  = (int*)alloc((size_t)Tt*Mn*4);
  int*   rp   = (int*)alloc((size_t)Tt*(Mn+1)*4);
  int*   bcnt = (int*)alloc((size_t)Tt*NB*4);
  int*   bfill= (int*)alloc((size_t)Tt*NB*4);
  int*   rpb  = (int*)alloc((size_t)Tt*(NB+1)*4);
  float* uA   = (float*)alloc((size_t)Tt*Mn*4);
  float* uB   = (float*)alloc((size_t)Tt*Mn*4);
  float* dinv = (float*)alloc((size_t)Tt*Mn*4);
  float* nrm2 = (float*)alloc((size_t)76*Tt*4);
  float* dotb = (float*)alloc((size_t)Tt*4);
  float* lamc = (float*)alloc((size_t)2*Tt*4);
  float* WW   = (float*)alloc((size_t)3*Tt*Hh*Oo*4);
  float* c0   = (float*)alloc((size_t)Oo*4);
  __hip_bfloat16* Wbf = (__hip_bfloat16*)alloc((size_t)Gg*C2*2);
  int*   bar  = (int*)alloc((size_t)Tt*4);
  (void)ws_size; (void)in_sizes; (void)n_in; (void)out_size;

  // CSR build: bucket histogram -> bucket scan -> partition -> per-bucket counting sort (emits rp+deg)
  k_init<<<(Tt*Mn + 255)/256, 256, 0, stream>>>(nrm2, dotb, uA, bcnt, bfill, bar);
  k_bcnt<<<Tt*BPT, 256, 0, stream>>>(ei, bcnt);
  k_bscan<<<Tt, 256, 0, stream>>>(bcnt, rpb);
  k_part2<<<Tt*BPT, 256, 0, stream>>>(ei, rpb, bfill, pair);
  k_csr2<<<Tt*NB, 256, 0, stream>>>(rpb, pair, col16, rp, deg);
  k_dinv<<<(Tt*Mn + 255)/256, 256, 0, stream>>>(deg, dinv);

  // GRU stack (layer-1 forward direction is dead code -> skipped)
  k_wcvt<<<(Gg*C2 + 255)/256, 256, 0, stream>>>(Wih1 + (size_t)Gg*C2, Wbf);
  k_gru0<<<(Mn + 31)/32, 256, 0, stream>>>(nf, Wih0, Whh0, bih0, bhh0, y0);
  {
    int waves = Tt*((Mn + 31)/32);
    k_gi1m<<<(waves + 3)/4, 256, 0, stream>>>(y0, Wbf, bih1 + Gg, gi);
  }
  k_gru1r<<<(Mn + 31)/32, 256, 0, stream>>>(gi, Whh1 + (size_t)Gg*Hh, bhh1 + Gg, lns, lnb, xbt);

  // power iteration: 75 rounds + 1 Rayleigh round, fused into ONE kernel with
  // per-t device barriers (relaxed sc1 coherence, NO cache-wide fences)
  k_pitall<<<Tt*CHK, 1024, 0, stream>>>(rp, col16, uA, uB, nrm2, dotb, lamc, bar);

  // Chebyshev: tx1 = Lhat(x), tx2 = 2*Lhat(tx1) - x
  k_cheb<<<(Tt*Mn)/4, 256, 0, stream>>>(xbt, xbt, tx1, rp, col16, dinv, lamc, 1.f, 0.f);
  k_cheb<<<(Tt*Mn)/4, 256, 0, stream>>>(tx1, xbt, tx2, rp, col16, dinv, lamc, 2.f, -1.f);

  // folded cheb-GEMM + conv + sigmoid
  k_ww<<<(3*Tt*Hh*Oo + 255)/256, 256, 0, stream>>>(chebW, chebb, convW, convb, WW, c0);
  k_final<<<(Mn + 63)/64, 256, 0, stream>>>(xbt, tx1, tx2, WW, c0, outp);
}

// Round 3
// 3204.414 us; speedup vs baseline: 1.3604x; 1.2348x over previous
//
#include <hip/hip_runtime.h>
#include <hip/hip_bf16.h>

#define DEV __device__ __forceinline__

constexpr int Mn  = 30000;   // nodes (B=1)
constexpr int Tt  = 12;
constexpr int CIN = 16;
constexpr int Hh  = 64;
constexpr int Gg  = 192;     // 3H
constexpr int C2  = 128;     // 2H
constexpr int Ee  = 960000;  // edges per timestep (bidirectional)
constexpr int HC  = 128;
constexpr int Oo  = 12;
constexpr int KW  = 128;
constexpr int HP  = 72;      // padded h row stride (floats)
constexpr int WP  = 194;     // padded weight row stride (bf16): bank stride 97 (odd) -> conflict-free
constexpr int XSP = 36;      // padded xs inner stride (floats): 16B-aligned, 2-way max
constexpr int NB  = 235;     // 128-row buckets per t (235*128 >= 30000)
constexpr int EPB = 8192;    // edges per block for bcnt/part2
constexpr int BPT = 118;     // ceil(Ee/EPB)
constexpr int CHK = 21;      // chunks per t for power iteration (252 blocks total)
constexpr int RC  = 1429;    // rows per chunk (21*1429 >= 30000)
constexpr int NRND= 76;      // 75 power rounds + 1 Rayleigh round

DEV float bf2f(__hip_bfloat16 v){ return __bfloat162float(v); }
DEV __hip_bfloat16 f2bf(float v){ return __float2bfloat16(v); }
DEV float sigm(float x){ return __builtin_amdgcn_rcpf(1.f + __expf(-x)); }
DEV float tanh_f(float x){ return 1.f - 2.f*__builtin_amdgcn_rcpf(__expf(2.f*x) + 1.f); }

// agent-scope (device-coherent, sc1) accessors: bypass stale local caches,
// served by the die-level coherence point. No cache-wide wb/inv fences.
DEV float aload_f(const float* p){ return __hip_atomic_load(p, __ATOMIC_RELAXED, __HIP_MEMORY_SCOPE_AGENT); }
DEV void  astore_f(float* p, float v){ __hip_atomic_store(p, v, __ATOMIC_RELAXED, __HIP_MEMORY_SCOPE_AGENT); }
DEV unsigned long long aload_u64(const unsigned long long* p){ return __hip_atomic_load(p, __ATOMIC_RELAXED, __HIP_MEMORY_SCOPE_AGENT); }
DEV int   aload_i(const int* p){ return __hip_atomic_load(p, __ATOMIC_RELAXED, __HIP_MEMORY_SCOPE_AGENT); }
DEV void  astore_i(int* p, int v){ __hip_atomic_store(p, v, __ATOMIC_RELAXED, __HIP_MEMORY_SCOPE_AGENT); }

typedef short bfrag8 __attribute__((ext_vector_type(8)));
typedef float ffrag4 __attribute__((ext_vector_type(4)));

// ---------------------------------------------------------------- init
__global__ void k_init(float* u0, int* bcnt, int* bfill, int* flag){
  int i = blockIdx.x*256 + threadIdx.x;
  if (i < Tt*Mn) u0[i] = 0.005773502691896258f;    // 1/sqrt(30000)
  if (i < Tt*CHK*16) flag[i] = 0;
  if (i < Tt*NB){ bcnt[i] = 0; bfill[i] = 0; }
}

// ---------------------------------------------------------------- stage 1: block-aggregated bucket histogram
__global__ __launch_bounds__(256) void k_bcnt(const int* __restrict__ ei, int* __restrict__ bcnt){
  __shared__ int h[NB];
  const int b = blockIdx.x;                 // 1416 = 8*177
  const int w = (b & 7)*177 + (b >> 3);
  const int t = w / BPT, ch = w - t*BPT;
  const int e0 = ch*EPB;
  const int tid = threadIdx.x;
  for (int i = tid; i < NB; i += 256) h[i] = 0;
  __syncthreads();
  #pragma unroll
  for (int i = 0; i < 32; ++i){
    int e = e0 + i*256 + tid;
    if (e < Ee){
      int r = ei[(size_t)(t*2)*Ee + e];
      atomicAdd(&h[r >> 7], 1);
    }
  }
  __syncthreads();
  for (int i = tid; i < NB; i += 256){
    int c = h[i];
    if (c > 0) atomicAdd(&bcnt[t*NB + i], c);
  }
}

// ---------------------------------------------------------------- stage 2: per-t exclusive scan of bucket counts
__global__ __launch_bounds__(256) void k_bscan(const int* __restrict__ bcnt, int* __restrict__ rpb){
  int t = blockIdx.x, tid = threadIdx.x;
  __shared__ int ps[256];
  int v = (tid < NB) ? bcnt[t*NB + tid] : 0;
  ps[tid] = v;
  __syncthreads();
  for (int o = 1; o < 256; o <<= 1){
    int x = (tid >= o) ? ps[tid-o] : 0;
    __syncthreads();
    ps[tid] += x;
    __syncthreads();
  }
  if (tid < NB) rpb[t*(NB+1) + tid] = ps[tid] - v;
  if (tid == 255) rpb[t*(NB+1) + NB] = ps[NB-1];
}

// ---------------------------------------------------------------- stage 3: partition edges into buckets (block-aggregated reservations)
__global__ __launch_bounds__(256) void k_part2(const int* __restrict__ ei, const int* __restrict__ rpb,
    int* __restrict__ bfill, unsigned* __restrict__ pair){
  __shared__ int hcnt[NB];
  __shared__ int hbase[NB];
  const int b = blockIdx.x;                 // 1416 = 8*177
  const int w = (b & 7)*177 + (b >> 3);
  const int t = w / BPT, ch = w - t*BPT;
  const int e0 = ch*EPB;
  const int tid = threadIdx.x;
  for (int i = tid; i < NB; i += 256) hcnt[i] = 0;
  __syncthreads();
  unsigned key[32];
  #pragma unroll
  for (int i = 0; i < 32; ++i){
    int e = e0 + i*256 + tid;
    unsigned k = 0xFFFFFFFFu;
    if (e < Ee){
      int r = ei[(size_t)(t*2)*Ee + e];
      int c = ei[(size_t)(t*2+1)*Ee + e];
      k = ((unsigned)r << 16) | (unsigned)c;
      atomicAdd(&hcnt[r >> 7], 1);
    }
    key[i] = k;
  }
  __syncthreads();
  for (int i = tid; i < NB; i += 256){
    int cnt = hcnt[i];
    int base = (cnt > 0) ? atomicAdd(&bfill[t*NB + i], cnt) : 0;
    hbase[i] = rpb[t*(NB+1) + i] + base;
  }
  __syncthreads();
  for (int i = tid; i < NB; i += 256) hcnt[i] = 0;
  __syncthreads();
  #pragma unroll
  for (int i = 0; i < 32; ++i){
    unsigned k = key[i];
    if (k != 0xFFFFFFFFu){
      int r = (int)(k >> 16);
      int bk = r >> 7;
      int pos = atomicAdd(&hcnt[bk], 1);
      pair[(size_t)t*Ee + hbase[bk] + pos] = ((unsigned)(r & 127) << 16) | (k & 0xFFFFu);
    }
  }
}

// ---------------------------------------------------------------- stage 4: per-bucket LDS counting sort -> col16, rp, deg
__global__ __launch_bounds__(256) void k_csr2(const int* __restrict__ rpb, const unsigned* __restrict__ pair,
    unsigned short* __restrict__ col16, int* __restrict__ rp, int* __restrict__ deg){
  __shared__ unsigned short cols_s[9216];
  __shared__ int lcnt[128], lfill[128];
  __shared__ int ps[256];
  const int blk = blockIdx.x;               // Tt*NB
  const int t = blk / NB, bk = blk - t*NB;
  const int r0 = bk << 7;
  const int nr = (r0 + 128 <= Mn) ? 128 : (Mn - r0);
  const int base = rpb[t*(NB+1) + bk];
  const int cnt  = rpb[t*(NB+1) + bk + 1] - base;
  const int tid = threadIdx.x;
  if (tid < 128) lcnt[tid] = 0;
  __syncthreads();
  for (int i = tid; i < cnt; i += 256){
    unsigned v = pair[(size_t)t*Ee + base + i];
    atomicAdd(&lcnt[v >> 16], 1);
  }
  __syncthreads();
  int v2 = (tid < 128) ? lcnt[tid] : 0;
  ps[tid] = v2;
  __syncthreads();
  for (int o = 1; o < 128; o <<= 1){
    int x = (tid >= o) ? ps[tid-o] : 0;
    __syncthreads();
    ps[tid] += x;
    __syncthreads();
  }
  if (tid < 128){
    int excl = ps[tid] - v2;
    lfill[tid] = excl;
    if (tid < nr){
      rp[t*(Mn+1) + r0 + tid] = base + excl;
      deg[t*Mn + r0 + tid] = v2;
    }
  }
  if (bk == NB-1 && tid == 0) rp[t*(Mn+1) + Mn] = base + cnt;
  __syncthreads();
  for (int i = tid; i < cnt; i += 256){
    unsigned v = pair[(size_t)t*Ee + base + i];
    int pos = atomicAdd(&lfill[v >> 16], 1);
    cols_s[pos] = (unsigned short)(v & 0xFFFFu);
  }
  __syncthreads();
  for (int i = tid; i < cnt; i += 256)
    col16[(size_t)t*Ee + base + i] = cols_s[i];
}

// ---------------------------------------------------------------- dinv
__global__ void k_dinv(const int* __restrict__ deg, float* __restrict__ dinv){
  int i = blockIdx.x*256 + threadIdx.x;
  if (i < Tt*Mn){ int d = deg[i]; dinv[i] = (d > 0) ? rsqrtf((float)d) : 0.f; }
}

// ---------------------------------------------------------------- GRU layer 0 (both dirs), writes y0 (T,M,128) bf16
__global__ __launch_bounds__(256) void k_gru0(
    const float* __restrict__ nf, const float* __restrict__ Wih, const float* __restrict__ Whh,
    const float* __restrict__ bih, const float* __restrict__ bhh, __hip_bfloat16* __restrict__ y0)
{
  __shared__ float xs[Tt][CIN][XSP];
  __shared__ __hip_bfloat16 wi[CIN][WP];
  __shared__ __hip_bfloat16 wh[Hh][WP];
  __shared__ float hb[32][HP];
  __shared__ float bi[Gg], bh[Gg];
  const int tid = threadIdx.x;
  const int m0  = blockIdx.x*32;
  for (int idx = tid; idx < Tt*32*CIN; idx += 256){
    int t = idx / (32*CIN); int rr = (idx / CIN) & 31; int k = idx & (CIN-1);
    int m = m0 + rr;
    xs[t][k][rr] = (m < Mn) ? nf[((size_t)t*Mn + m)*CIN + k] : 0.f;
  }
  const int jg = tid & 31, rg = tid >> 5;
  const int j0 = jg*2, rg4 = rg*4;
  for (int d = 0; d < 2; ++d){
    __syncthreads();
    for (int idx = tid; idx < Gg*CIN; idx += 256){
      int g = idx / CIN, k = idx & (CIN-1);
      wi[k][g] = f2bf(Wih[((size_t)d*Gg + g)*CIN + k]);
    }
    for (int idx = tid; idx < Gg*Hh; idx += 256){
      int g = idx >> 6, k = idx & 63;
      wh[k][g] = f2bf(Whh[((size_t)d*Gg + g)*Hh + k]);
    }
    if (tid < Gg){ bi[tid] = bih[d*Gg + tid]; bh[tid] = bhh[d*Gg + tid]; }
    for (int idx = tid; idx < 32*HP; idx += 256) ((float*)hb)[idx] = 0.f;
    __syncthreads();
    for (int step = 0; step < Tt; ++step){
      int t = d ? (Tt-1-step) : step;
      float ar[4][2], az[4][2], ai[4][2], ah[4][2];
      #pragma unroll
      for (int i = 0; i < 4; ++i){
        #pragma unroll
        for (int jj = 0; jj < 2; ++jj){
          int j = j0 + jj;
          ar[i][jj] = bi[j] + bh[j];
          az[i][jj] = bi[Hh+j] + bh[Hh+j];
          ai[i][jj] = bi[2*Hh+j];
          ah[i][jj] = bh[2*Hh+j];
        }
      }
      #pragma unroll
      for (int k = 0; k < CIN; ++k){
        float4 xv4 = *(const float4*)&xs[t][k][rg4];
        float xv[4] = {xv4.x, xv4.y, xv4.z, xv4.w};
        __hip_bfloat162 pr = *(const __hip_bfloat162*)&wi[k][j0];
        __hip_bfloat162 pz = *(const __hip_bfloat162*)&wi[k][Hh+j0];
        __hip_bfloat162 pn = *(const __hip_bfloat162*)&wi[k][2*Hh+j0];
        float wr[2] = {bf2f(pr.x), bf2f(pr.y)};
        float wz[2] = {bf2f(pz.x), bf2f(pz.y)};
        float wn[2] = {bf2f(pn.x), bf2f(pn.y)};
        #pragma unroll
        for (int i = 0; i < 4; ++i){
          #pragma unroll
          for (int jj = 0; jj < 2; ++jj){
            ar[i][jj] += xv[i]*wr[jj];
            az[i][jj] += xv[i]*wz[jj];
            ai[i][jj] += xv[i]*wn[jj];
          }
        }
      }
      #pragma unroll 4
      for (int k4 = 0; k4 < 16; ++k4){
        float4 h0 = *(const float4*)&hb[rg4+0][k4*4];
        float4 h1 = *(const float4*)&hb[rg4+1][k4*4];
        float4 h2 = *(const float4*)&hb[rg4+2][k4*4];
        float4 h3 = *(const float4*)&hb[rg4+3][k4*4];
        #pragma unroll
        for (int kk = 0; kk < 4; ++kk){
          int k = k4*4 + kk;
          float hv[4] = { ((const float*)&h0)[kk], ((const float*)&h1)[kk],
                          ((const float*)&h2)[kk], ((const float*)&h3)[kk] };
          __hip_bfloat162 pr = *(const __hip_bfloat162*)&wh[k][j0];
          __hip_bfloat162 pz = *(const __hip_bfloat162*)&wh[k][Hh+j0];
          __hip_bfloat162 pn = *(const __hip_bfloat162*)&wh[k][2*Hh+j0];
          float wr[2] = {bf2f(pr.x), bf2f(pr.y)};
          float wz[2] = {bf2f(pz.x), bf2f(pz.y)};
          float wn[2] = {bf2f(pn.x), bf2f(pn.y)};
          #pragma unroll
          for (int i = 0; i < 4; ++i){
            #pragma unroll
            for (int jj = 0; jj < 2; ++jj){
              ar[i][jj] += hv[i]*wr[jj];
              az[i][jj] += hv[i]*wz[jj];
              ah[i][jj] += hv[i]*wn[jj];
            }
          }
        }
      }
      __syncthreads();
      #pragma unroll
      for (int i = 0; i < 4; ++i){
        int r = rg4 + i; int m = m0 + r;
        float hn2[2];
        #pragma unroll
        for (int jj = 0; jj < 2; ++jj){
          float rr = sigm(ar[i][jj]);
          float zz = sigm(az[i][jj]);
          float nn = tanh_f(ai[i][jj] + rr*ah[i][jj]);
          float hv = hb[r][j0+jj];
          hn2[jj] = (1.f-zz)*nn + zz*hv;
          hb[r][j0+jj] = hn2[jj];
        }
        if (m < Mn){
          __hip_bfloat162 pk; pk.x = f2bf(hn2[0]); pk.y = f2bf(hn2[1]);
          *(__hip_bfloat162*)&y0[((size_t)t*Mn + m)*C2 + d*Hh + j0] = pk;
        }
      }
      __syncthreads();
    }
  }
}

// ---------------------------------------------------------------- convert layer-1 reverse weights to bf16
__global__ void k_wcvt(const float* __restrict__ W, __hip_bfloat16* __restrict__ Wbf){
  int i = blockIdx.x*256 + threadIdx.x;
  if (i < Gg*C2) Wbf[i] = f2bf(W[i]);
}

// ---------------------------------------------------------------- layer-1 input projection via MFMA
__global__ __launch_bounds__(256) void k_gi1m(const __hip_bfloat16* __restrict__ y0,
    const __hip_bfloat16* __restrict__ Wbf, const float* __restrict__ bih, __hip_bfloat16* __restrict__ gi)
{
  const int wid  = (blockIdx.x*256 + threadIdx.x) >> 6;
  const int lane = threadIdx.x & 63;
  const int SEGS = (Mn + 31)/32;
  if (wid >= Tt*SEGS) return;
  const int t = wid / SEGS, seg = wid - t*SEGS;
  const int m0 = seg*32;
  const int lr = lane & 15, lq = lane >> 4;
  const __hip_bfloat16* yb = y0 + (size_t)t*Mn*C2;

  ffrag4 acc[2][12];
  #pragma unroll
  for (int i = 0; i < 2; ++i){
    #pragma unroll
    for (int n = 0; n < 12; ++n) acc[i][n] = (ffrag4){0.f,0.f,0.f,0.f};
  }
  #pragma unroll
  for (int ks = 0; ks < 4; ++ks){
    const int ko = ks*32 + lq*8;
    bfrag8 a0 = *(const bfrag8*)(yb + (size_t)(m0 + lr     )*C2 + ko);
    bfrag8 a1 = *(const bfrag8*)(yb + (size_t)(m0 + 16 + lr)*C2 + ko);
    #pragma unroll
    for (int nt = 0; nt < 12; ++nt){
      bfrag8 b = *(const bfrag8*)(Wbf + (size_t)(nt*16 + lr)*C2 + ko);
      acc[0][nt] = __builtin_amdgcn_mfma_f32_16x16x32_bf16(a0, b, acc[0][nt], 0, 0, 0);
      acc[1][nt] = __builtin_amdgcn_mfma_f32_16x16x32_bf16(a1, b, acc[1][nt], 0, 0, 0);
    }
  }
  #pragma unroll
  for (int nt = 0; nt < 12; ++nt){
    int g = nt*16 + lr;
    float bb = bih[g];
    #pragma unroll
    for (int r = 0; r < 4; ++r){
      int mm0 = m0 + lq*4 + r;
      int mm1 = mm0 + 16;
      if (mm0 < Mn) gi[((size_t)t*Mn + mm0)*Gg + g] = f2bf(acc[0][nt][r] + bb);
      if (mm1 < Mn) gi[((size_t)t*Mn + mm1)*Gg + g] = f2bf(acc[1][nt][r] + bb);
    }
  }
}

// ---------------------------------------------------------------- GRU layer 1 (reverse only) + fused LayerNorm
__global__ __launch_bounds__(256) void k_gru1r(const __hip_bfloat16* __restrict__ gi,
    const float* __restrict__ Whh, const float* __restrict__ bhh,
    const float* __restrict__ lns, const float* __restrict__ lnb,
    __hip_bfloat16* __restrict__ xbt)
{
  __shared__ __hip_bfloat16 wh[Hh][WP];
  __shared__ float hb[32][HP];
  __shared__ float bh[Gg];
  __shared__ float sc[Hh], bs[Hh];
  const int tid = threadIdx.x;
  const int m0  = blockIdx.x*32;
  for (int idx = tid; idx < Gg*Hh; idx += 256){
    int g = idx >> 6, k = idx & 63;
    wh[k][g] = f2bf(Whh[(size_t)g*Hh + k]);
  }
  if (tid < Gg) bh[tid] = bhh[tid];
  if (tid < Hh){ sc[tid] = lns[tid]; bs[tid] = lnb[tid]; }
  for (int idx = tid; idx < 32*HP; idx += 256) ((float*)hb)[idx] = 0.f;
  __syncthreads();
  const int jg = tid & 31, rg = tid >> 5;
  const int j0 = jg*2, rg4 = rg*4;
  for (int step = 0; step < Tt; ++step){
    int t = Tt-1-step;
    float ar[4][2], az[4][2], ai[4][2], ah[4][2];
    #pragma unroll
    for (int i = 0; i < 4; ++i){
      int m = m0 + rg4 + i;
      int mc = (m < Mn) ? m : 0;
      const __hip_bfloat16* gp = gi + ((size_t)t*Mn + mc)*Gg;
      __hip_bfloat162 pr = *(const __hip_bfloat162*)&gp[j0];
      __hip_bfloat162 pz = *(const __hip_bfloat162*)&gp[Hh+j0];
      __hip_bfloat162 pn = *(const __hip_bfloat162*)&gp[2*Hh+j0];
      #pragma unroll
      for (int jj = 0; jj < 2; ++jj){
        int j = j0 + jj;
        float gr = jj ? bf2f(pr.y) : bf2f(pr.x);
        float gz = jj ? bf2f(pz.y) : bf2f(pz.x);
        float gn = jj ? bf2f(pn.y) : bf2f(pn.x);
        ar[i][jj] = gr + bh[j];
        az[i][jj] = gz + bh[Hh+j];
        ai[i][jj] = gn;
        ah[i][jj] = bh[2*Hh+j];
      }
    }
    #pragma unroll 4
    for (int k4 = 0; k4 < 16; ++k4){
      float4 h0 = *(const float4*)&hb[rg4+0][k4*4];
      float4 h1 = *(const float4*)&hb[rg4+1][k4*4];
      float4 h2 = *(const float4*)&hb[rg4+2][k4*4];
      float4 h3 = *(const float4*)&hb[rg4+3][k4*4];
      #pragma unroll
      for (int kk = 0; kk < 4; ++kk){
        int k = k4*4 + kk;
        float hv[4] = { ((const float*)&h0)[kk], ((const float*)&h1)[kk],
                        ((const float*)&h2)[kk], ((const float*)&h3)[kk] };
        __hip_bfloat162 pr = *(const __hip_bfloat162*)&wh[k][j0];
        __hip_bfloat162 pz = *(const __hip_bfloat162*)&wh[k][Hh+j0];
        __hip_bfloat162 pn = *(const __hip_bfloat162*)&wh[k][2*Hh+j0];
        float wr[2] = {bf2f(pr.x), bf2f(pr.y)};
        float wz[2] = {bf2f(pz.x), bf2f(pz.y)};
        float wn[2] = {bf2f(pn.x), bf2f(pn.y)};
        #pragma unroll
        for (int i = 0; i < 4; ++i){
          #pragma unroll
          for (int jj = 0; jj < 2; ++jj){
            ar[i][jj] += hv[i]*wr[jj];
            az[i][jj] += hv[i]*wz[jj];
            ah[i][jj] += hv[i]*wn[jj];
          }
        }
      }
    }
    __syncthreads();
    #pragma unroll
    for (int i = 0; i < 4; ++i){
      int r = rg4 + i;
      #pragma unroll
      for (int jj = 0; jj < 2; ++jj){
        float rr = sigm(ar[i][jj]);
        float zz = sigm(az[i][jj]);
        float nn = tanh_f(ai[i][jj] + rr*ah[i][jj]);
        float hv = hb[r][j0+jj];
        hb[r][j0+jj] = (1.f-zz)*nn + zz*hv;
      }
    }
    __syncthreads();
    {
      int r = tid >> 3, l = tid & 7;
      float vals[8];
      float s1 = 0.f, s2 = 0.f;
      #pragma unroll
      for (int q = 0; q < 8; ++q){ float v = hb[r][l + 8*q]; vals[q] = v; s1 += v; s2 += v*v; }
      #pragma unroll
      for (int off = 1; off <= 4; off <<= 1){ s1 += __shfl_xor(s1, off); s2 += __shfl_xor(s2, off); }
      float mu  = s1 * (1.f/64.f);
      float var = s2 * (1.f/64.f) - mu*mu;
      float rs  = rsqrtf(var + 1e-5f);
      int m = m0 + r;
      if (m < Mn){
        __hip_bfloat16* op = xbt + ((size_t)t*Mn + m)*Hh;
        #pragma unroll
        for (int q = 0; q < 8; ++q){ int j = l + 8*q; op[j] = f2bf((vals[q]-mu)*rs*sc[j] + bs[j]); }
      }
    }
    __syncthreads();
  }
}

// ---------------------------------------------------------------- fused power iteration: all 76 rounds in ONE kernel.
// 252 blocks, 120KB LDS -> 1 block/CU -> all co-resident.
// Sync redesign (R3): ZERO same-address RMW atomics. Each block stores its
// norm^2 partial to its OWN padded 64B slot (double-buffered by round parity)
// and then its OWN monotonic epoch flag. Every block's wave-0 polls all 21
// flags with a single gathered load, then gathers the 21 partials and
// butterfly-reduces locally (identical order in all blocks -> identical
// inv_s). u is TRIPLE-buffered so a fast block at round r+1 cannot overwrite
// the buffer a slow block still reads for round r (reuse at r+2 is gated by
// the flags of r+1). col16/rp stay plain cached loads (L2-hot all 76 rounds).
__global__ __launch_bounds__(1024) void k_pitall(const int* __restrict__ rp,
    const unsigned short* __restrict__ col,
    float* __restrict__ uA, float* __restrict__ uB, float* __restrict__ uC,
    float* __restrict__ part, int* __restrict__ flag, float* __restrict__ lamc)
{
  __shared__ alignas(16) float u_s[Mn];     // 120000 B
  __shared__ float redw[16];
  __shared__ float s_nrm, s_dot;
  const int b = blockIdx.x;                 // Tt*CHK = 252
  const int t = b / CHK, ch = b - t*CHK;
  const int r0 = ch*RC;
  const int r1 = (r0 + RC < Mn) ? r0 + RC : Mn;
  const int tid = threadIdx.x;
  const unsigned short* cp = col + (size_t)t*Ee;
  const int fbaseF = t*CHK*16;              // flag slots: 64B apart
  const int fbaseP = t*CHK*32;              // part slots: 2 parities x 64B per block
  // cache row ranges in registers once (each thread owns <=2 rows)
  const int m0r = r0 + tid;
  const int m1r = m0r + 1024;
  int rb0 = 0, re0 = 0, rb1 = 0, re1 = 0;
  {
    const int* rpt = rp + t*(Mn+1);
    if (m0r < r1){ rb0 = rpt[m0r]; re0 = rpt[m0r+1]; }
    if (m1r < r1){ rb1 = rpt[m1r]; re1 = rpt[m1r+1]; }
  }
  if (tid == 0){ s_nrm = 1.0f; s_dot = 0.f; }
  // triple-buffer rotation (register pointers, no runtime indexing)
  float* u_in = uA;  // read for round r
  float* u_ot = uB;  // written in round r
  float* u_nx = uC;  // spare (written in round r+1)
  for (int r = 1; r <= NRND; ++r){
    const int fin = (r == NRND);
    // stage full u_t via agent-scope (sc1) 8B loads
    const unsigned long long* up = (const unsigned long long*)(u_in + t*Mn);
    for (int i = tid; i < Mn/2; i += 1024)
      ((unsigned long long*)u_s)[i] = aload_u64(up + i);
    __syncthreads();                         // staging + s_nrm visible
    const float inv_s = fin ? 1.f : 1.f/(sqrtf(s_nrm) + 1e-12f);
    float local = 0.f;
    if (m0r < r1){
      float s = 0.f;
      int i = rb0;
      for (; i < re0 && (i & 3); ++i) s += u_s[cp[i]];
      for (; i + 4 <= re0; i += 4){
        ushort4 c4 = *(const ushort4*)(cp + i);
        s += (u_s[c4.x] + u_s[c4.y]) + (u_s[c4.z] + u_s[c4.w]);
      }
      for (; i < re0; ++i) s += u_s[cp[i]];
      float uv = u_s[m0r];
      float wv = (float)(re0 - rb0)*uv - s;
      if (!fin){ float o = inv_s*wv; astore_f(&u_ot[t*Mn + m0r], o); local += o*o; }
      else local += uv*wv;
    }
    if (m1r < r1){
      float s = 0.f;
      int i = rb1;
      for (; i < re1 && (i & 3); ++i) s += u_s[cp[i]];
      for (; i + 4 <= re1; i += 4){
        ushort4 c4 = *(const ushort4*)(cp + i);
        s += (u_s[c4.x] + u_s[c4.y]) + (u_s[c4.z] + u_s[c4.w]);
      }
      for (; i < re1; ++i) s += u_s[cp[i]];
      float uv = u_s[m1r];
      float wv = (float)(re1 - rb1)*uv - s;
      if (!fin){ float o = inv_s*wv; astore_f(&u_ot[t*Mn + m1r], o); local += o*o; }
      else local += uv*wv;
    }
    #pragma unroll
    for (int o2 = 1; o2 < 64; o2 <<= 1) local += __shfl_xor(local, o2);
    if ((tid & 63) == 0) redw[tid >> 6] = local;
    asm volatile("s_waitcnt vmcnt(0)" ::: "memory");  // each wave drains its own u-stores
    __syncthreads();                                  // all 16 waves drained + redw visible
    if (tid < 64){
      // finish block reduction in wave 0 (butterfly, deterministic)
      float tot = (tid < 16) ? redw[tid] : 0.f;
      #pragma unroll
      for (int o2 = 1; o2 < 16; o2 <<= 1) tot += __shfl_xor(tot, o2);
      if (tid == 0){
        astore_f(&part[fbaseP + ch*32 + (r & 1)*16], tot);
        asm volatile("s_waitcnt vmcnt(0)" ::: "memory"); // partial acked before flag
        astore_i(&flag[fbaseF + ch*16], r);              // arrive (own slot, monotonic)
      }
      // poll all CHK flags: one gathered vector load per iteration
      const bool mine = (tid < CHK);
      for (;;){
        int v = mine ? aload_i(&flag[fbaseF + tid*16]) : 0x7FFFFFFF;
        if (__all(v >= r)) break;
        __builtin_amdgcn_s_sleep(2);
      }
      // gather partials (fresh sc1 loads, issued after poll exit) and reduce
      float p = mine ? aload_f(&part[fbaseP + tid*32 + (r & 1)*16]) : 0.f;
      #pragma unroll
      for (int o2 = 1; o2 < 32; o2 <<= 1) p += __shfl_xor(p, o2);
      if (tid == 0){ if (fin) s_dot = p; else s_nrm = p; }
    }
    __syncthreads();
    // rotate triple buffer
    float* tmp = u_in; u_in = u_ot; u_ot = u_nx; u_nx = tmp;
  }
  // folded lamfin: one block per t; s_nrm = nrm2 of round 75, s_dot = Rayleigh dot
  if (ch == 0 && tid == 0){
    float nn = sqrtf(s_nrm) + 1e-12f;
    float lam = s_dot / (nn*nn);
    lamc[2*t+0] = -2.f/lam;
    lamc[2*t+1] =  2.f/lam - 1.f;
  }
}

// ---------------------------------------------------------------- Chebyshev SpMM (wave per row, lane = channel, XCD-swizzled)
__global__ __launch_bounds__(256) void k_cheb(const __hip_bfloat16* __restrict__ xin,
    const __hip_bfloat16* __restrict__ xb0, __hip_bfloat16* __restrict__ outp,
    const int* __restrict__ rp, const unsigned short* __restrict__ col,
    const float* __restrict__ dinv, const float* __restrict__ lamc, float s1, float s2)
{
  const int blk = blockIdx.x;               // 90000 = 8*11250
  const int w = (blk & 7)*11250 + (blk >> 3);
  const int gw = w*4 + (threadIdx.x >> 6);
  const int lane = threadIdx.x & 63;
  int t = gw / Mn, m = gw - t*Mn;
  float coef = lamc[2*t], diag = lamc[2*t+1];
  const __hip_bfloat16* xt = xin + (size_t)t*Mn*Hh;
  const float* dv = dinv + t*Mn;
  float acc = diag * bf2f(xt[(size_t)m*Hh + lane]);
  float cdm = coef * dv[m];
  int bgn = rp[t*(Mn+1)+m], end = rp[t*(Mn+1)+m+1];
  const unsigned short* cp = col + (size_t)t*Ee;
  int i = bgn;
  for (; i < end && (i & 3); ++i){ int c = cp[i]; acc += (cdm*dv[c])*bf2f(xt[(size_t)c*Hh + lane]); }
  for (; i + 4 <= end; i += 4){
    ushort4 c4 = *(const ushort4*)(cp + i);
    float w0 = cdm*dv[c4.x], w1 = cdm*dv[c4.y], w2 = cdm*dv[c4.z], w3 = cdm*dv[c4.w];
    acc += w0*bf2f(xt[(size_t)c4.x*Hh + lane]);
    acc += w1*bf2f(xt[(size_t)c4.y*Hh + lane]);
    acc += w2*bf2f(xt[(size_t)c4.z*Hh + lane]);
    acc += w3*bf2f(xt[(size_t)c4.w*Hh + lane]);
  }
  for (; i < end; ++i){ int c = cp[i]; acc += (cdm*dv[c])*bf2f(xt[(size_t)c*Hh + lane]); }
  float o = s1*acc;
  if (s2 != 0.f) o += s2*bf2f(xb0[(size_t)gw*Hh + lane]);
  outp[(size_t)gw*Hh + lane] = f2bf(o);
}

// ---------------------------------------------------------------- fold cheb_W into conv_W
__global__ void k_ww(const float* __restrict__ chebW, const float* __restrict__ chebb,
    const float* __restrict__ convW, const float* __restrict__ convb, float* __restrict__ WW, float* __restrict__ c0)
{
  int idx = blockIdx.x*256 + threadIdx.x;
  if (idx < 3*Tt*Hh*Oo){
    int oc = idx % Oo; int j = (idx/Oo) % Hh; int t = (idx/(Oo*Hh)) % Tt; int i = idx/(Oo*Hh*Tt);
    const float* cw = chebW + ((size_t)i*Hh + j)*HC + (HC-KW);
    const float* vw = convW + ((size_t)oc*Tt + t)*KW;
    float s = 0.f;
    for (int k = 0; k < KW; ++k) s += cw[k]*vw[k];
    WW[idx] = s;
  }
  if (blockIdx.x == 0 && threadIdx.x < Oo){
    int oc = threadIdx.x;
    float s = convb[oc];
    for (int t = 0; t < Tt; ++t){
      const float* vw = convW + ((size_t)oc*Tt + t)*KW;
      for (int k = 0; k < KW; ++k) s += chebb[(HC-KW)+k]*vw[k];
    }
    c0[oc] = s;
  }
}

// ---------------------------------------------------------------- fused cheb-GEMM + temporal conv + sigmoid
__global__ __launch_bounds__(256) void k_final(const __hip_bfloat16* __restrict__ tx0,
    const __hip_bfloat16* __restrict__ tx1, const __hip_bfloat16* __restrict__ tx2,
    const float* __restrict__ WW, const float* __restrict__ c0, float* __restrict__ outp)
{
  __shared__ float xs[64][65];
  __shared__ float ww[64][12];
  const int tid = threadIdx.x;
  const int n0 = blockIdx.x*64;
  const int n = tid & 63, ob = (tid >> 6)*3;
  float acc[3] = {0.f, 0.f, 0.f};
  for (int it = 0; it < 3*Tt; ++it){
    int ii = it / Tt, t = it % Tt;
    const __hip_bfloat16* tx = (ii == 0) ? tx0 : (ii == 1) ? tx1 : tx2;
    __syncthreads();
    for (int idx = tid; idx < 64*64; idx += 256){
      int mm = idx >> 6, j = idx & 63;
      int m = n0 + mm;
      xs[mm][j] = (m < Mn) ? bf2f(tx[((size_t)t*Mn + m)*Hh + j]) : 0.f;
    }
    for (int idx = tid; idx < 64*Oo; idx += 256)
      ((float*)ww)[idx] = WW[((size_t)(ii*Tt + t)*Hh)*Oo + idx];
    __syncthreads();
    #pragma unroll 8
    for (int j = 0; j < 64; ++j){
      float x = xs[n][j];
      acc[0] += x*ww[j][ob+0];
      acc[1] += x*ww[j][ob+1];
      acc[2] += x*ww[j][ob+2];
    }
  }
  int m = n0 + n;
  if (m < Mn){
    #pragma unroll
    for (int q = 0; q < 3; ++q) outp[(size_t)m*Oo + ob + q] = sigm(acc[q] + c0[ob+q]);
  }
}

// ================================================================ host
extern "C" void kernel_launch(void* const* d_in, const int* in_sizes, int n_in,
                              void* d_out, int out_size, void* d_ws, size_t ws_size,
                              hipStream_t stream)
{
  const float* nf    = (const float*)d_in[0];
  const int*   ei    = (const int*)d_in[1];
  const float* Wih0  = (const float*)d_in[2];
  const float* Whh0  = (const float*)d_in[3];
  const float* bih0  = (const float*)d_in[4];
  const float* bhh0  = (const float*)d_in[5];
  const float* Wih1  = (const float*)d_in[6];
  const float* Whh1  = (const float*)d_in[7];
  const float* bih1  = (const float*)d_in[8];
  const float* bhh1  = (const float*)d_in[9];
  const float* lns   = (const float*)d_in[10];
  const float* lnb   = (const float*)d_in[11];
  const float* chebW = (const float*)d_in[12];
  const float* chebb = (const float*)d_in[13];
  const float* convW = (const float*)d_in[14];
  const float* convb = (const float*)d_in[15];
  float* outp = (float*)d_out;

  char* base = (char*)d_ws;
  size_t off = 0;
  auto alloc = [&](size_t bytes)->char*{ char* p = base + off; off += (bytes + 255) & ~(size_t)255; return p; };

  __hip_bfloat16* y0  = (__hip_bfloat16*)alloc((size_t)Tt*Mn*C2*2);
  __hip_bfloat16* tx1 = y0;
  __hip_bfloat16* tx2 = y0 + (size_t)Tt*Mn*Hh;
  __hip_bfloat16* gi  = (__hip_bfloat16*)alloc((size_t)Tt*Mn*Gg*2);
  unsigned* pair = (unsigned*)gi;          // overlaps gi: pair dead before k_gi1m writes gi
  __hip_bfloat16* xbt = (__hip_bfloat16*)alloc((size_t)Tt*Mn*Hh*2);
  unsigned short* col16 = (unsigned short*)alloc((size_t)Tt*Ee*2);
  int*   deg  = (int*)alloc((size_t)Tt*Mn*4);
  int*   rp   = (int*)alloc((size_t)Tt*(Mn+1)*4);
  int*   bcnt = (int*)alloc((size_t)Tt*NB*4);
  int*   bfill= (int*)alloc((size_t)Tt*NB*4);
  int*   rpb  = (int*)alloc((size_t)Tt*(NB+1)*4);
  float* uA   = (float*)alloc((size_t)Tt*Mn*4);
  float* uB   = (float*)alloc((size_t)Tt*Mn*4);
  float* uC   = (float*)alloc((size_t)Tt*Mn*4);
  float* dinv = (float*)alloc((size_t)Tt*Mn*4);
  float* lamc = (float*)alloc((size_t)2*Tt*4);
  float* WW   = (float*)alloc((size_t)3*Tt*Hh*Oo*4);
  float* c0   = (float*)alloc((size_t)Oo*4);
  __hip_bfloat16* Wbf = (__hip_bfloat16*)alloc((size_t)Gg*C2*2);
  float* part = (float*)alloc((size_t)Tt*CHK*32*4);   // 2 parity slots x 64B per block
  int*   flag = (int*)alloc((size_t)Tt*CHK*16*4);     // 1 epoch flag x 64B per block
  (void)ws_size; (void)in_sizes; (void)n_in; (void)out_size;

  // CSR build: bucket histogram -> bucket scan -> partition -> per-bucket counting sort (emits rp+deg)
  k_init<<<(Tt*Mn + 255)/256, 256, 0, stream>>>(uA, bcnt, bfill, flag);
  k_bcnt<<<Tt*BPT, 256, 0, stream>>>(ei, bcnt);
  k_bscan<<<Tt, 256, 0, stream>>>(bcnt, rpb);
  k_part2<<<Tt*BPT, 256, 0, stream>>>(ei, rpb, bfill, pair);
  k_csr2<<<Tt*NB, 256, 0, stream>>>(rpb, pair, col16, rp, deg);
  k_dinv<<<(Tt*Mn + 255)/256, 256, 0, stream>>>(deg, dinv);

  // GRU stack (layer-1 forward direction is dead code -> skipped)
  k_wcvt<<<(Gg*C2 + 255)/256, 256, 0, stream>>>(Wih1 + (size_t)Gg*C2, Wbf);
  k_gru0<<<(Mn + 31)/32, 256, 0, stream>>>(nf, Wih0, Whh0, bih0, bhh0, y0);
  {
    int waves = Tt*((Mn + 31)/32);
    k_gi1m<<<(waves + 3)/4, 256, 0, stream>>>(y0, Wbf, bih1 + Gg, gi);
  }
  k_gru1r<<<(Mn + 31)/32, 256, 0, stream>>>(gi, Whh1 + (size_t)Gg*Hh, bhh1 + Gg, lns, lnb, xbt);

  // power iteration: 75 rounds + 1 Rayleigh round, fused into ONE kernel;
  // contention-free flag barrier (no same-address RMWs), triple-buffered u
  k_pitall<<<Tt*CHK, 1024, 0, stream>>>(rp, col16, uA, uB, uC, part, flag, lamc);

  // Chebyshev: tx1 = Lhat(x), tx2 = 2*Lhat(tx1) - x
  k_cheb<<<(Tt*Mn)/4, 256, 0, stream>>>(xbt, xbt, tx1, rp, col16, dinv, lamc, 1.f, 0.f);
  k_cheb<<<(Tt*Mn)/4, 256, 0, stream>>>(tx1, xbt, tx2, rp, col16, dinv, lamc, 2.f, -1.f);

  // folded cheb-GEMM + conv + sigmoid
  k_ww<<<(3*Tt*Hh*Oo + 255)/256, 256, 0, stream>>>(chebW, chebb, convW, convb, WW, c0);
  k_final<<<(Mn + 63)/64, 256, 0, stream>>>(xbt, tx1, tx2, WW, c0, outp);
}

// Round 4
// 3080.036 us; speedup vs baseline: 1.4153x; 1.0404x over previous
//
#include <hip/hip_runtime.h>
#include <hip/hip_bf16.h>

#define DEV __device__ __forceinline__

constexpr int Mn  = 30000;   // nodes (B=1)
constexpr int Tt  = 12;
constexpr int CIN = 16;
constexpr int Hh  = 64;
constexpr int Gg  = 192;     // 3H
constexpr int C2  = 128;     // 2H
constexpr int Ee  = 960000;  // edges per timestep (bidirectional)
constexpr int HC  = 128;
constexpr int Oo  = 12;
constexpr int KW  = 128;
constexpr int HP  = 72;      // padded h row stride (floats)
constexpr int WP  = 194;     // padded weight row stride (bf16): bank stride 97 (odd) -> conflict-free
constexpr int XSP = 36;      // padded xs inner stride (floats): 16B-aligned, 2-way max
constexpr int NB  = 235;     // 128-row buckets per t (235*128 >= 30000)
constexpr int EPB = 8192;    // edges per block for bcnt/part2
constexpr int BPT = 118;     // ceil(Ee/EPB)
constexpr int CHK = 21;      // chunks per t for power iteration (252 blocks total)
constexpr int RC  = 1440;    // rows per chunk (16B-aligned chunk base; 21*1440 >= 30000)
constexpr int NRND= 76;      // 75 power rounds + 1 Rayleigh round
constexpr int NF4A= 21*256;  // phase-A float4 count (rows [r0, r0+1024) per chunk)
constexpr int NF4B= 20*104 + 44; // phase-B float4 count (rows [r0+1024, r1) per chunk)

DEV float bf2f(__hip_bfloat16 v){ return __bfloat162float(v); }
DEV __hip_bfloat16 f2bf(float v){ return __float2bfloat16(v); }
DEV float sigm(float x){ return __builtin_amdgcn_rcpf(1.f + __expf(-x)); }
DEV float tanh_f(float x){ return 1.f - 2.f*__builtin_amdgcn_rcpf(__expf(2.f*x) + 1.f); }

// agent-scope (device-coherent, sc1) accessors for cross-XCD flags/partials/u-stores
DEV float aload_f(const float* p){ return __hip_atomic_load(p, __ATOMIC_RELAXED, __HIP_MEMORY_SCOPE_AGENT); }
DEV void  astore_f(float* p, float v){ __hip_atomic_store(p, v, __ATOMIC_RELAXED, __HIP_MEMORY_SCOPE_AGENT); }
DEV int   aload_i(const int* p){ return __hip_atomic_load(p, __ATOMIC_RELAXED, __HIP_MEMORY_SCOPE_AGENT); }
DEV void  astore_i(int* p, int v){ __hip_atomic_store(p, v, __ATOMIC_RELAXED, __HIP_MEMORY_SCOPE_AGENT); }

typedef short bfrag8 __attribute__((ext_vector_type(8)));
typedef float ffrag4 __attribute__((ext_vector_type(4)));

// ---------------------------------------------------------------- init (flags + CSR counters only; u seed is in-kernel now)
__global__ void k_init(int* bcnt, int* bfill, int* flagA, int* flagB){
  int i = blockIdx.x*256 + threadIdx.x;
  if (i < Tt*CHK*16){ flagA[i] = 0; flagB[i] = 0; }
  if (i < Tt*NB){ bcnt[i] = 0; bfill[i] = 0; }
}

// ---------------------------------------------------------------- stage 1: block-aggregated bucket histogram
__global__ __launch_bounds__(256) void k_bcnt(const int* __restrict__ ei, int* __restrict__ bcnt){
  __shared__ int h[NB];
  const int b = blockIdx.x;                 // 1416 = 8*177
  const int w = (b & 7)*177 + (b >> 3);
  const int t = w / BPT, ch = w - t*BPT;
  const int e0 = ch*EPB;
  const int tid = threadIdx.x;
  for (int i = tid; i < NB; i += 256) h[i] = 0;
  __syncthreads();
  #pragma unroll
  for (int i = 0; i < 32; ++i){
    int e = e0 + i*256 + tid;
    if (e < Ee){
      int r = ei[(size_t)(t*2)*Ee + e];
      atomicAdd(&h[r >> 7], 1);
    }
  }
  __syncthreads();
  for (int i = tid; i < NB; i += 256){
    int c = h[i];
    if (c > 0) atomicAdd(&bcnt[t*NB + i], c);
  }
}

// ---------------------------------------------------------------- stage 2: per-t exclusive scan of bucket counts
__global__ __launch_bounds__(256) void k_bscan(const int* __restrict__ bcnt, int* __restrict__ rpb){
  int t = blockIdx.x, tid = threadIdx.x;
  __shared__ int ps[256];
  int v = (tid < NB) ? bcnt[t*NB + tid] : 0;
  ps[tid] = v;
  __syncthreads();
  for (int o = 1; o < 256; o <<= 1){
    int x = (tid >= o) ? ps[tid-o] : 0;
    __syncthreads();
    ps[tid] += x;
    __syncthreads();
  }
  if (tid < NB) rpb[t*(NB+1) + tid] = ps[tid] - v;
  if (tid == 255) rpb[t*(NB+1) + NB] = ps[NB-1];
}

// ---------------------------------------------------------------- stage 3: partition edges into buckets (block-aggregated reservations)
__global__ __launch_bounds__(256) void k_part2(const int* __restrict__ ei, const int* __restrict__ rpb,
    int* __restrict__ bfill, unsigned* __restrict__ pair){
  __shared__ int hcnt[NB];
  __shared__ int hbase[NB];
  const int b = blockIdx.x;                 // 1416 = 8*177
  const int w = (b & 7)*177 + (b >> 3);
  const int t = w / BPT, ch = w - t*BPT;
  const int e0 = ch*EPB;
  const int tid = threadIdx.x;
  for (int i = tid; i < NB; i += 256) hcnt[i] = 0;
  __syncthreads();
  unsigned key[32];
  #pragma unroll
  for (int i = 0; i < 32; ++i){
    int e = e0 + i*256 + tid;
    unsigned k = 0xFFFFFFFFu;
    if (e < Ee){
      int r = ei[(size_t)(t*2)*Ee + e];
      int c = ei[(size_t)(t*2+1)*Ee + e];
      k = ((unsigned)r << 16) | (unsigned)c;
      atomicAdd(&hcnt[r >> 7], 1);
    }
    key[i] = k;
  }
  __syncthreads();
  for (int i = tid; i < NB; i += 256){
    int cnt = hcnt[i];
    int base = (cnt > 0) ? atomicAdd(&bfill[t*NB + i], cnt) : 0;
    hbase[i] = rpb[t*(NB+1) + i] + base;
  }
  __syncthreads();
  for (int i = tid; i < NB; i += 256) hcnt[i] = 0;
  __syncthreads();
  #pragma unroll
  for (int i = 0; i < 32; ++i){
    unsigned k = key[i];
    if (k != 0xFFFFFFFFu){
      int r = (int)(k >> 16);
      int bk = r >> 7;
      int pos = atomicAdd(&hcnt[bk], 1);
      pair[(size_t)t*Ee + hbase[bk] + pos] = ((unsigned)(r & 127) << 16) | (k & 0xFFFFu);
    }
  }
}

// ---------------------------------------------------------------- stage 4: per-bucket LDS counting sort -> col16, rp, deg
__global__ __launch_bounds__(256) void k_csr2(const int* __restrict__ rpb, const unsigned* __restrict__ pair,
    unsigned short* __restrict__ col16, int* __restrict__ rp, int* __restrict__ deg){
  __shared__ unsigned short cols_s[9216];
  __shared__ int lcnt[128], lfill[128];
  __shared__ int ps[256];
  const int blk = blockIdx.x;               // Tt*NB
  const int t = blk / NB, bk = blk - t*NB;
  const int r0 = bk << 7;
  const int nr = (r0 + 128 <= Mn) ? 128 : (Mn - r0);
  const int base = rpb[t*(NB+1) + bk];
  const int cnt  = rpb[t*(NB+1) + bk + 1] - base;
  const int tid = threadIdx.x;
  if (tid < 128) lcnt[tid] = 0;
  __syncthreads();
  for (int i = tid; i < cnt; i += 256){
    unsigned v = pair[(size_t)t*Ee + base + i];
    atomicAdd(&lcnt[v >> 16], 1);
  }
  __syncthreads();
  int v2 = (tid < 128) ? lcnt[tid] : 0;
  ps[tid] = v2;
  __syncthreads();
  for (int o = 1; o < 128; o <<= 1){
    int x = (tid >= o) ? ps[tid-o] : 0;
    __syncthreads();
    ps[tid] += x;
    __syncthreads();
  }
  if (tid < 128){
    int excl = ps[tid] - v2;
    lfill[tid] = excl;
    if (tid < nr){
      rp[t*(Mn+1) + r0 + tid] = base + excl;
      deg[t*Mn + r0 + tid] = v2;
    }
  }
  if (bk == NB-1 && tid == 0) rp[t*(Mn+1) + Mn] = base + cnt;
  __syncthreads();
  for (int i = tid; i < cnt; i += 256){
    unsigned v = pair[(size_t)t*Ee + base + i];
    int pos = atomicAdd(&lfill[v >> 16], 1);
    cols_s[pos] = (unsigned short)(v & 0xFFFFu);
  }
  __syncthreads();
  for (int i = tid; i < cnt; i += 256)
    col16[(size_t)t*Ee + base + i] = cols_s[i];
}

// ---------------------------------------------------------------- dinv
__global__ void k_dinv(const int* __restrict__ deg, float* __restrict__ dinv){
  int i = blockIdx.x*256 + threadIdx.x;
  if (i < Tt*Mn){ int d = deg[i]; dinv[i] = (d > 0) ? rsqrtf((float)d) : 0.f; }
}

// ---------------------------------------------------------------- GRU layer 0 (both dirs), writes y0 (T,M,128) bf16
__global__ __launch_bounds__(256) void k_gru0(
    const float* __restrict__ nf, const float* __restrict__ Wih, const float* __restrict__ Whh,
    const float* __restrict__ bih, const float* __restrict__ bhh, __hip_bfloat16* __restrict__ y0)
{
  __shared__ float xs[Tt][CIN][XSP];
  __shared__ __hip_bfloat16 wi[CIN][WP];
  __shared__ __hip_bfloat16 wh[Hh][WP];
  __shared__ float hb[32][HP];
  __shared__ float bi[Gg], bh[Gg];
  const int tid = threadIdx.x;
  const int m0  = blockIdx.x*32;
  for (int idx = tid; idx < Tt*32*CIN; idx += 256){
    int t = idx / (32*CIN); int rr = (idx / CIN) & 31; int k = idx & (CIN-1);
    int m = m0 + rr;
    xs[t][k][rr] = (m < Mn) ? nf[((size_t)t*Mn + m)*CIN + k] : 0.f;
  }
  const int jg = tid & 31, rg = tid >> 5;
  const int j0 = jg*2, rg4 = rg*4;
  for (int d = 0; d < 2; ++d){
    __syncthreads();
    for (int idx = tid; idx < Gg*CIN; idx += 256){
      int g = idx / CIN, k = idx & (CIN-1);
      wi[k][g] = f2bf(Wih[((size_t)d*Gg + g)*CIN + k]);
    }
    for (int idx = tid; idx < Gg*Hh; idx += 256){
      int g = idx >> 6, k = idx & 63;
      wh[k][g] = f2bf(Whh[((size_t)d*Gg + g)*Hh + k]);
    }
    if (tid < Gg){ bi[tid] = bih[d*Gg + tid]; bh[tid] = bhh[d*Gg + tid]; }
    for (int idx = tid; idx < 32*HP; idx += 256) ((float*)hb)[idx] = 0.f;
    __syncthreads();
    for (int step = 0; step < Tt; ++step){
      int t = d ? (Tt-1-step) : step;
      float ar[4][2], az[4][2], ai[4][2], ah[4][2];
      #pragma unroll
      for (int i = 0; i < 4; ++i){
        #pragma unroll
        for (int jj = 0; jj < 2; ++jj){
          int j = j0 + jj;
          ar[i][jj] = bi[j] + bh[j];
          az[i][jj] = bi[Hh+j] + bh[Hh+j];
          ai[i][jj] = bi[2*Hh+j];
          ah[i][jj] = bh[2*Hh+j];
        }
      }
      #pragma unroll
      for (int k = 0; k < CIN; ++k){
        float4 xv4 = *(const float4*)&xs[t][k][rg4];
        float xv[4] = {xv4.x, xv4.y, xv4.z, xv4.w};
        __hip_bfloat162 pr = *(const __hip_bfloat162*)&wi[k][j0];
        __hip_bfloat162 pz = *(const __hip_bfloat162*)&wi[k][Hh+j0];
        __hip_bfloat162 pn = *(const __hip_bfloat162*)&wi[k][2*Hh+j0];
        float wr[2] = {bf2f(pr.x), bf2f(pr.y)};
        float wz[2] = {bf2f(pz.x), bf2f(pz.y)};
        float wn[2] = {bf2f(pn.x), bf2f(pn.y)};
        #pragma unroll
        for (int i = 0; i < 4; ++i){
          #pragma unroll
          for (int jj = 0; jj < 2; ++jj){
            ar[i][jj] += xv[i]*wr[jj];
            az[i][jj] += xv[i]*wz[jj];
            ai[i][jj] += xv[i]*wn[jj];
          }
        }
      }
      #pragma unroll 4
      for (int k4 = 0; k4 < 16; ++k4){
        float4 h0 = *(const float4*)&hb[rg4+0][k4*4];
        float4 h1 = *(const float4*)&hb[rg4+1][k4*4];
        float4 h2 = *(const float4*)&hb[rg4+2][k4*4];
        float4 h3 = *(const float4*)&hb[rg4+3][k4*4];
        #pragma unroll
        for (int kk = 0; kk < 4; ++kk){
          int k = k4*4 + kk;
          float hv[4] = { ((const float*)&h0)[kk], ((const float*)&h1)[kk],
                          ((const float*)&h2)[kk], ((const float*)&h3)[kk] };
          __hip_bfloat162 pr = *(const __hip_bfloat162*)&wh[k][j0];
          __hip_bfloat162 pz = *(const __hip_bfloat162*)&wh[k][Hh+j0];
          __hip_bfloat162 pn = *(const __hip_bfloat162*)&wh[k][2*Hh+j0];
          float wr[2] = {bf2f(pr.x), bf2f(pr.y)};
          float wz[2] = {bf2f(pz.x), bf2f(pz.y)};
          float wn[2] = {bf2f(pn.x), bf2f(pn.y)};
          #pragma unroll
          for (int i = 0; i < 4; ++i){
            #pragma unroll
            for (int jj = 0; jj < 2; ++jj){
              ar[i][jj] += hv[i]*wr[jj];
              az[i][jj] += hv[i]*wz[jj];
              ah[i][jj] += hv[i]*wn[jj];
            }
          }
        }
      }
      __syncthreads();
      #pragma unroll
      for (int i = 0; i < 4; ++i){
        int r = rg4 + i; int m = m0 + r;
        float hn2[2];
        #pragma unroll
        for (int jj = 0; jj < 2; ++jj){
          float rr = sigm(ar[i][jj]);
          float zz = sigm(az[i][jj]);
          float nn = tanh_f(ai[i][jj] + rr*ah[i][jj]);
          float hv = hb[r][j0+jj];
          hn2[jj] = (1.f-zz)*nn + zz*hv;
          hb[r][j0+jj] = hn2[jj];
        }
        if (m < Mn){
          __hip_bfloat162 pk; pk.x = f2bf(hn2[0]); pk.y = f2bf(hn2[1]);
          *(__hip_bfloat162*)&y0[((size_t)t*Mn + m)*C2 + d*Hh + j0] = pk;
        }
      }
      __syncthreads();
    }
  }
}

// ---------------------------------------------------------------- convert layer-1 reverse weights to bf16
__global__ void k_wcvt(const float* __restrict__ W, __hip_bfloat16* __restrict__ Wbf){
  int i = blockIdx.x*256 + threadIdx.x;
  if (i < Gg*C2) Wbf[i] = f2bf(W[i]);
}

// ---------------------------------------------------------------- layer-1 input projection via MFMA
__global__ __launch_bounds__(256) void k_gi1m(const __hip_bfloat16* __restrict__ y0,
    const __hip_bfloat16* __restrict__ Wbf, const float* __restrict__ bih, __hip_bfloat16* __restrict__ gi)
{
  const int wid  = (blockIdx.x*256 + threadIdx.x) >> 6;
  const int lane = threadIdx.x & 63;
  const int SEGS = (Mn + 31)/32;
  if (wid >= Tt*SEGS) return;
  const int t = wid / SEGS, seg = wid - t*SEGS;
  const int m0 = seg*32;
  const int lr = lane & 15, lq = lane >> 4;
  const __hip_bfloat16* yb = y0 + (size_t)t*Mn*C2;

  ffrag4 acc[2][12];
  #pragma unroll
  for (int i = 0; i < 2; ++i){
    #pragma unroll
    for (int n = 0; n < 12; ++n) acc[i][n] = (ffrag4){0.f,0.f,0.f,0.f};
  }
  #pragma unroll
  for (int ks = 0; ks < 4; ++ks){
    const int ko = ks*32 + lq*8;
    bfrag8 a0 = *(const bfrag8*)(yb + (size_t)(m0 + lr     )*C2 + ko);
    bfrag8 a1 = *(const bfrag8*)(yb + (size_t)(m0 + 16 + lr)*C2 + ko);
    #pragma unroll
    for (int nt = 0; nt < 12; ++nt){
      bfrag8 b = *(const bfrag8*)(Wbf + (size_t)(nt*16 + lr)*C2 + ko);
      acc[0][nt] = __builtin_amdgcn_mfma_f32_16x16x32_bf16(a0, b, acc[0][nt], 0, 0, 0);
      acc[1][nt] = __builtin_amdgcn_mfma_f32_16x16x32_bf16(a1, b, acc[1][nt], 0, 0, 0);
    }
  }
  #pragma unroll
  for (int nt = 0; nt < 12; ++nt){
    int g = nt*16 + lr;
    float bb = bih[g];
    #pragma unroll
    for (int r = 0; r < 4; ++r){
      int mm0 = m0 + lq*4 + r;
      int mm1 = mm0 + 16;
      if (mm0 < Mn) gi[((size_t)t*Mn + mm0)*Gg + g] = f2bf(acc[0][nt][r] + bb);
      if (mm1 < Mn) gi[((size_t)t*Mn + mm1)*Gg + g] = f2bf(acc[1][nt][r] + bb);
    }
  }
}

// ---------------------------------------------------------------- GRU layer 1 (reverse only) + fused LayerNorm
__global__ __launch_bounds__(256) void k_gru1r(const __hip_bfloat16* __restrict__ gi,
    const float* __restrict__ Whh, const float* __restrict__ bhh,
    const float* __restrict__ lns, const float* __restrict__ lnb,
    __hip_bfloat16* __restrict__ xbt)
{
  __shared__ __hip_bfloat16 wh[Hh][WP];
  __shared__ float hb[32][HP];
  __shared__ float bh[Gg];
  __shared__ float sc[Hh], bs[Hh];
  const int tid = threadIdx.x;
  const int m0  = blockIdx.x*32;
  for (int idx = tid; idx < Gg*Hh; idx += 256){
    int g = idx >> 6, k = idx & 63;
    wh[k][g] = f2bf(Whh[(size_t)g*Hh + k]);
  }
  if (tid < Gg) bh[tid] = bhh[tid];
  if (tid < Hh){ sc[tid] = lns[tid]; bs[tid] = lnb[tid]; }
  for (int idx = tid; idx < 32*HP; idx += 256) ((float*)hb)[idx] = 0.f;
  __syncthreads();
  const int jg = tid & 31, rg = tid >> 5;
  const int j0 = jg*2, rg4 = rg*4;
  for (int step = 0; step < Tt; ++step){
    int t = Tt-1-step;
    float ar[4][2], az[4][2], ai[4][2], ah[4][2];
    #pragma unroll
    for (int i = 0; i < 4; ++i){
      int m = m0 + rg4 + i;
      int mc = (m < Mn) ? m : 0;
      const __hip_bfloat16* gp = gi + ((size_t)t*Mn + mc)*Gg;
      __hip_bfloat162 pr = *(const __hip_bfloat162*)&gp[j0];
      __hip_bfloat162 pz = *(const __hip_bfloat162*)&gp[Hh+j0];
      __hip_bfloat162 pn = *(const __hip_bfloat162*)&gp[2*Hh+j0];
      #pragma unroll
      for (int jj = 0; jj < 2; ++jj){
        int j = j0 + jj;
        float gr = jj ? bf2f(pr.y) : bf2f(pr.x);
        float gz = jj ? bf2f(pz.y) : bf2f(pz.x);
        float gn = jj ? bf2f(pn.y) : bf2f(pn.x);
        ar[i][jj] = gr + bh[j];
        az[i][jj] = gz + bh[Hh+j];
        ai[i][jj] = gn;
        ah[i][jj] = bh[2*Hh+j];
      }
    }
    #pragma unroll 4
    for (int k4 = 0; k4 < 16; ++k4){
      float4 h0 = *(const float4*)&hb[rg4+0][k4*4];
      float4 h1 = *(const float4*)&hb[rg4+1][k4*4];
      float4 h2 = *(const float4*)&hb[rg4+2][k4*4];
      float4 h3 = *(const float4*)&hb[rg4+3][k4*4];
      #pragma unroll
      for (int kk = 0; kk < 4; ++kk){
        int k = k4*4 + kk;
        float hv[4] = { ((const float*)&h0)[kk], ((const float*)&h1)[kk],
                        ((const float*)&h2)[kk], ((const float*)&h3)[kk] };
        __hip_bfloat162 pr = *(const __hip_bfloat162*)&wh[k][j0];
        __hip_bfloat162 pz = *(const __hip_bfloat162*)&wh[k][Hh+j0];
        __hip_bfloat162 pn = *(const __hip_bfloat162*)&wh[k][2*Hh+j0];
        float wr[2] = {bf2f(pr.x), bf2f(pr.y)};
        float wz[2] = {bf2f(pz.x), bf2f(pz.y)};
        float wn[2] = {bf2f(pn.x), bf2f(pn.y)};
        #pragma unroll
        for (int i = 0; i < 4; ++i){
          #pragma unroll
          for (int jj = 0; jj < 2; ++jj){
            ar[i][jj] += hv[i]*wr[jj];
            az[i][jj] += hv[i]*wz[jj];
            ah[i][jj] += hv[i]*wn[jj];
          }
        }
      }
    }
    __syncthreads();
    #pragma unroll
    for (int i = 0; i < 4; ++i){
      int r = rg4 + i;
      #pragma unroll
      for (int jj = 0; jj < 2; ++jj){
        float rr = sigm(ar[i][jj]);
        float zz = sigm(az[i][jj]);
        float nn = tanh_f(ai[i][jj] + rr*ah[i][jj]);
        float hv = hb[r][j0+jj];
        hb[r][j0+jj] = (1.f-zz)*nn + zz*hv;
      }
    }
    __syncthreads();
    {
      int r = tid >> 3, l = tid & 7;
      float vals[8];
      float s1 = 0.f, s2 = 0.f;
      #pragma unroll
      for (int q = 0; q < 8; ++q){ float v = hb[r][l + 8*q]; vals[q] = v; s1 += v; s2 += v*v; }
      #pragma unroll
      for (int off = 1; off <= 4; off <<= 1){ s1 += __shfl_xor(s1, off); s2 += __shfl_xor(s2, off); }
      float mu  = s1 * (1.f/64.f);
      float var = s2 * (1.f/64.f) - mu*mu;
      float rs  = rsqrtf(var + 1e-5f);
      int m = m0 + r;
      if (m < Mn){
        __hip_bfloat16* op = xbt + ((size_t)t*Mn + m)*Hh;
        #pragma unroll
        for (int q = 0; q < 8; ++q){ int j = l + 8*q; op[j] = f2bf((vals[q]-mu)*rs*sc[j] + bs[j]); }
      }
    }
    __syncthreads();
  }
}

// ---------------------------------------------------------------- fused power iteration: all 76 rounds in ONE kernel.
// 252 blocks, 120KB LDS -> 1 block/CU -> all co-resident.
// R4 redesign: ROUND-UNIQUE u buffers (urb + r*Tt*Mn, carved from the dead gi
// arena) let staging use PLAIN CACHED float4 loads: every address is L2-virgin
// on first read (kernel-start acquire invalidated L2; buffer r written sc1 in
// round r, read only in round r+1) -> L2 miss fetches CURRENT data from the
// coherent L3 and blocks sharing an XCD hit L2. ~20x less fabric traffic than
// R3's sc1 staging. u-stores stay sc1 (write-through to L3, no L2 pollution).
// Rows split into phase A (first 1024/chunk) and B (rest) with separate
// monotonic epoch flags; each wave polls A(r-1) -> stages A -> polls B(r-1) ->
// stages B, hiding the cross-die flag latency under the A-stage. Round 1 fills
// u_s with the constant seed (no staging). Per-row math bit-identical to R3.
__global__ __launch_bounds__(1024) void k_pitall(const int* __restrict__ rp,
    const unsigned short* __restrict__ col, float* __restrict__ urb,
    float* __restrict__ part, int* __restrict__ flagA, int* __restrict__ flagB,
    float* __restrict__ lamc)
{
  __shared__ alignas(16) float u_s[Mn];     // 120000 B
  __shared__ float redw[16];
  __shared__ float s_nrm;
  const int b = blockIdx.x;                 // Tt*CHK = 252
  const int t = b / CHK, ch = b - t*CHK;
  const int r0 = ch*RC;
  const int r1 = (r0 + RC < Mn) ? r0 + RC : Mn;
  const int tid = threadIdx.x;
  const int lane = tid & 63;
  const unsigned short* cp = col + (size_t)t*Ee;
  const int fS = t*CHK*16;                  // flag slots: 64B apart
  const int fP = t*CHK*32;                  // partial slots: 2 parities x 64B per block
  const int m0r = r0 + tid;                 // phase-A row
  const int m1r = m0r + 1024;               // phase-B row
  int rb0 = 0, re0 = 0, rb1 = 0, re1 = 0;
  {
    const int* rpt = rp + t*(Mn+1);
    if (m0r < r1){ rb0 = rpt[m0r]; re0 = rpt[m0r+1]; }
    if (m1r < r1){ rb1 = rpt[m1r]; re1 = rpt[m1r+1]; }
  }
  if (tid == 0) s_nrm = 1.0f;
  for (int r = 1; r <= NRND; ++r){
    const int fin = (r == NRND);
    if (r == 1){
      // u^0 is a constant: fill LDS directly, no staging, no polls
      for (int i = tid; i < Mn; i += 1024) u_s[i] = 0.005773502691896258f;
    } else {
      const float4* u4 = (const float4*)(urb + (size_t)(r-1)*(Tt*Mn) + (size_t)t*Mn);
      float4* s4 = (float4*)u_s;
      const bool mine = lane < CHK;
      for (;;){ int v = mine ? aload_i(&flagA[fS + lane*16]) : 0x7FFFFFFF;
                if (__all(v >= r-1)) break; __builtin_amdgcn_s_sleep(2); }
      asm volatile("" ::: "memory");        // no hoisting of plain loads above poll
      for (int i = tid; i < NF4A; i += 1024){
        int idx = (i >> 8)*360 + (i & 255); // 256 f4 per chunk, chunk stride 360 f4
        s4[idx] = u4[idx];
      }
      for (;;){ int v = mine ? aload_i(&flagB[fS + lane*16]) : 0x7FFFFFFF;
                if (__all(v >= r-1)) break; __builtin_amdgcn_s_sleep(2); }
      asm volatile("" ::: "memory");
      for (int i = tid; i < NF4B; i += 1024){
        int ck = i/104, off = i - ck*104;   // 104 f4 per full chunk tail, last=44
        int idx = ck*360 + 256 + off;
        s4[idx] = u4[idx];
      }
      // wave 0 gathers prev-round partials -> s_nrm (deterministic butterfly)
      if (tid < 64){
        float p = (lane < CHK) ? aload_f(&part[fP + lane*32 + ((r-1)&1)*16]) : 0.f;
        #pragma unroll
        for (int o2 = 1; o2 < 32; o2 <<= 1) p += __shfl_xor(p, o2);
        if (tid == 0) s_nrm = p;
      }
    }
    __syncthreads();                         // staging + s_nrm visible
    const float inv_s = fin ? 1.f : 1.f/(sqrtf(s_nrm) + 1e-12f);
    float* u_ot = urb + (size_t)r*(Tt*Mn);
    float local = 0.f;
    // ---- phase A rows
    if (m0r < r1){
      float s = 0.f;
      int i = rb0;
      for (; i < re0 && (i & 3); ++i) s += u_s[cp[i]];
      for (; i + 4 <= re0; i += 4){
        ushort4 c4 = *(const ushort4*)(cp + i);
        s += (u_s[c4.x] + u_s[c4.y]) + (u_s[c4.z] + u_s[c4.w]);
      }
      for (; i < re0; ++i) s += u_s[cp[i]];
      float uv = u_s[m0r];
      float wv = (float)(re0 - rb0)*uv - s;
      if (!fin){ float o = inv_s*wv; astore_f(&u_ot[t*Mn + m0r], o); local += o*o; }
      else local += uv*wv;
    }
    asm volatile("s_waitcnt vmcnt(0)" ::: "memory");  // own A-stores acked at L3
    __syncthreads();                                  // all waves' A-stores drained
    if (tid == 0) astore_i(&flagA[fS + ch*16], r);    // publish phase A
    // ---- phase B rows
    if (m1r < r1){
      float s = 0.f;
      int i = rb1;
      for (; i < re1 && (i & 3); ++i) s += u_s[cp[i]];
      for (; i + 4 <= re1; i += 4){
        ushort4 c4 = *(const ushort4*)(cp + i);
        s += (u_s[c4.x] + u_s[c4.y]) + (u_s[c4.z] + u_s[c4.w]);
      }
      for (; i < re1; ++i) s += u_s[cp[i]];
      float uv = u_s[m1r];
      float wv = (float)(re1 - rb1)*uv - s;
      if (!fin){ float o = inv_s*wv; astore_f(&u_ot[t*Mn + m1r], o); local += o*o; }
      else local += uv*wv;
    }
    #pragma unroll
    for (int o2 = 1; o2 < 64; o2 <<= 1) local += __shfl_xor(local, o2);
    if ((tid & 63) == 0) redw[tid >> 6] = local;
    asm volatile("s_waitcnt vmcnt(0)" ::: "memory");  // own B-stores acked
    __syncthreads();                                  // all drained + redw visible
    if (tid < 64){
      float tot = (tid < 16) ? redw[tid] : 0.f;
      #pragma unroll
      for (int o2 = 1; o2 < 16; o2 <<= 1) tot += __shfl_xor(tot, o2);
      if (tid == 0){
        astore_f(&part[fP + ch*32 + (r & 1)*16], tot);
        asm volatile("s_waitcnt vmcnt(0)" ::: "memory"); // partial acked before flag
        astore_i(&flagB[fS + ch*16], r);                 // publish phase B + partial
      }
    }
  }
  // folded lamfin: only ch==0 waits for the final partials
  if (ch == 0 && tid < 64){
    const bool mine = lane < CHK;
    for (;;){ int v = mine ? aload_i(&flagB[fS + lane*16]) : 0x7FFFFFFF;
              if (__all(v >= NRND)) break; __builtin_amdgcn_s_sleep(2); }
    asm volatile("" ::: "memory");
    float p = mine ? aload_f(&part[fP + lane*32 + (NRND & 1)*16]) : 0.f;
    #pragma unroll
    for (int o2 = 1; o2 < 32; o2 <<= 1) p += __shfl_xor(p, o2);
    if (tid == 0){
      float nn = sqrtf(s_nrm) + 1e-12f;     // s_nrm = ||w||^2 of round 75
      float lam = p / (nn*nn);
      lamc[2*t+0] = -2.f/lam;
      lamc[2*t+1] =  2.f/lam - 1.f;
    }
  }
}

// ---------------------------------------------------------------- Chebyshev SpMM (wave per row, lane = channel, XCD-swizzled)
__global__ __launch_bounds__(256) void k_cheb(const __hip_bfloat16* __restrict__ xin,
    const __hip_bfloat16* __restrict__ xb0, __hip_bfloat16* __restrict__ outp,
    const int* __restrict__ rp, const unsigned short* __restrict__ col,
    const float* __restrict__ dinv, const float* __restrict__ lamc, float s1, float s2)
{
  const int blk = blockIdx.x;               // 90000 = 8*11250
  const int w = (blk & 7)*11250 + (blk >> 3);
  const int gw = w*4 + (threadIdx.x >> 6);
  const int lane = threadIdx.x & 63;
  int t = gw / Mn, m = gw - t*Mn;
  float coef = lamc[2*t], diag = lamc[2*t+1];
  const __hip_bfloat16* xt = xin + (size_t)t*Mn*Hh;
  const float* dv = dinv + t*Mn;
  float acc = diag * bf2f(xt[(size_t)m*Hh + lane]);
  float cdm = coef * dv[m];
  int bgn = rp[t*(Mn+1)+m], end = rp[t*(Mn+1)+m+1];
  const unsigned short* cp = col + (size_t)t*Ee;
  int i = bgn;
  for (; i < end && (i & 3); ++i){ int c = cp[i]; acc += (cdm*dv[c])*bf2f(xt[(size_t)c*Hh + lane]); }
  for (; i + 4 <= end; i += 4){
    ushort4 c4 = *(const ushort4*)(cp + i);
    float w0 = cdm*dv[c4.x], w1 = cdm*dv[c4.y], w2 = cdm*dv[c4.z], w3 = cdm*dv[c4.w];
    acc += w0*bf2f(xt[(size_t)c4.x*Hh + lane]);
    acc += w1*bf2f(xt[(size_t)c4.y*Hh + lane]);
    acc += w2*bf2f(xt[(size_t)c4.z*Hh + lane]);
    acc += w3*bf2f(xt[(size_t)c4.w*Hh + lane]);
  }
  for (; i < end; ++i){ int c = cp[i]; acc += (cdm*dv[c])*bf2f(xt[(size_t)c*Hh + lane]); }
  float o = s1*acc;
  if (s2 != 0.f) o += s2*bf2f(xb0[(size_t)gw*Hh + lane]);
  outp[(size_t)gw*Hh + lane] = f2bf(o);
}

// ---------------------------------------------------------------- fold cheb_W into conv_W
__global__ void k_ww(const float* __restrict__ chebW, const float* __restrict__ chebb,
    const float* __restrict__ convW, const float* __restrict__ convb, float* __restrict__ WW, float* __restrict__ c0)
{
  int idx = blockIdx.x*256 + threadIdx.x;
  if (idx < 3*Tt*Hh*Oo){
    int oc = idx % Oo; int j = (idx/Oo) % Hh; int t = (idx/(Oo*Hh)) % Tt; int i = idx/(Oo*Hh*Tt);
    const float* cw = chebW + ((size_t)i*Hh + j)*HC + (HC-KW);
    const float* vw = convW + ((size_t)oc*Tt + t)*KW;
    float s = 0.f;
    for (int k = 0; k < KW; ++k) s += cw[k]*vw[k];
    WW[idx] = s;
  }
  if (blockIdx.x == 0 && threadIdx.x < Oo){
    int oc = threadIdx.x;
    float s = convb[oc];
    for (int t = 0; t < Tt; ++t){
      const float* vw = convW + ((size_t)oc*Tt + t)*KW;
      for (int k = 0; k < KW; ++k) s += chebb[(HC-KW)+k]*vw[k];
    }
    c0[oc] = s;
  }
}

// ---------------------------------------------------------------- fused cheb-GEMM + temporal conv + sigmoid
__global__ __launch_bounds__(256) void k_final(const __hip_bfloat16* __restrict__ tx0,
    const __hip_bfloat16* __restrict__ tx1, const __hip_bfloat16* __restrict__ tx2,
    const float* __restrict__ WW, const float* __restrict__ c0, float* __restrict__ outp)
{
  __shared__ float xs[64][65];
  __shared__ float ww[64][12];
  const int tid = threadIdx.x;
  const int n0 = blockIdx.x*64;
  const int n = tid & 63, ob = (tid >> 6)*3;
  float acc[3] = {0.f, 0.f, 0.f};
  for (int it = 0; it < 3*Tt; ++it){
    int ii = it / Tt, t = it % Tt;
    const __hip_bfloat16* tx = (ii == 0) ? tx0 : (ii == 1) ? tx1 : tx2;
    __syncthreads();
    for (int idx = tid; idx < 64*64; idx += 256){
      int mm = idx >> 6, j = idx & 63;
      int m = n0 + mm;
      xs[mm][j] = (m < Mn) ? bf2f(tx[((size_t)t*Mn + m)*Hh + j]) : 0.f;
    }
    for (int idx = tid; idx < 64*Oo; idx += 256)
      ((float*)ww)[idx] = WW[((size_t)(ii*Tt + t)*Hh)*Oo + idx];
    __syncthreads();
    #pragma unroll 8
    for (int j = 0; j < 64; ++j){
      float x = xs[n][j];
      acc[0] += x*ww[j][ob+0];
      acc[1] += x*ww[j][ob+1];
      acc[2] += x*ww[j][ob+2];
    }
  }
  int m = n0 + n;
  if (m < Mn){
    #pragma unroll
    for (int q = 0; q < 3; ++q) outp[(size_t)m*Oo + ob + q] = sigm(acc[q] + c0[ob+q]);
  }
}

// ================================================================ host
extern "C" void kernel_launch(void* const* d_in, const int* in_sizes, int n_in,
                              void* d_out, int out_size, void* d_ws, size_t ws_size,
                              hipStream_t stream)
{
  const float* nf    = (const float*)d_in[0];
  const int*   ei    = (const int*)d_in[1];
  const float* Wih0  = (const float*)d_in[2];
  const float* Whh0  = (const float*)d_in[3];
  const float* bih0  = (const float*)d_in[4];
  const float* bhh0  = (const float*)d_in[5];
  const float* Wih1  = (const float*)d_in[6];
  const float* Whh1  = (const float*)d_in[7];
  const float* bih1  = (const float*)d_in[8];
  const float* bhh1  = (const float*)d_in[9];
  const float* lns   = (const float*)d_in[10];
  const float* lnb   = (const float*)d_in[11];
  const float* chebW = (const float*)d_in[12];
  const float* chebb = (const float*)d_in[13];
  const float* convW = (const float*)d_in[14];
  const float* convb = (const float*)d_in[15];
  float* outp = (float*)d_out;

  char* base = (char*)d_ws;
  size_t off = 0;
  auto alloc = [&](size_t bytes)->char*{ char* p = base + off; off += (bytes + 255) & ~(size_t)255; return p; };

  __hip_bfloat16* y0  = (__hip_bfloat16*)alloc((size_t)Tt*Mn*C2*2);
  __hip_bfloat16* tx1 = y0;
  __hip_bfloat16* tx2 = y0 + (size_t)Tt*Mn*Hh;
  __hip_bfloat16* gi  = (__hip_bfloat16*)alloc((size_t)Tt*Mn*Gg*2);
  unsigned* pair = (unsigned*)gi;          // overlaps gi: pair dead before k_gi1m writes gi
  float* urb = (float*)gi;                 // power-iteration round buffers: (NRND+1)*Tt*Mn*4
                                           // = 110.9 MB <= gi's 138.2 MB (gi dead after k_gru1r)
  __hip_bfloat16* xbt = (__hip_bfloat16*)alloc((size_t)Tt*Mn*Hh*2);
  unsigned short* col16 = (unsigned short*)alloc((size_t)Tt*Ee*2);
  int*   deg  = (int*)alloc((size_t)Tt*Mn*4);
  int*   rp   = (int*)alloc((size_t)Tt*(Mn+1)*4);
  int*   bcnt = (int*)alloc((size_t)Tt*NB*4);
  int*   bfill= (int*)alloc((size_t)Tt*NB*4);
  int*   rpb  = (int*)alloc((size_t)Tt*(NB+1)*4);
  float* dinv = (float*)alloc((size_t)Tt*Mn*4);
  float* lamc = (float*)alloc((size_t)2*Tt*4);
  float* WW   = (float*)alloc((size_t)3*Tt*Hh*Oo*4);
  float* c0   = (float*)alloc((size_t)Oo*4);
  __hip_bfloat16* Wbf = (__hip_bfloat16*)alloc((size_t)Gg*C2*2);
  float* part  = (float*)alloc((size_t)Tt*CHK*32*4);  // 2 parity slots x 64B per block
  int*   flagA = (int*)alloc((size_t)Tt*CHK*16*4);    // phase-A epoch flags, 64B apart
  int*   flagB = (int*)alloc((size_t)Tt*CHK*16*4);    // phase-B epoch flags
  (void)ws_size; (void)in_sizes; (void)n_in; (void)out_size;

  // CSR build: bucket histogram -> bucket scan -> partition -> per-bucket counting sort (emits rp+deg)
  k_init<<<16, 256, 0, stream>>>(bcnt, bfill, flagA, flagB);
  k_bcnt<<<Tt*BPT, 256, 0, stream>>>(ei, bcnt);
  k_bscan<<<Tt, 256, 0, stream>>>(bcnt, rpb);
  k_part2<<<Tt*BPT, 256, 0, stream>>>(ei, rpb, bfill, pair);
  k_csr2<<<Tt*NB, 256, 0, stream>>>(rpb, pair, col16, rp, deg);
  k_dinv<<<(Tt*Mn + 255)/256, 256, 0, stream>>>(deg, dinv);

  // GRU stack (layer-1 forward direction is dead code -> skipped)
  k_wcvt<<<(Gg*C2 + 255)/256, 256, 0, stream>>>(Wih1 + (size_t)Gg*C2, Wbf);
  k_gru0<<<(Mn + 31)/32, 256, 0, stream>>>(nf, Wih0, Whh0, bih0, bhh0, y0);
  {
    int waves = Tt*((Mn + 31)/32);
    k_gi1m<<<(waves + 3)/4, 256, 0, stream>>>(y0, Wbf, bih1 + Gg, gi);
  }
  k_gru1r<<<(Mn + 31)/32, 256, 0, stream>>>(gi, Whh1 + (size_t)Gg*Hh, bhh1 + Gg, lns, lnb, xbt);

  // power iteration: 75 rounds + 1 Rayleigh round, fused into ONE kernel;
  // round-unique u buffers in the dead gi arena, A/B-phase flag barrier
  k_pitall<<<Tt*CHK, 1024, 0, stream>>>(rp, col16, urb, part, flagA, flagB, lamc);

  // Chebyshev: tx1 = Lhat(x), tx2 = 2*Lhat(tx1) - x
  k_cheb<<<(Tt*Mn)/4, 256, 0, stream>>>(xbt, xbt, tx1, rp, col16, dinv, lamc, 1.f, 0.f);
  k_cheb<<<(Tt*Mn)/4, 256, 0, stream>>>(tx1, xbt, tx2, rp, col16, dinv, lamc, 2.f, -1.f);

  // folded cheb-GEMM + conv + sigmoid
  k_ww<<<(3*Tt*Hh*Oo + 255)/256, 256, 0, stream>>>(chebW, chebb, convW, convb, WW, c0);
  k_final<<<(Mn + 63)/64, 256, 0, stream>>>(xbt, tx1, tx2, WW, c0, outp);
}

// Round 5
// 3016.274 us; speedup vs baseline: 1.4452x; 1.0211x over previous
//
#include <hip/hip_runtime.h>
#include <hip/hip_bf16.h>

#define DEV __device__ __forceinline__

constexpr int Mn  = 30000;   // nodes (B=1)
constexpr int Tt  = 12;
constexpr int CIN = 16;
constexpr int Hh  = 64;
constexpr int Gg  = 192;     // 3H
constexpr int C2  = 128;     // 2H
constexpr int Ee  = 960000;  // edges per timestep (bidirectional)
constexpr int HC  = 128;
constexpr int Oo  = 12;
constexpr int KW  = 128;
constexpr int HP  = 72;      // padded h row stride (floats)
constexpr int WP  = 194;     // padded weight row stride (bf16): bank stride 97 (odd) -> conflict-free
constexpr int XSP = 36;      // padded xs inner stride (floats): 16B-aligned, 2-way max
constexpr int NB  = 235;     // 128-row buckets per t (235*128 >= 30000)
constexpr int EPB = 8192;    // edges per block for bcnt/part2
constexpr int BPT = 118;     // ceil(Ee/EPB)
constexpr int CHK = 21;      // chunks per t for power iteration (252 blocks total)
constexpr int RC  = 1440;    // rows per chunk (16B-aligned chunk base; 21*1440 >= 30000)
constexpr int NRND= 76;      // 75 power rounds + 1 Rayleigh round
constexpr int NF4A= 21*256;  // phase-A float4 count (rows [r0, r0+1024) per chunk)
constexpr int NF4B= 20*104 + 44; // phase-B float4 count (rows [r0+1024, r1) per chunk)

DEV float bf2f(__hip_bfloat16 v){ return __bfloat162float(v); }
DEV __hip_bfloat16 f2bf(float v){ return __float2bfloat16(v); }
DEV float sigm(float x){ return __builtin_amdgcn_rcpf(1.f + __expf(-x)); }
DEV float tanh_f(float x){ return 1.f - 2.f*__builtin_amdgcn_rcpf(__expf(2.f*x) + 1.f); }

// agent-scope (device-coherent, sc1) accessors for cross-XCD flags/u-stores
DEV float aload_f(const float* p){ return __hip_atomic_load(p, __ATOMIC_RELAXED, __HIP_MEMORY_SCOPE_AGENT); }
DEV void  astore_f(float* p, float v){ __hip_atomic_store(p, v, __ATOMIC_RELAXED, __HIP_MEMORY_SCOPE_AGENT); }
DEV int   aload_i(const int* p){ return __hip_atomic_load(p, __ATOMIC_RELAXED, __HIP_MEMORY_SCOPE_AGENT); }
DEV void  astore_i(int* p, int v){ __hip_atomic_store(p, v, __ATOMIC_RELAXED, __HIP_MEMORY_SCOPE_AGENT); }
DEV unsigned long long aload_u64(const unsigned long long* p){ return __hip_atomic_load(p, __ATOMIC_RELAXED, __HIP_MEMORY_SCOPE_AGENT); }
DEV void astore_u64(unsigned long long* p, unsigned long long v){ __hip_atomic_store(p, v, __ATOMIC_RELAXED, __HIP_MEMORY_SCOPE_AGENT); }

typedef short bfrag8 __attribute__((ext_vector_type(8)));
typedef float ffrag4 __attribute__((ext_vector_type(4)));

// ---------------------------------------------------------------- init (flags + CSR counters only)
__global__ void k_init(int* bcnt, int* bfill, int* flagA, unsigned long long* pbB){
  int i = blockIdx.x*256 + threadIdx.x;
  if (i < Tt*CHK*16){ flagA[i] = 0; pbB[i] = 0ull; }
  if (i < Tt*NB){ bcnt[i] = 0; bfill[i] = 0; }
}

// ---------------------------------------------------------------- stage 1: block-aggregated bucket histogram
__global__ __launch_bounds__(256) void k_bcnt(const int* __restrict__ ei, int* __restrict__ bcnt){
  __shared__ int h[NB];
  const int b = blockIdx.x;                 // 1416 = 8*177
  const int w = (b & 7)*177 + (b >> 3);
  const int t = w / BPT, ch = w - t*BPT;
  const int e0 = ch*EPB;
  const int tid = threadIdx.x;
  for (int i = tid; i < NB; i += 256) h[i] = 0;
  __syncthreads();
  #pragma unroll
  for (int i = 0; i < 32; ++i){
    int e = e0 + i*256 + tid;
    if (e < Ee){
      int r = ei[(size_t)(t*2)*Ee + e];
      atomicAdd(&h[r >> 7], 1);
    }
  }
  __syncthreads();
  for (int i = tid; i < NB; i += 256){
    int c = h[i];
    if (c > 0) atomicAdd(&bcnt[t*NB + i], c);
  }
}

// ---------------------------------------------------------------- stage 2: per-t exclusive scan of bucket counts
__global__ __launch_bounds__(256) void k_bscan(const int* __restrict__ bcnt, int* __restrict__ rpb){
  int t = blockIdx.x, tid = threadIdx.x;
  __shared__ int ps[256];
  int v = (tid < NB) ? bcnt[t*NB + tid] : 0;
  ps[tid] = v;
  __syncthreads();
  for (int o = 1; o < 256; o <<= 1){
    int x = (tid >= o) ? ps[tid-o] : 0;
    __syncthreads();
    ps[tid] += x;
    __syncthreads();
  }
  if (tid < NB) rpb[t*(NB+1) + tid] = ps[tid] - v;
  if (tid == 255) rpb[t*(NB+1) + NB] = ps[NB-1];
}

// ---------------------------------------------------------------- stage 3: partition edges into buckets (block-aggregated reservations)
__global__ __launch_bounds__(256) void k_part2(const int* __restrict__ ei, const int* __restrict__ rpb,
    int* __restrict__ bfill, unsigned* __restrict__ pair){
  __shared__ int hcnt[NB];
  __shared__ int hbase[NB];
  const int b = blockIdx.x;                 // 1416 = 8*177
  const int w = (b & 7)*177 + (b >> 3);
  const int t = w / BPT, ch = w - t*BPT;
  const int e0 = ch*EPB;
  const int tid = threadIdx.x;
  for (int i = tid; i < NB; i += 256) hcnt[i] = 0;
  __syncthreads();
  unsigned key[32];
  #pragma unroll
  for (int i = 0; i < 32; ++i){
    int e = e0 + i*256 + tid;
    unsigned k = 0xFFFFFFFFu;
    if (e < Ee){
      int r = ei[(size_t)(t*2)*Ee + e];
      int c = ei[(size_t)(t*2+1)*Ee + e];
      k = ((unsigned)r << 16) | (unsigned)c;
      atomicAdd(&hcnt[r >> 7], 1);
    }
    key[i] = k;
  }
  __syncthreads();
  for (int i = tid; i < NB; i += 256){
    int cnt = hcnt[i];
    int base = (cnt > 0) ? atomicAdd(&bfill[t*NB + i], cnt) : 0;
    hbase[i] = rpb[t*(NB+1) + i] + base;
  }
  __syncthreads();
  for (int i = tid; i < NB; i += 256) hcnt[i] = 0;
  __syncthreads();
  #pragma unroll
  for (int i = 0; i < 32; ++i){
    unsigned k = key[i];
    if (k != 0xFFFFFFFFu){
      int r = (int)(k >> 16);
      int bk = r >> 7;
      int pos = atomicAdd(&hcnt[bk], 1);
      pair[(size_t)t*Ee + hbase[bk] + pos] = ((unsigned)(r & 127) << 16) | (k & 0xFFFFu);
    }
  }
}

// ---------------------------------------------------------------- stage 4: per-bucket LDS counting sort -> col16, rp, deg
__global__ __launch_bounds__(256) void k_csr2(const int* __restrict__ rpb, const unsigned* __restrict__ pair,
    unsigned short* __restrict__ col16, int* __restrict__ rp, int* __restrict__ deg){
  __shared__ unsigned short cols_s[9216];
  __shared__ int lcnt[128], lfill[128];
  __shared__ int ps[256];
  const int blk = blockIdx.x;               // Tt*NB
  const int t = blk / NB, bk = blk - t*NB;
  const int r0 = bk << 7;
  const int nr = (r0 + 128 <= Mn) ? 128 : (Mn - r0);
  const int base = rpb[t*(NB+1) + bk];
  const int cnt  = rpb[t*(NB+1) + bk + 1] - base;
  const int tid = threadIdx.x;
  if (tid < 128) lcnt[tid] = 0;
  __syncthreads();
  for (int i = tid; i < cnt; i += 256){
    unsigned v = pair[(size_t)t*Ee + base + i];
    atomicAdd(&lcnt[v >> 16], 1);
  }
  __syncthreads();
  int v2 = (tid < 128) ? lcnt[tid] : 0;
  ps[tid] = v2;
  __syncthreads();
  for (int o = 1; o < 128; o <<= 1){
    int x = (tid >= o) ? ps[tid-o] : 0;
    __syncthreads();
    ps[tid] += x;
    __syncthreads();
  }
  if (tid < 128){
    int excl = ps[tid] - v2;
    lfill[tid] = excl;
    if (tid < nr){
      rp[t*(Mn+1) + r0 + tid] = base + excl;
      deg[t*Mn + r0 + tid] = v2;
    }
  }
  if (bk == NB-1 && tid == 0) rp[t*(Mn+1) + Mn] = base + cnt;
  __syncthreads();
  for (int i = tid; i < cnt; i += 256){
    unsigned v = pair[(size_t)t*Ee + base + i];
    int pos = atomicAdd(&lfill[v >> 16], 1);
    cols_s[pos] = (unsigned short)(v & 0xFFFFu);
  }
  __syncthreads();
  for (int i = tid; i < cnt; i += 256)
    col16[(size_t)t*Ee + base + i] = cols_s[i];
}

// ---------------------------------------------------------------- dinv
__global__ void k_dinv(const int* __restrict__ deg, float* __restrict__ dinv){
  int i = blockIdx.x*256 + threadIdx.x;
  if (i < Tt*Mn){ int d = deg[i]; dinv[i] = (d > 0) ? rsqrtf((float)d) : 0.f; }
}

// ---------------------------------------------------------------- GRU layer 0 (both dirs), writes y0 (T,M,128) bf16
__global__ __launch_bounds__(256) void k_gru0(
    const float* __restrict__ nf, const float* __restrict__ Wih, const float* __restrict__ Whh,
    const float* __restrict__ bih, const float* __restrict__ bhh, __hip_bfloat16* __restrict__ y0)
{
  __shared__ float xs[Tt][CIN][XSP];
  __shared__ __hip_bfloat16 wi[CIN][WP];
  __shared__ __hip_bfloat16 wh[Hh][WP];
  __shared__ float hb[32][HP];
  __shared__ float bi[Gg], bh[Gg];
  const int tid = threadIdx.x;
  const int m0  = blockIdx.x*32;
  for (int idx = tid; idx < Tt*32*CIN; idx += 256){
    int t = idx / (32*CIN); int rr = (idx / CIN) & 31; int k = idx & (CIN-1);
    int m = m0 + rr;
    xs[t][k][rr] = (m < Mn) ? nf[((size_t)t*Mn + m)*CIN + k] : 0.f;
  }
  const int jg = tid & 31, rg = tid >> 5;
  const int j0 = jg*2, rg4 = rg*4;
  for (int d = 0; d < 2; ++d){
    __syncthreads();
    for (int idx = tid; idx < Gg*CIN; idx += 256){
      int g = idx / CIN, k = idx & (CIN-1);
      wi[k][g] = f2bf(Wih[((size_t)d*Gg + g)*CIN + k]);
    }
    for (int idx = tid; idx < Gg*Hh; idx += 256){
      int g = idx >> 6, k = idx & 63;
      wh[k][g] = f2bf(Whh[((size_t)d*Gg + g)*Hh + k]);
    }
    if (tid < Gg){ bi[tid] = bih[d*Gg + tid]; bh[tid] = bhh[d*Gg + tid]; }
    for (int idx = tid; idx < 32*HP; idx += 256) ((float*)hb)[idx] = 0.f;
    __syncthreads();
    for (int step = 0; step < Tt; ++step){
      int t = d ? (Tt-1-step) : step;
      float ar[4][2], az[4][2], ai[4][2], ah[4][2];
      #pragma unroll
      for (int i = 0; i < 4; ++i){
        #pragma unroll
        for (int jj = 0; jj < 2; ++jj){
          int j = j0 + jj;
          ar[i][jj] = bi[j] + bh[j];
          az[i][jj] = bi[Hh+j] + bh[Hh+j];
          ai[i][jj] = bi[2*Hh+j];
          ah[i][jj] = bh[2*Hh+j];
        }
      }
      #pragma unroll
      for (int k = 0; k < CIN; ++k){
        float4 xv4 = *(const float4*)&xs[t][k][rg4];
        float xv[4] = {xv4.x, xv4.y, xv4.z, xv4.w};
        __hip_bfloat162 pr = *(const __hip_bfloat162*)&wi[k][j0];
        __hip_bfloat162 pz = *(const __hip_bfloat162*)&wi[k][Hh+j0];
        __hip_bfloat162 pn = *(const __hip_bfloat162*)&wi[k][2*Hh+j0];
        float wr[2] = {bf2f(pr.x), bf2f(pr.y)};
        float wz[2] = {bf2f(pz.x), bf2f(pz.y)};
        float wn[2] = {bf2f(pn.x), bf2f(pn.y)};
        #pragma unroll
        for (int i = 0; i < 4; ++i){
          #pragma unroll
          for (int jj = 0; jj < 2; ++jj){
            ar[i][jj] += xv[i]*wr[jj];
            az[i][jj] += xv[i]*wz[jj];
            ai[i][jj] += xv[i]*wn[jj];
          }
        }
      }
      #pragma unroll 4
      for (int k4 = 0; k4 < 16; ++k4){
        float4 h0 = *(const float4*)&hb[rg4+0][k4*4];
        float4 h1 = *(const float4*)&hb[rg4+1][k4*4];
        float4 h2 = *(const float4*)&hb[rg4+2][k4*4];
        float4 h3 = *(const float4*)&hb[rg4+3][k4*4];
        #pragma unroll
        for (int kk = 0; kk < 4; ++kk){
          int k = k4*4 + kk;
          float hv[4] = { ((const float*)&h0)[kk], ((const float*)&h1)[kk],
                          ((const float*)&h2)[kk], ((const float*)&h3)[kk] };
          __hip_bfloat162 pr = *(const __hip_bfloat162*)&wh[k][j0];
          __hip_bfloat162 pz = *(const __hip_bfloat162*)&wh[k][Hh+j0];
          __hip_bfloat162 pn = *(const __hip_bfloat162*)&wh[k][2*Hh+j0];
          float wr[2] = {bf2f(pr.x), bf2f(pr.y)};
          float wz[2] = {bf2f(pz.x), bf2f(pz.y)};
          float wn[2] = {bf2f(pn.x), bf2f(pn.y)};
          #pragma unroll
          for (int i = 0; i < 4; ++i){
            #pragma unroll
            for (int jj = 0; jj < 2; ++jj){
              ar[i][jj] += hv[i]*wr[jj];
              az[i][jj] += hv[i]*wz[jj];
              ah[i][jj] += hv[i]*wn[jj];
            }
          }
        }
      }
      __syncthreads();
      #pragma unroll
      for (int i = 0; i < 4; ++i){
        int r = rg4 + i; int m = m0 + r;
        float hn2[2];
        #pragma unroll
        for (int jj = 0; jj < 2; ++jj){
          float rr = sigm(ar[i][jj]);
          float zz = sigm(az[i][jj]);
          float nn = tanh_f(ai[i][jj] + rr*ah[i][jj]);
          float hv = hb[r][j0+jj];
          hn2[jj] = (1.f-zz)*nn + zz*hv;
          hb[r][j0+jj] = hn2[jj];
        }
        if (m < Mn){
          __hip_bfloat162 pk; pk.x = f2bf(hn2[0]); pk.y = f2bf(hn2[1]);
          *(__hip_bfloat162*)&y0[((size_t)t*Mn + m)*C2 + d*Hh + j0] = pk;
        }
      }
      __syncthreads();
    }
  }
}

// ---------------------------------------------------------------- convert layer-1 reverse weights to bf16
__global__ void k_wcvt(const float* __restrict__ W, __hip_bfloat16* __restrict__ Wbf){
  int i = blockIdx.x*256 + threadIdx.x;
  if (i < Gg*C2) Wbf[i] = f2bf(W[i]);
}

// ---------------------------------------------------------------- layer-1 input projection via MFMA
__global__ __launch_bounds__(256) void k_gi1m(const __hip_bfloat16* __restrict__ y0,
    const __hip_bfloat16* __restrict__ Wbf, const float* __restrict__ bih, __hip_bfloat16* __restrict__ gi)
{
  const int wid  = (blockIdx.x*256 + threadIdx.x) >> 6;
  const int lane = threadIdx.x & 63;
  const int SEGS = (Mn + 31)/32;
  if (wid >= Tt*SEGS) return;
  const int t = wid / SEGS, seg = wid - t*SEGS;
  const int m0 = seg*32;
  const int lr = lane & 15, lq = lane >> 4;
  const __hip_bfloat16* yb = y0 + (size_t)t*Mn*C2;

  ffrag4 acc[2][12];
  #pragma unroll
  for (int i = 0; i < 2; ++i){
    #pragma unroll
    for (int n = 0; n < 12; ++n) acc[i][n] = (ffrag4){0.f,0.f,0.f,0.f};
  }
  #pragma unroll
  for (int ks = 0; ks < 4; ++ks){
    const int ko = ks*32 + lq*8;
    bfrag8 a0 = *(const bfrag8*)(yb + (size_t)(m0 + lr     )*C2 + ko);
    bfrag8 a1 = *(const bfrag8*)(yb + (size_t)(m0 + 16 + lr)*C2 + ko);
    #pragma unroll
    for (int nt = 0; nt < 12; ++nt){
      bfrag8 b = *(const bfrag8*)(Wbf + (size_t)(nt*16 + lr)*C2 + ko);
      acc[0][nt] = __builtin_amdgcn_mfma_f32_16x16x32_bf16(a0, b, acc[0][nt], 0, 0, 0);
      acc[1][nt] = __builtin_amdgcn_mfma_f32_16x16x32_bf16(a1, b, acc[1][nt], 0, 0, 0);
    }
  }
  #pragma unroll
  for (int nt = 0; nt < 12; ++nt){
    int g = nt*16 + lr;
    float bb = bih[g];
    #pragma unroll
    for (int r = 0; r < 4; ++r){
      int mm0 = m0 + lq*4 + r;
      int mm1 = mm0 + 16;
      if (mm0 < Mn) gi[((size_t)t*Mn + mm0)*Gg + g] = f2bf(acc[0][nt][r] + bb);
      if (mm1 < Mn) gi[((size_t)t*Mn + mm1)*Gg + g] = f2bf(acc[1][nt][r] + bb);
    }
  }
}

// ---------------------------------------------------------------- GRU layer 1 (reverse only) + fused LayerNorm
__global__ __launch_bounds__(256) void k_gru1r(const __hip_bfloat16* __restrict__ gi,
    const float* __restrict__ Whh, const float* __restrict__ bhh,
    const float* __restrict__ lns, const float* __restrict__ lnb,
    __hip_bfloat16* __restrict__ xbt)
{
  __shared__ __hip_bfloat16 wh[Hh][WP];
  __shared__ float hb[32][HP];
  __shared__ float bh[Gg];
  __shared__ float sc[Hh], bs[Hh];
  const int tid = threadIdx.x;
  const int m0  = blockIdx.x*32;
  for (int idx = tid; idx < Gg*Hh; idx += 256){
    int g = idx >> 6, k = idx & 63;
    wh[k][g] = f2bf(Whh[(size_t)g*Hh + k]);
  }
  if (tid < Gg) bh[tid] = bhh[tid];
  if (tid < Hh){ sc[tid] = lns[tid]; bs[tid] = lnb[tid]; }
  for (int idx = tid; idx < 32*HP; idx += 256) ((float*)hb)[idx] = 0.f;
  __syncthreads();
  const int jg = tid & 31, rg = tid >> 5;
  const int j0 = jg*2, rg4 = rg*4;
  for (int step = 0; step < Tt; ++step){
    int t = Tt-1-step;
    float ar[4][2], az[4][2], ai[4][2], ah[4][2];
    #pragma unroll
    for (int i = 0; i < 4; ++i){
      int m = m0 + rg4 + i;
      int mc = (m < Mn) ? m : 0;
      const __hip_bfloat16* gp = gi + ((size_t)t*Mn + mc)*Gg;
      __hip_bfloat162 pr = *(const __hip_bfloat162*)&gp[j0];
      __hip_bfloat162 pz = *(const __hip_bfloat162*)&gp[Hh+j0];
      __hip_bfloat162 pn = *(const __hip_bfloat162*)&gp[2*Hh+j0];
      #pragma unroll
      for (int jj = 0; jj < 2; ++jj){
        int j = j0 + jj;
        float gr = jj ? bf2f(pr.y) : bf2f(pr.x);
        float gz = jj ? bf2f(pz.y) : bf2f(pz.x);
        float gn = jj ? bf2f(pn.y) : bf2f(pn.x);
        ar[i][jj] = gr + bh[j];
        az[i][jj] = gz + bh[Hh+j];
        ai[i][jj] = gn;
        ah[i][jj] = bh[2*Hh+j];
      }
    }
    #pragma unroll 4
    for (int k4 = 0; k4 < 16; ++k4){
      float4 h0 = *(const float4*)&hb[rg4+0][k4*4];
      float4 h1 = *(const float4*)&hb[rg4+1][k4*4];
      float4 h2 = *(const float4*)&hb[rg4+2][k4*4];
      float4 h3 = *(const float4*)&hb[rg4+3][k4*4];
      #pragma unroll
      for (int kk = 0; kk < 4; ++kk){
        int k = k4*4 + kk;
        float hv[4] = { ((const float*)&h0)[kk], ((const float*)&h1)[kk],
                        ((const float*)&h2)[kk], ((const float*)&h3)[kk] };
        __hip_bfloat162 pr = *(const __hip_bfloat162*)&wh[k][j0];
        __hip_bfloat162 pz = *(const __hip_bfloat162*)&wh[k][Hh+j0];
        __hip_bfloat162 pn = *(const __hip_bfloat162*)&wh[k][2*Hh+j0];
        float wr[2] = {bf2f(pr.x), bf2f(pr.y)};
        float wz[2] = {bf2f(pz.x), bf2f(pz.y)};
        float wn[2] = {bf2f(pn.x), bf2f(pn.y)};
        #pragma unroll
        for (int i = 0; i < 4; ++i){
          #pragma unroll
          for (int jj = 0; jj < 2; ++jj){
            ar[i][jj] += hv[i]*wr[jj];
            az[i][jj] += hv[i]*wz[jj];
            ah[i][jj] += hv[i]*wn[jj];
          }
        }
      }
    }
    __syncthreads();
    #pragma unroll
    for (int i = 0; i < 4; ++i){
      int r = rg4 + i;
      #pragma unroll
      for (int jj = 0; jj < 2; ++jj){
        float rr = sigm(ar[i][jj]);
        float zz = sigm(az[i][jj]);
        float nn = tanh_f(ai[i][jj] + rr*ah[i][jj]);
        float hv = hb[r][j0+jj];
        hb[r][j0+jj] = (1.f-zz)*nn + zz*hv;
      }
    }
    __syncthreads();
    {
      int r = tid >> 3, l = tid & 7;
      float vals[8];
      float s1 = 0.f, s2 = 0.f;
      #pragma unroll
      for (int q = 0; q < 8; ++q){ float v = hb[r][l + 8*q]; vals[q] = v; s1 += v; s2 += v*v; }
      #pragma unroll
      for (int off = 1; off <= 4; off <<= 1){ s1 += __shfl_xor(s1, off); s2 += __shfl_xor(s2, off); }
      float mu  = s1 * (1.f/64.f);
      float var = s2 * (1.f/64.f) - mu*mu;
      float rs  = rsqrtf(var + 1e-5f);
      int m = m0 + r;
      if (m < Mn){
        __hip_bfloat16* op = xbt + ((size_t)t*Mn + m)*Hh;
        #pragma unroll
        for (int q = 0; q < 8; ++q){ int j = l + 8*q; op[j] = f2bf((vals[q]-mu)*rs*sc[j] + bs[j]); }
      }
    }
    __syncthreads();
  }
}

// ---------------------------------------------------------------- fused power iteration: all 76 rounds in ONE kernel.
// 252 blocks, 120KB LDS -> 1 block/CU -> all co-resident.
// R5 sync streamline: (1) ONLY WAVE 0 polls the cross-die flags (sc1 loads
// bypass caches, so R4's 16-waves-polling = 16x redundant fabric traffic
// hammering the 12x21 flag lines -> self-inflicted contention). Waves 1-15
// spin on a monotonic LDS word released by wave 0. (2) Norm^2 partial and
// epoch are PACKED into one u64 slot (2 parity slots/block, 64B apart): the
// successful poll load already carries the partials -> separate partial
// gather + ordering waitcnt + two-store publish all removed. Staging layout,
// A/B phasing, round-unique u buffers and all per-row math identical to R4.
__global__ __launch_bounds__(1024) void k_pitall(const int* __restrict__ rp,
    const unsigned short* __restrict__ col, float* __restrict__ urb,
    int* __restrict__ flagA, unsigned long long* __restrict__ pbB,
    float* __restrict__ lamc)
{
  __shared__ alignas(16) float u_s[Mn];     // 120000 B
  __shared__ float redw[16];
  __shared__ float s_nrm;
  __shared__ int s_goA, s_goB;
  const int b = blockIdx.x;                 // Tt*CHK = 252
  const int t = b / CHK, ch = b - t*CHK;
  const int r0 = ch*RC;
  const int r1 = (r0 + RC < Mn) ? r0 + RC : Mn;
  const int tid = threadIdx.x;
  const int lane = tid & 63;
  const int wv   = tid >> 6;                // wave id 0..15
  const unsigned short* cp = col + (size_t)t*Ee;
  const int fS = t*CHK*16;                  // flagA slots: u32, 64B apart
  const int pB = t*CHK*16;                  // pbB slots: u64, per block 2 parity x 64B
  const int m0r = r0 + tid;                 // phase-A row
  const int m1r = m0r + 1024;               // phase-B row
  int rb0 = 0, re0 = 0, rb1 = 0, re1 = 0;
  {
    const int* rpt = rp + t*(Mn+1);
    if (m0r < r1){ rb0 = rpt[m0r]; re0 = rpt[m0r+1]; }
    if (m1r < r1){ rb1 = rpt[m1r]; re1 = rpt[m1r+1]; }
  }
  if (tid == 0){ s_nrm = 1.0f; s_goA = 0; s_goB = 0; }
  __syncthreads();
  for (int r = 1; r <= NRND; ++r){
    const int fin = (r == NRND);
    if (r == 1){
      // u^0 is a constant: fill LDS directly, no staging, no polls
      for (int i = tid; i < Mn; i += 1024) u_s[i] = 0.005773502691896258f;
    } else {
      const int rr = r - 1;
      const float4* u4 = (const float4*)(urb + (size_t)rr*(Tt*Mn) + (size_t)t*Mn);
      float4* s4 = (float4*)u_s;
      // ---- phase A gate: wave 0 polls fabric, others spin on LDS
      if (wv == 0){
        const bool mine = lane < CHK;
        for (;;){ int v = mine ? aload_i(&flagA[fS + lane*16]) : 0x7FFFFFFF;
                  if (__all(v >= rr)) break; __builtin_amdgcn_s_sleep(4); }
        if (lane == 0) __hip_atomic_store(&s_goA, rr, __ATOMIC_RELAXED, __HIP_MEMORY_SCOPE_WORKGROUP);
      } else {
        while (__hip_atomic_load(&s_goA, __ATOMIC_RELAXED, __HIP_MEMORY_SCOPE_WORKGROUP) < rr)
          __builtin_amdgcn_s_sleep(2);
      }
      asm volatile("" ::: "memory");        // no hoisting of stage loads above gate
      for (int i = tid; i < NF4A; i += 1024){
        int idx = (i >> 8)*360 + (i & 255); // 256 f4 per chunk, chunk stride 360 f4
        s4[idx] = u4[idx];
      }
      // ---- phase B gate: poll packed {epoch, partial} u64 slots
      unsigned long long pv = 0;
      if (wv == 0){
        const bool mine = lane < CHK;
        for (;;){ pv = mine ? aload_u64(&pbB[(size_t)(pB + lane*16) + (rr & 1)*8])
                            : ((unsigned long long)rr << 32);
                  if (__all((int)(pv >> 32) == rr)) break; __builtin_amdgcn_s_sleep(4); }
        if (lane == 0) __hip_atomic_store(&s_goB, rr, __ATOMIC_RELAXED, __HIP_MEMORY_SCOPE_WORKGROUP);
      } else {
        while (__hip_atomic_load(&s_goB, __ATOMIC_RELAXED, __HIP_MEMORY_SCOPE_WORKGROUP) < rr)
          __builtin_amdgcn_s_sleep(2);
      }
      asm volatile("" ::: "memory");
      for (int i = tid; i < NF4B; i += 1024){
        int ck = i/104, off = i - ck*104;   // 104 f4 per full chunk tail, last=44
        int idx = ck*360 + 256 + off;
        s4[idx] = u4[idx];
      }
      // wave 0 already holds the 21 partials from the poll load: reduce -> s_nrm
      if (wv == 0){
        float p = (lane < CHK) ? __uint_as_float((unsigned)pv) : 0.f;
        #pragma unroll
        for (int o2 = 1; o2 < 32; o2 <<= 1) p += __shfl_xor(p, o2);
        if (tid == 0) s_nrm = p;
      }
    }
    __syncthreads();                         // staging + s_nrm visible
    const float inv_s = fin ? 1.f : 1.f/(sqrtf(s_nrm) + 1e-12f);
    float* u_ot = urb + (size_t)r*(Tt*Mn);
    float local = 0.f;
    // ---- phase A rows
    if (m0r < r1){
      float s = 0.f;
      int i = rb0;
      for (; i < re0 && (i & 3); ++i) s += u_s[cp[i]];
      for (; i + 4 <= re0; i += 4){
        ushort4 c4 = *(const ushort4*)(cp + i);
        s += (u_s[c4.x] + u_s[c4.y]) + (u_s[c4.z] + u_s[c4.w]);
      }
      for (; i < re0; ++i) s += u_s[cp[i]];
      float uv = u_s[m0r];
      float wv2 = (float)(re0 - rb0)*uv - s;
      if (!fin){ float o = inv_s*wv2; astore_f(&u_ot[t*Mn + m0r], o); local += o*o; }
      else local += uv*wv2;
    }
    asm volatile("s_waitcnt vmcnt(0)" ::: "memory");  // own A-stores acked at L3
    __syncthreads();                                  // all waves' A-stores drained
    if (tid == 0) astore_i(&flagA[fS + ch*16], r);    // publish phase A
    // ---- phase B rows
    if (m1r < r1){
      float s = 0.f;
      int i = rb1;
      for (; i < re1 && (i & 3); ++i) s += u_s[cp[i]];
      for (; i + 4 <= re1; i += 4){
        ushort4 c4 = *(const ushort4*)(cp + i);
        s += (u_s[c4.x] + u_s[c4.y]) + (u_s[c4.z] + u_s[c4.w]);
      }
      for (; i < re1; ++i) s += u_s[cp[i]];
      float uv = u_s[m1r];
      float wv2 = (float)(re1 - rb1)*uv - s;
      if (!fin){ float o = inv_s*wv2; astore_f(&u_ot[t*Mn + m1r], o); local += o*o; }
      else local += uv*wv2;
    }
    #pragma unroll
    for (int o2 = 1; o2 < 64; o2 <<= 1) local += __shfl_xor(local, o2);
    if ((tid & 63) == 0) redw[tid >> 6] = local;
    asm volatile("s_waitcnt vmcnt(0)" ::: "memory");  // own B-stores acked
    __syncthreads();                                  // all drained + redw visible
    if (tid < 64){
      float tot = (tid < 16) ? redw[tid] : 0.f;
      #pragma unroll
      for (int o2 = 1; o2 < 16; o2 <<= 1) tot += __shfl_xor(tot, o2);
      if (tid == 0){
        unsigned long long out = ((unsigned long long)r << 32)
                               | (unsigned long long)__float_as_uint(tot);
        astore_u64(&pbB[(size_t)(pB + ch*16) + (r & 1)*8], out);  // single-store publish
      }
    }
  }
  // folded lamfin: only ch==0 waits for the final packed partials
  if (ch == 0 && tid < 64){
    const bool mine = lane < CHK;
    unsigned long long pv = 0;
    for (;;){ pv = mine ? aload_u64(&pbB[(size_t)(pB + lane*16) + (NRND & 1)*8])
                        : ((unsigned long long)NRND << 32);
              if (__all((int)(pv >> 32) == NRND)) break; __builtin_amdgcn_s_sleep(4); }
    float p = mine ? __uint_as_float((unsigned)pv) : 0.f;
    #pragma unroll
    for (int o2 = 1; o2 < 32; o2 <<= 1) p += __shfl_xor(p, o2);
    if (tid == 0){
      float nn = sqrtf(s_nrm) + 1e-12f;     // s_nrm = ||w||^2 of round 75
      float lam = p / (nn*nn);
      lamc[2*t+0] = -2.f/lam;
      lamc[2*t+1] =  2.f/lam - 1.f;
    }
  }
}

// ---------------------------------------------------------------- Chebyshev SpMM (wave per row, lane = channel, XCD-swizzled)
__global__ __launch_bounds__(256) void k_cheb(const __hip_bfloat16* __restrict__ xin,
    const __hip_bfloat16* __restrict__ xb0, __hip_bfloat16* __restrict__ outp,
    const int* __restrict__ rp, const unsigned short* __restrict__ col,
    const float* __restrict__ dinv, const float* __restrict__ lamc, float s1, float s2)
{
  const int blk = blockIdx.x;               // 90000 = 8*11250
  const int w = (blk & 7)*11250 + (blk >> 3);
  const int gw = w*4 + (threadIdx.x >> 6);
  const int lane = threadIdx.x & 63;
  int t = gw / Mn, m = gw - t*Mn;
  float coef = lamc[2*t], diag = lamc[2*t+1];
  const __hip_bfloat16* xt = xin + (size_t)t*Mn*Hh;
  const float* dv = dinv + t*Mn;
  float acc = diag * bf2f(xt[(size_t)m*Hh + lane]);
  float cdm = coef * dv[m];
  int bgn = rp[t*(Mn+1)+m], end = rp[t*(Mn+1)+m+1];
  const unsigned short* cp = col + (size_t)t*Ee;
  int i = bgn;
  for (; i < end && (i & 3); ++i){ int c = cp[i]; acc += (cdm*dv[c])*bf2f(xt[(size_t)c*Hh + lane]); }
  for (; i + 4 <= end; i += 4){
    ushort4 c4 = *(const ushort4*)(cp + i);
    float w0 = cdm*dv[c4.x], w1 = cdm*dv[c4.y], w2 = cdm*dv[c4.z], w3 = cdm*dv[c4.w];
    acc += w0*bf2f(xt[(size_t)c4.x*Hh + lane]);
    acc += w1*bf2f(xt[(size_t)c4.y*Hh + lane]);
    acc += w2*bf2f(xt[(size_t)c4.z*Hh + lane]);
    acc += w3*bf2f(xt[(size_t)c4.w*Hh + lane]);
  }
  for (; i < end; ++i){ int c = cp[i]; acc += (cdm*dv[c])*bf2f(xt[(size_t)c*Hh + lane]); }
  float o = s1*acc;
  if (s2 != 0.f) o += s2*bf2f(xb0[(size_t)gw*Hh + lane]);
  outp[(size_t)gw*Hh + lane] = f2bf(o);
}

// ---------------------------------------------------------------- fold cheb_W into conv_W
__global__ void k_ww(const float* __restrict__ chebW, const float* __restrict__ chebb,
    const float* __restrict__ convW, const float* __restrict__ convb, float* __restrict__ WW, float* __restrict__ c0)
{
  int idx = blockIdx.x*256 + threadIdx.x;
  if (idx < 3*Tt*Hh*Oo){
    int oc = idx % Oo; int j = (idx/Oo) % Hh; int t = (idx/(Oo*Hh)) % Tt; int i = idx/(Oo*Hh*Tt);
    const float* cw = chebW + ((size_t)i*Hh + j)*HC + (HC-KW);
    const float* vw = convW + ((size_t)oc*Tt + t)*KW;
    float s = 0.f;
    for (int k = 0; k < KW; ++k) s += cw[k]*vw[k];
    WW[idx] = s;
  }
  if (blockIdx.x == 0 && threadIdx.x < Oo){
    int oc = threadIdx.x;
    float s = convb[oc];
    for (int t = 0; t < Tt; ++t){
      const float* vw = convW + ((size_t)oc*Tt + t)*KW;
      for (int k = 0; k < KW; ++k) s += chebb[(HC-KW)+k]*vw[k];
    }
    c0[oc] = s;
  }
}

// ---------------------------------------------------------------- fused cheb-GEMM + temporal conv + sigmoid
__global__ __launch_bounds__(256) void k_final(const __hip_bfloat16* __restrict__ tx0,
    const __hip_bfloat16* __restrict__ tx1, const __hip_bfloat16* __restrict__ tx2,
    const float* __restrict__ WW, const float* __restrict__ c0, float* __restrict__ outp)
{
  __shared__ float xs[64][65];
  __shared__ float ww[64][12];
  const int tid = threadIdx.x;
  const int n0 = blockIdx.x*64;
  const int n = tid & 63, ob = (tid >> 6)*3;
  float acc[3] = {0.f, 0.f, 0.f};
  for (int it = 0; it < 3*Tt; ++it){
    int ii = it / Tt, t = it % Tt;
    const __hip_bfloat16* tx = (ii == 0) ? tx0 : (ii == 1) ? tx1 : tx2;
    __syncthreads();
    for (int idx = tid; idx < 64*64; idx += 256){
      int mm = idx >> 6, j = idx & 63;
      int m = n0 + mm;
      xs[mm][j] = (m < Mn) ? bf2f(tx[((size_t)t*Mn + m)*Hh + j]) : 0.f;
    }
    for (int idx = tid; idx < 64*Oo; idx += 256)
      ((float*)ww)[idx] = WW[((size_t)(ii*Tt + t)*Hh)*Oo + idx];
    __syncthreads();
    #pragma unroll 8
    for (int j = 0; j < 64; ++j){
      float x = xs[n][j];
      acc[0] += x*ww[j][ob+0];
      acc[1] += x*ww[j][ob+1];
      acc[2] += x*ww[j][ob+2];
    }
  }
  int m = n0 + n;
  if (m < Mn){
    #pragma unroll
    for (int q = 0; q < 3; ++q) outp[(size_t)m*Oo + ob + q] = sigm(acc[q] + c0[ob+q]);
  }
}

// ================================================================ host
extern "C" void kernel_launch(void* const* d_in, const int* in_sizes, int n_in,
                              void* d_out, int out_size, void* d_ws, size_t ws_size,
                              hipStream_t stream)
{
  const float* nf    = (const float*)d_in[0];
  const int*   ei    = (const int*)d_in[1];
  const float* Wih0  = (const float*)d_in[2];
  const float* Whh0  = (const float*)d_in[3];
  const float* bih0  = (const float*)d_in[4];
  const float* bhh0  = (const float*)d_in[5];
  const float* Wih1  = (const float*)d_in[6];
  const float* Whh1  = (const float*)d_in[7];
  const float* bih1  = (const float*)d_in[8];
  const float* bhh1  = (const float*)d_in[9];
  const float* lns   = (const float*)d_in[10];
  const float* lnb   = (const float*)d_in[11];
  const float* chebW = (const float*)d_in[12];
  const float* chebb = (const float*)d_in[13];
  const float* convW = (const float*)d_in[14];
  const float* convb = (const float*)d_in[15];
  float* outp = (float*)d_out;

  char* base = (char*)d_ws;
  size_t off = 0;
  auto alloc = [&](size_t bytes)->char*{ char* p = base + off; off += (bytes + 255) & ~(size_t)255; return p; };

  __hip_bfloat16* y0  = (__hip_bfloat16*)alloc((size_t)Tt*Mn*C2*2);
  __hip_bfloat16* tx1 = y0;
  __hip_bfloat16* tx2 = y0 + (size_t)Tt*Mn*Hh;
  __hip_bfloat16* gi  = (__hip_bfloat16*)alloc((size_t)Tt*Mn*Gg*2);
  unsigned* pair = (unsigned*)gi;          // overlaps gi: pair dead before k_gi1m writes gi
  float* urb = (float*)gi;                 // power-iteration round buffers: (NRND+1)*Tt*Mn*4
                                           // = 110.9 MB <= gi's 138.2 MB (gi dead after k_gru1r)
  __hip_bfloat16* xbt = (__hip_bfloat16*)alloc((size_t)Tt*Mn*Hh*2);
  unsigned short* col16 = (unsigned short*)alloc((size_t)Tt*Ee*2);
  int*   deg  = (int*)alloc((size_t)Tt*Mn*4);
  int*   rp   = (int*)alloc((size_t)Tt*(Mn+1)*4);
  int*   bcnt = (int*)alloc((size_t)Tt*NB*4);
  int*   bfill= (int*)alloc((size_t)Tt*NB*4);
  int*   rpb  = (int*)alloc((size_t)Tt*(NB+1)*4);
  float* dinv = (float*)alloc((size_t)Tt*Mn*4);
  float* lamc = (float*)alloc((size_t)2*Tt*4);
  float* WW   = (float*)alloc((size_t)3*Tt*Hh*Oo*4);
  float* c0   = (float*)alloc((size_t)Oo*4);
  __hip_bfloat16* Wbf = (__hip_bfloat16*)alloc((size_t)Gg*C2*2);
  int*   flagA = (int*)alloc((size_t)Tt*CHK*16*4);              // phase-A epoch flags, 64B apart
  unsigned long long* pbB = (unsigned long long*)alloc((size_t)Tt*CHK*16*8); // packed {epoch,partial}, 2 parity x 64B
  (void)ws_size; (void)in_sizes; (void)n_in; (void)out_size;

  // CSR build: bucket histogram -> bucket scan -> partition -> per-bucket counting sort (emits rp+deg)
  k_init<<<16, 256, 0, stream>>>(bcnt, bfill, flagA, pbB);
  k_bcnt<<<Tt*BPT, 256, 0, stream>>>(ei, bcnt);
  k_bscan<<<Tt, 256, 0, stream>>>(bcnt, rpb);
  k_part2<<<Tt*BPT, 256, 0, stream>>>(ei, rpb, bfill, pair);
  k_csr2<<<Tt*NB, 256, 0, stream>>>(rpb, pair, col16, rp, deg);
  k_dinv<<<(Tt*Mn + 255)/256, 256, 0, stream>>>(deg, dinv);

  // GRU stack (layer-1 forward direction is dead code -> skipped)
  k_wcvt<<<(Gg*C2 + 255)/256, 256, 0, stream>>>(Wih1 + (size_t)Gg*C2, Wbf);
  k_gru0<<<(Mn + 31)/32, 256, 0, stream>>>(nf, Wih0, Whh0, bih0, bhh0, y0);
  {
    int waves = Tt*((Mn + 31)/32);
    k_gi1m<<<(waves + 3)/4, 256, 0, stream>>>(y0, Wbf, bih1 + Gg, gi);
  }
  k_gru1r<<<(Mn + 31)/32, 256, 0, stream>>>(gi, Whh1 + (size_t)Gg*Hh, bhh1 + Gg, lns, lnb, xbt);

  // power iteration: 75 rounds + 1 Rayleigh round, fused into ONE kernel;
  // wave0-only polling + LDS broadcast + packed u64 {epoch,partial} publishes
  k_pitall<<<Tt*CHK, 1024, 0, stream>>>(rp, col16, urb, flagA, pbB, lamc);

  // Chebyshev: tx1 = Lhat(x), tx2 = 2*Lhat(tx1) - x
  k_cheb<<<(Tt*Mn)/4, 256, 0, stream>>>(xbt, xbt, tx1, rp, col16, dinv, lamc, 1.f, 0.f);
  k_cheb<<<(Tt*Mn)/4, 256, 0, stream>>>(tx1, xbt, tx2, rp, col16, dinv, lamc, 2.f, -1.f);

  // folded cheb-GEMM + conv + sigmoid
  k_ww<<<(3*Tt*Hh*Oo + 255)/256, 256, 0, stream>>>(chebW, chebb, convW, convb, WW, c0);
  k_final<<<(Mn + 63)/64, 256, 0, stream>>>(xbt, tx1, tx2, WW, c0, outp);
}

// Round 6
// 2556.928 us; speedup vs baseline: 1.7049x; 1.1796x over previous
//
#include <hip/hip_runtime.h>
#include <hip/hip_bf16.h>

#define DEV __device__ __forceinline__

constexpr int Mn  = 30000;   // nodes (B=1)
constexpr int Tt  = 12;
constexpr int CIN = 16;
constexpr int Hh  = 64;
constexpr int Gg  = 192;     // 3H
constexpr int C2  = 128;     // 2H
constexpr int Ee  = 960000;  // edges per timestep (bidirectional)
constexpr int HC  = 128;
constexpr int Oo  = 12;
constexpr int KW  = 128;
constexpr int SEGS= 938;     // 32-row segments per t (938*32 >= 30000)
constexpr int NB  = 235;     // 128-row buckets per t (235*128 >= 30000)
constexpr int EPB = 8192;    // edges per block for bcnt/part2
constexpr int BPT = 118;     // ceil(Ee/EPB)
constexpr int CHK = 21;      // chunks per t for power iteration (252 blocks total)
constexpr int RC  = 1440;    // rows per chunk (16B-aligned chunk base; 21*1440 >= 30000)
constexpr int NRND= 76;      // 75 power rounds + 1 Rayleigh round
constexpr int NF4A= 21*256;  // phase-A float4 count (rows [r0, r0+1024) per chunk)
constexpr int NF4B= 20*104 + 44; // phase-B float4 count (rows [r0+1024, r1) per chunk)

DEV float bf2f(__hip_bfloat16 v){ return __bfloat162float(v); }
DEV __hip_bfloat16 f2bf(float v){ return __float2bfloat16(v); }
DEV float sigm(float x){ return __builtin_amdgcn_rcpf(1.f + __expf(-x)); }
DEV float tanh_f(float x){ return 1.f - 2.f*__builtin_amdgcn_rcpf(__expf(2.f*x) + 1.f); }

// agent-scope (device-coherent, sc1) accessors for cross-XCD flags/u-stores
DEV float aload_f(const float* p){ return __hip_atomic_load(p, __ATOMIC_RELAXED, __HIP_MEMORY_SCOPE_AGENT); }
DEV void  astore_f(float* p, float v){ __hip_atomic_store(p, v, __ATOMIC_RELAXED, __HIP_MEMORY_SCOPE_AGENT); }
DEV int   aload_i(const int* p){ return __hip_atomic_load(p, __ATOMIC_RELAXED, __HIP_MEMORY_SCOPE_AGENT); }
DEV void  astore_i(int* p, int v){ __hip_atomic_store(p, v, __ATOMIC_RELAXED, __HIP_MEMORY_SCOPE_AGENT); }
DEV unsigned long long aload_u64(const unsigned long long* p){ return __hip_atomic_load(p, __ATOMIC_RELAXED, __HIP_MEMORY_SCOPE_AGENT); }
DEV void astore_u64(unsigned long long* p, unsigned long long v){ __hip_atomic_store(p, v, __ATOMIC_RELAXED, __HIP_MEMORY_SCOPE_AGENT); }

typedef short bfrag8 __attribute__((ext_vector_type(8)));
typedef float ffrag4 __attribute__((ext_vector_type(4)));

// swizzled element offset into a [32 rows][64 cols] bf16 h-tile (row = 128B ->
// 8 16B chunks; chunk ^= row&7 spreads the 16-row fragment reads over 8 banks)
DEV int off_h(int row, int col){
  return row*64 + ((((col >> 3) ^ (row & 7)) << 3) | (col & 7));
}

DEV short bfbits(float v){ __hip_bfloat16 b = f2bf(v); return *reinterpret_cast<short*>(&b); }

// ---------------------------------------------------------------- init (flags + CSR counters only)
__global__ void k_init(int* bcnt, int* bfill, int* flagA, unsigned long long* pbB){
  int i = blockIdx.x*256 + threadIdx.x;
  if (i < Tt*CHK*16){ flagA[i] = 0; pbB[i] = 0ull; }
  if (i < Tt*NB){ bcnt[i] = 0; bfill[i] = 0; }
}

// ---------------------------------------------------------------- stage 1: block-aggregated bucket histogram
__global__ __launch_bounds__(256) void k_bcnt(const int* __restrict__ ei, int* __restrict__ bcnt){
  __shared__ int h[NB];
  const int b = blockIdx.x;                 // 1416 = 8*177
  const int w = (b & 7)*177 + (b >> 3);
  const int t = w / BPT, ch = w - t*BPT;
  const int e0 = ch*EPB;
  const int tid = threadIdx.x;
  for (int i = tid; i < NB; i += 256) h[i] = 0;
  __syncthreads();
  #pragma unroll
  for (int i = 0; i < 32; ++i){
    int e = e0 + i*256 + tid;
    if (e < Ee){
      int r = ei[(size_t)(t*2)*Ee + e];
      atomicAdd(&h[r >> 7], 1);
    }
  }
  __syncthreads();
  for (int i = tid; i < NB; i += 256){
    int c = h[i];
    if (c > 0) atomicAdd(&bcnt[t*NB + i], c);
  }
}

// ---------------------------------------------------------------- stage 2: per-t exclusive scan of bucket counts
__global__ __launch_bounds__(256) void k_bscan(const int* __restrict__ bcnt, int* __restrict__ rpb){
  int t = blockIdx.x, tid = threadIdx.x;
  __shared__ int ps[256];
  int v = (tid < NB) ? bcnt[t*NB + tid] : 0;
  ps[tid] = v;
  __syncthreads();
  for (int o = 1; o < 256; o <<= 1){
    int x = (tid >= o) ? ps[tid-o] : 0;
    __syncthreads();
    ps[tid] += x;
    __syncthreads();
  }
  if (tid < NB) rpb[t*(NB+1) + tid] = ps[tid] - v;
  if (tid == 255) rpb[t*(NB+1) + NB] = ps[NB-1];
}

// ---------------------------------------------------------------- stage 3: partition edges into buckets (block-aggregated reservations)
__global__ __launch_bounds__(256) void k_part2(const int* __restrict__ ei, const int* __restrict__ rpb,
    int* __restrict__ bfill, unsigned* __restrict__ pair){
  __shared__ int hcnt[NB];
  __shared__ int hbase[NB];
  const int b = blockIdx.x;                 // 1416 = 8*177
  const int w = (b & 7)*177 + (b >> 3);
  const int t = w / BPT, ch = w - t*BPT;
  const int e0 = ch*EPB;
  const int tid = threadIdx.x;
  for (int i = tid; i < NB; i += 256) hcnt[i] = 0;
  __syncthreads();
  unsigned key[32];
  #pragma unroll
  for (int i = 0; i < 32; ++i){
    int e = e0 + i*256 + tid;
    unsigned k = 0xFFFFFFFFu;
    if (e < Ee){
      int r = ei[(size_t)(t*2)*Ee + e];
      int c = ei[(size_t)(t*2+1)*Ee + e];
      k = ((unsigned)r << 16) | (unsigned)c;
      atomicAdd(&hcnt[r >> 7], 1);
    }
    key[i] = k;
  }
  __syncthreads();
  for (int i = tid; i < NB; i += 256){
    int cnt = hcnt[i];
    int base = (cnt > 0) ? atomicAdd(&bfill[t*NB + i], cnt) : 0;
    hbase[i] = rpb[t*(NB+1) + i] + base;
  }
  __syncthreads();
  for (int i = tid; i < NB; i += 256) hcnt[i] = 0;
  __syncthreads();
  #pragma unroll
  for (int i = 0; i < 32; ++i){
    unsigned k = key[i];
    if (k != 0xFFFFFFFFu){
      int r = (int)(k >> 16);
      int bk = r >> 7;
      int pos = atomicAdd(&hcnt[bk], 1);
      pair[(size_t)t*Ee + hbase[bk] + pos] = ((unsigned)(r & 127) << 16) | (k & 0xFFFFu);
    }
  }
}

// ---------------------------------------------------------------- stage 4: per-bucket LDS counting sort -> col16, rp, deg
__global__ __launch_bounds__(256) void k_csr2(const int* __restrict__ rpb, const unsigned* __restrict__ pair,
    unsigned short* __restrict__ col16, int* __restrict__ rp, int* __restrict__ deg){
  __shared__ unsigned short cols_s[9216];
  __shared__ int lcnt[128], lfill[128];
  __shared__ int ps[256];
  const int blk = blockIdx.x;               // Tt*NB
  const int t = blk / NB, bk = blk - t*NB;
  const int r0 = bk << 7;
  const int nr = (r0 + 128 <= Mn) ? 128 : (Mn - r0);
  const int base = rpb[t*(NB+1) + bk];
  const int cnt  = rpb[t*(NB+1) + bk + 1] - base;
  const int tid = threadIdx.x;
  if (tid < 128) lcnt[tid] = 0;
  __syncthreads();
  for (int i = tid; i < cnt; i += 256){
    unsigned v = pair[(size_t)t*Ee + base + i];
    atomicAdd(&lcnt[v >> 16], 1);
  }
  __syncthreads();
  int v2 = (tid < 128) ? lcnt[tid] : 0;
  ps[tid] = v2;
  __syncthreads();
  for (int o = 1; o < 128; o <<= 1){
    int x = (tid >= o) ? ps[tid-o] : 0;
    __syncthreads();
    ps[tid] += x;
    __syncthreads();
  }
  if (tid < 128){
    int excl = ps[tid] - v2;
    lfill[tid] = excl;
    if (tid < nr){
      rp[t*(Mn+1) + r0 + tid] = base + excl;
      deg[t*Mn + r0 + tid] = v2;
    }
  }
  if (bk == NB-1 && tid == 0) rp[t*(Mn+1) + Mn] = base + cnt;
  __syncthreads();
  for (int i = tid; i < cnt; i += 256){
    unsigned v = pair[(size_t)t*Ee + base + i];
    int pos = atomicAdd(&lfill[v >> 16], 1);
    cols_s[pos] = (unsigned short)(v & 0xFFFFu);
  }
  __syncthreads();
  for (int i = tid; i < cnt; i += 256)
    col16[(size_t)t*Ee + base + i] = cols_s[i];
}

// ---------------------------------------------------------------- dinv
__global__ void k_dinv(const int* __restrict__ deg, float* __restrict__ dinv){
  int i = blockIdx.x*256 + threadIdx.x;
  if (i < Tt*Mn){ int d = deg[i]; dinv[i] = (d > 0) ? rsqrtf((float)d) : 0.f; }
}

// ---------------------------------------------------------------- GRU layer 0 (both dirs) via MFMA, writes y0 (T,M,128) bf16
// Recurrent h[32x64]@Whh^T[64x192] on matrix cores. Numerics match the prior
// VALU version: W in bf16 (as before); h enters MFMA as h_hi+h_lo (two bf16
// MFMAs against the same W == f32-h x bf16-W); x packed as hi|lo into the
// K=32 slot with W repeated (== f32-x x bf16-W). h_old carried exactly in
// f32 registers (lane->rows mapping is step-invariant). Gate triples r/z/n =
// col-tiles {w, w+4, w+8} land in the SAME lane -> gate math is lane-local.
__global__ __launch_bounds__(256) void k_gru0(
    const float* __restrict__ nf, const float* __restrict__ Wih, const float* __restrict__ Whh,
    const float* __restrict__ bih, const float* __restrict__ bhh, __hip_bfloat16* __restrict__ y0)
{
  __shared__ __hip_bfloat16 xp[Tt*32*32];   // [t][row][k]: cols 0-15 x_hi, 16-31 x_lo (24.6 KB)
  __shared__ __hip_bfloat16 h_hi[32*64];    // swizzled (4 KB)
  __shared__ __hip_bfloat16 h_lo[32*64];    // swizzled (4 KB)
  const int tid = threadIdx.x;
  const int m0  = blockIdx.x*32;
  const int lane = tid & 63, wv = tid >> 6;
  const int lr = lane & 15, lq = lane >> 4;
  // stage x once (hi/lo split preserves f32 precision through bf16 MFMA)
  for (int idx = tid; idx < Tt*32*CIN; idx += 256){
    int t = idx >> 9; int row = (idx >> 4) & 31; int k = idx & 15;
    int m = m0 + row;
    float v = (m < Mn) ? nf[((size_t)t*Mn + m)*CIN + k] : 0.f;
    __hip_bfloat16 hi = f2bf(v);
    xp[(t*32 + row)*32 + k]      = hi;
    xp[(t*32 + row)*32 + 16 + k] = f2bf(v - bf2f(hi));
  }
  for (int d = 0; d < 2; ++d){
    // per-wave weight fragments (B operand: col = lane&15, k = (lane>>4)*8+r)
    bfrag8 Bh[3][2], Bx[3];
    float b_r, b_z, b_in, b_hn;
    {
      const float* Wh = Whh + (size_t)d*Gg*Hh;
      const float* Wx = Wih + (size_t)d*Gg*CIN;
      #pragma unroll
      for (int c = 0; c < 3; ++c){
        int g = (wv + 4*c)*16 + lr;
        #pragma unroll
        for (int ks = 0; ks < 2; ++ks){
          bfrag8 f;
          #pragma unroll
          for (int r = 0; r < 8; ++r) f[r] = bfbits(Wh[(size_t)g*Hh + ks*32 + lq*8 + r]);
          Bh[c][ks] = f;
        }
        bfrag8 fx;
        #pragma unroll
        for (int r = 0; r < 8; ++r) fx[r] = bfbits(Wx[(size_t)g*CIN + ((lq*8 + r) & 15)]);
        Bx[c] = fx;
      }
      int j = wv*16 + lr;
      b_r  = bih[d*Gg + j]        + bhh[d*Gg + j];
      b_z  = bih[d*Gg + Hh + j]   + bhh[d*Gg + Hh + j];
      b_in = bih[d*Gg + 2*Hh + j];
      b_hn = bhh[d*Gg + 2*Hh + j];
    }
    float hreg[8];
    #pragma unroll
    for (int q = 0; q < 8; ++q) hreg[q] = 0.f;
    for (int i = tid; i < 32*64; i += 256){ h_hi[i] = f2bf(0.f); h_lo[i] = f2bf(0.f); }
    __syncthreads();                         // xp staged + h zeroed
    for (int step = 0; step < Tt; ++step){
      int t = d ? (Tt-1-step) : step;
      // A fragments (row = lane&15, k = (lane>>4)*8+r)
      bfrag8 xa[2], hhf[2][2], hlf[2][2];
      #pragma unroll
      for (int rt = 0; rt < 2; ++rt){
        int row = rt*16 + lr;
        xa[rt] = *(const bfrag8*)&xp[(t*32 + row)*32 + lq*8];
        #pragma unroll
        for (int ks = 0; ks < 2; ++ks){
          int e = off_h(row, ks*32 + lq*8);
          hhf[rt][ks] = *(const bfrag8*)&h_hi[e];
          hlf[rt][ks] = *(const bfrag8*)&h_lo[e];
        }
      }
      ffrag4 Cr[2], Cz[2], Cai[2], Cah[2];
      #pragma unroll
      for (int rt = 0; rt < 2; ++rt){
        ffrag4 z4 = (ffrag4){0.f,0.f,0.f,0.f};
        Cr[rt]  = __builtin_amdgcn_mfma_f32_16x16x32_bf16(xa[rt], Bx[0], z4, 0,0,0);
        Cz[rt]  = __builtin_amdgcn_mfma_f32_16x16x32_bf16(xa[rt], Bx[1], z4, 0,0,0);
        Cai[rt] = __builtin_amdgcn_mfma_f32_16x16x32_bf16(xa[rt], Bx[2], z4, 0,0,0);
        Cah[rt] = z4;
        #pragma unroll
        for (int ks = 0; ks < 2; ++ks){
          Cr[rt]  = __builtin_amdgcn_mfma_f32_16x16x32_bf16(hhf[rt][ks], Bh[0][ks], Cr[rt], 0,0,0);
          Cr[rt]  = __builtin_amdgcn_mfma_f32_16x16x32_bf16(hlf[rt][ks], Bh[0][ks], Cr[rt], 0,0,0);
          Cz[rt]  = __builtin_amdgcn_mfma_f32_16x16x32_bf16(hhf[rt][ks], Bh[1][ks], Cz[rt], 0,0,0);
          Cz[rt]  = __builtin_amdgcn_mfma_f32_16x16x32_bf16(hlf[rt][ks], Bh[1][ks], Cz[rt], 0,0,0);
          Cah[rt] = __builtin_amdgcn_mfma_f32_16x16x32_bf16(hhf[rt][ks], Bh[2][ks], Cah[rt], 0,0,0);
          Cah[rt] = __builtin_amdgcn_mfma_f32_16x16x32_bf16(hlf[rt][ks], Bh[2][ks], Cah[rt], 0,0,0);
        }
      }
      __syncthreads();                       // h frag reads done before rewrite
      // gates (D: row = (lane>>4)*4+reg, col = lane&15 within tile)
      #pragma unroll
      for (int rt = 0; rt < 2; ++rt){
        #pragma unroll
        for (int q = 0; q < 4; ++q){
          float r = sigm(Cr[rt][q] + b_r);
          float z = sigm(Cz[rt][q] + b_z);
          float n = tanh_f((Cai[rt][q] + b_in) + r*(Cah[rt][q] + b_hn));
          float h = (1.f - z)*n + z*hreg[rt*4+q];
          hreg[rt*4+q] = h;
          __hip_bfloat16 hi = f2bf(h);
          int e = off_h(rt*16 + lq*4 + q, wv*16 + lr);
          h_hi[e] = hi;
          h_lo[e] = f2bf(h - bf2f(hi));
        }
      }
      __syncthreads();                       // h updated for y0-write + next step
      // cooperative y0 write: y0 = bf16(h) = h_hi exactly
      {
        int row = tid >> 3, cg = tid & 7;
        int m = m0 + row;
        if (m < Mn){
          float4 v = *(const float4*)&h_hi[off_h(row, cg*8)];
          *(float4*)&y0[((size_t)t*Mn + m)*C2 + d*Hh + cg*8] = v;
        }
      }
    }
    __syncthreads();                         // before next dir re-zeroes h
  }
}

// ---------------------------------------------------------------- convert layer-1 reverse weights to bf16
__global__ void k_wcvt(const float* __restrict__ W, __hip_bfloat16* __restrict__ Wbf){
  int i = blockIdx.x*256 + threadIdx.x;
  if (i < Gg*C2) Wbf[i] = f2bf(W[i]);
}

// ---------------------------------------------------------------- layer-1 input projection via MFMA
// Output stored in FRAGMENT-NATIVE layout: ushort4 (4 bf16) per lane at
// [t][seg][rt][nt][lane] so k_gru1r's C-init is 6 coalesced 8B loads.
__global__ __launch_bounds__(256) void k_gi1m(const __hip_bfloat16* __restrict__ y0,
    const __hip_bfloat16* __restrict__ Wbf, const float* __restrict__ bih, __hip_bfloat16* __restrict__ gi)
{
  const int wid  = (blockIdx.x*256 + threadIdx.x) >> 6;
  const int lane = threadIdx.x & 63;
  if (wid >= Tt*SEGS) return;
  const int t = wid / SEGS, seg = wid - t*SEGS;
  const int m0 = seg*32;
  const int lr = lane & 15, lq = lane >> 4;
  const __hip_bfloat16* yb = y0 + (size_t)t*Mn*C2;

  ffrag4 acc[2][12];
  #pragma unroll
  for (int i = 0; i < 2; ++i){
    #pragma unroll
    for (int n = 0; n < 12; ++n) acc[i][n] = (ffrag4){0.f,0.f,0.f,0.f};
  }
  #pragma unroll
  for (int ks = 0; ks < 4; ++ks){
    const int ko = ks*32 + lq*8;
    bfrag8 a0 = *(const bfrag8*)(yb + (size_t)(m0 + lr     )*C2 + ko);
    bfrag8 a1 = *(const bfrag8*)(yb + (size_t)(m0 + 16 + lr)*C2 + ko);
    #pragma unroll
    for (int nt = 0; nt < 12; ++nt){
      bfrag8 b = *(const bfrag8*)(Wbf + (size_t)(nt*16 + lr)*C2 + ko);
      acc[0][nt] = __builtin_amdgcn_mfma_f32_16x16x32_bf16(a0, b, acc[0][nt], 0, 0, 0);
      acc[1][nt] = __builtin_amdgcn_mfma_f32_16x16x32_bf16(a1, b, acc[1][nt], 0, 0, 0);
    }
  }
  ushort4* go = (ushort4*)gi;
  #pragma unroll
  for (int i = 0; i < 2; ++i){
    #pragma unroll
    for (int nt = 0; nt < 12; ++nt){
      float bb = bih[nt*16 + lr];
      ushort4 pk;
      pk.x = (unsigned short)bfbits(acc[i][nt][0] + bb);
      pk.y = (unsigned short)bfbits(acc[i][nt][1] + bb);
      pk.z = (unsigned short)bfbits(acc[i][nt][2] + bb);
      pk.w = (unsigned short)bfbits(acc[i][nt][3] + bb);
      go[((((size_t)t*SEGS + seg)*2 + i)*12 + nt)*64 + lane] = pk;
    }
  }
}

// ---------------------------------------------------------------- GRU layer 1 (reverse) via MFMA + fused LayerNorm
__global__ __launch_bounds__(256) void k_gru1r(const __hip_bfloat16* __restrict__ gi,
    const float* __restrict__ Whh, const float* __restrict__ bhh,
    const float* __restrict__ lns, const float* __restrict__ lnb,
    __hip_bfloat16* __restrict__ xbt)
{
  __shared__ __hip_bfloat16 h_hi[32*64];    // swizzled (4 KB)
  __shared__ __hip_bfloat16 h_lo[32*64];
  __shared__ float h_f32[32*72];            // exact f32 h for LayerNorm (9.2 KB)
  __shared__ float sc[Hh], bs[Hh];
  const int tid = threadIdx.x;
  const int seg = blockIdx.x;
  const int m0  = seg*32;
  const int lane = tid & 63, wv = tid >> 6;
  const int lr = lane & 15, lq = lane >> 4;
  // weight fragments + biases
  bfrag8 Bh[3][2];
  float b_r, b_z, b_hn;
  #pragma unroll
  for (int c = 0; c < 3; ++c){
    int g = (wv + 4*c)*16 + lr;
    #pragma unroll
    for (int ks = 0; ks < 2; ++ks){
      bfrag8 f;
      #pragma unroll
      for (int r = 0; r < 8; ++r) f[r] = bfbits(Whh[(size_t)g*Hh + ks*32 + lq*8 + r]);
      Bh[c][ks] = f;
    }
  }
  {
    int j = wv*16 + lr;
    b_r  = bhh[j];
    b_z  = bhh[Hh + j];
    b_hn = bhh[2*Hh + j];
  }
  if (tid < Hh){ sc[tid] = lns[tid]; bs[tid] = lnb[tid]; }
  float hreg[8];
  #pragma unroll
  for (int q = 0; q < 8; ++q) hreg[q] = 0.f;
  for (int i = tid; i < 32*64; i += 256){ h_hi[i] = f2bf(0.f); h_lo[i] = f2bf(0.f); }
  __syncthreads();
  const ushort4* gbase = (const ushort4*)gi;
  for (int step = 0; step < Tt; ++step){
    int t = Tt-1-step;
    // C init from fragment-native gi (r: tile wv, z: wv+4, n-input: wv+8)
    ffrag4 Cr[2], Cz[2], Cai[2], Cah[2];
    #pragma unroll
    for (int rt = 0; rt < 2; ++rt){
      size_t base = (((size_t)t*SEGS + seg)*2 + rt)*12;
      ushort4 gr4 = gbase[(base + wv     )*64 + lane];
      ushort4 gz4 = gbase[(base + wv + 4 )*64 + lane];
      ushort4 gn4 = gbase[(base + wv + 8 )*64 + lane];
      __hip_bfloat16 b;
      ffrag4 cr, cz, cn;
      b = *(__hip_bfloat16*)&gr4.x; cr[0] = bf2f(b);
      b = *(__hip_bfloat16*)&gr4.y; cr[1] = bf2f(b);
      b = *(__hip_bfloat16*)&gr4.z; cr[2] = bf2f(b);
      b = *(__hip_bfloat16*)&gr4.w; cr[3] = bf2f(b);
      b = *(__hip_bfloat16*)&gz4.x; cz[0] = bf2f(b);
      b = *(__hip_bfloat16*)&gz4.y; cz[1] = bf2f(b);
      b = *(__hip_bfloat16*)&gz4.z; cz[2] = bf2f(b);
      b = *(__hip_bfloat16*)&gz4.w; cz[3] = bf2f(b);
      b = *(__hip_bfloat16*)&gn4.x; cn[0] = bf2f(b);
      b = *(__hip_bfloat16*)&gn4.y; cn[1] = bf2f(b);
      b = *(__hip_bfloat16*)&gn4.z; cn[2] = bf2f(b);
      b = *(__hip_bfloat16*)&gn4.w; cn[3] = bf2f(b);
      Cr[rt] = cr; Cz[rt] = cz; Cai[rt] = cn;
      Cah[rt] = (ffrag4){0.f,0.f,0.f,0.f};
    }
    // recurrent MFMAs (hi+lo)
    bfrag8 hhf[2][2], hlf[2][2];
    #pragma unroll
    for (int rt = 0; rt < 2; ++rt){
      int row = rt*16 + lr;
      #pragma unroll
      for (int ks = 0; ks < 2; ++ks){
        int e = off_h(row, ks*32 + lq*8);
        hhf[rt][ks] = *(const bfrag8*)&h_hi[e];
        hlf[rt][ks] = *(const bfrag8*)&h_lo[e];
      }
    }
    #pragma unroll
    for (int rt = 0; rt < 2; ++rt){
      #pragma unroll
      for (int ks = 0; ks < 2; ++ks){
        Cr[rt]  = __builtin_amdgcn_mfma_f32_16x16x32_bf16(hhf[rt][ks], Bh[0][ks], Cr[rt], 0,0,0);
        Cr[rt]  = __builtin_amdgcn_mfma_f32_16x16x32_bf16(hlf[rt][ks], Bh[0][ks], Cr[rt], 0,0,0);
        Cz[rt]  = __builtin_amdgcn_mfma_f32_16x16x32_bf16(hhf[rt][ks], Bh[1][ks], Cz[rt], 0,0,0);
        Cz[rt]  = __builtin_amdgcn_mfma_f32_16x16x32_bf16(hlf[rt][ks], Bh[1][ks], Cz[rt], 0,0,0);
        Cah[rt] = __builtin_amdgcn_mfma_f32_16x16x32_bf16(hhf[rt][ks], Bh[2][ks], Cah[rt], 0,0,0);
        Cah[rt] = __builtin_amdgcn_mfma_f32_16x16x32_bf16(hlf[rt][ks], Bh[2][ks], Cah[rt], 0,0,0);
      }
    }
    __syncthreads();
    // gates
    #pragma unroll
    for (int rt = 0; rt < 2; ++rt){
      #pragma unroll
      for (int q = 0; q < 4; ++q){
        float r = sigm(Cr[rt][q] + b_r);
        float z = sigm(Cz[rt][q] + b_z);
        float n = tanh_f(Cai[rt][q] + r*(Cah[rt][q] + b_hn));
        float h = (1.f - z)*n + z*hreg[rt*4+q];
        hreg[rt*4+q] = h;
        __hip_bfloat16 hi = f2bf(h);
        int row = rt*16 + lq*4 + q;
        int e = off_h(row, wv*16 + lr);
        h_hi[e] = hi;
        h_lo[e] = f2bf(h - bf2f(hi));
        h_f32[row*72 + wv*16 + lr] = h;
      }
    }
    __syncthreads();
    // fused LayerNorm on exact f32 h -> xbt (identical math to prior version)
    {
      int row = tid >> 3, l = tid & 7;
      float4 v0 = *(const float4*)&h_f32[row*72 + l*8];
      float4 v1 = *(const float4*)&h_f32[row*72 + l*8 + 4];
      float vals[8] = {v0.x, v0.y, v0.z, v0.w, v1.x, v1.y, v1.z, v1.w};
      float s1 = 0.f, s2 = 0.f;
      #pragma unroll
      for (int q = 0; q < 8; ++q){ s1 += vals[q]; s2 += vals[q]*vals[q]; }
      #pragma unroll
      for (int off = 1; off <= 4; off <<= 1){ s1 += __shfl_xor(s1, off); s2 += __shfl_xor(s2, off); }
      float mu  = s1 * (1.f/64.f);
      float var = s2 * (1.f/64.f) - mu*mu;
      float rs  = rsqrtf(var + 1e-5f);
      int m = m0 + row;
      if (m < Mn){
        __hip_bfloat16 ob[8];
        #pragma unroll
        for (int q = 0; q < 8; ++q){ int j = l*8 + q; ob[q] = f2bf((vals[q]-mu)*rs*sc[j] + bs[j]); }
        *(float4*)&xbt[((size_t)t*Mn + m)*Hh + l*8] = *(float4*)ob;
      }
    }
    __syncthreads();
  }
}

// ---------------------------------------------------------------- fused power iteration (R5 structure, validated)
__global__ __launch_bounds__(1024) void k_pitall(const int* __restrict__ rp,
    const unsigned short* __restrict__ col, float* __restrict__ urb,
    int* __restrict__ flagA, unsigned long long* __restrict__ pbB,
    float* __restrict__ lamc)
{
  __shared__ alignas(16) float u_s[Mn];     // 120000 B
  __shared__ float redw[16];
  __shared__ float s_nrm;
  __shared__ int s_goA, s_goB;
  const int b = blockIdx.x;                 // Tt*CHK = 252
  const int t = b / CHK, ch = b - t*CHK;
  const int r0 = ch*RC;
  const int r1 = (r0 + RC < Mn) ? r0 + RC : Mn;
  const int tid = threadIdx.x;
  const int lane = tid & 63;
  const int wv   = tid >> 6;                // wave id 0..15
  const unsigned short* cp = col + (size_t)t*Ee;
  const int fS = t*CHK*16;                  // flagA slots: u32, 64B apart
  const int pB = t*CHK*16;                  // pbB slots: u64, per block 2 parity x 64B
  const int m0r = r0 + tid;                 // phase-A row
  const int m1r = m0r + 1024;               // phase-B row
  int rb0 = 0, re0 = 0, rb1 = 0, re1 = 0;
  {
    const int* rpt = rp + t*(Mn+1);
    if (m0r < r1){ rb0 = rpt[m0r]; re0 = rpt[m0r+1]; }
    if (m1r < r1){ rb1 = rpt[m1r]; re1 = rpt[m1r+1]; }
  }
  if (tid == 0){ s_nrm = 1.0f; s_goA = 0; s_goB = 0; }
  __syncthreads();
  for (int r = 1; r <= NRND; ++r){
    const int fin = (r == NRND);
    if (r == 1){
      for (int i = tid; i < Mn; i += 1024) u_s[i] = 0.005773502691896258f;
    } else {
      const int rr = r - 1;
      const float4* u4 = (const float4*)(urb + (size_t)rr*(Tt*Mn) + (size_t)t*Mn);
      float4* s4 = (float4*)u_s;
      if (wv == 0){
        const bool mine = lane < CHK;
        for (;;){ int v = mine ? aload_i(&flagA[fS + lane*16]) : 0x7FFFFFFF;
                  if (__all(v >= rr)) break; __builtin_amdgcn_s_sleep(4); }
        if (lane == 0) __hip_atomic_store(&s_goA, rr, __ATOMIC_RELAXED, __HIP_MEMORY_SCOPE_WORKGROUP);
      } else {
        while (__hip_atomic_load(&s_goA, __ATOMIC_RELAXED, __HIP_MEMORY_SCOPE_WORKGROUP) < rr)
          __builtin_amdgcn_s_sleep(2);
      }
      asm volatile("" ::: "memory");
      for (int i = tid; i < NF4A; i += 1024){
        int idx = (i >> 8)*360 + (i & 255);
        s4[idx] = u4[idx];
      }
      unsigned long long pv = 0;
      if (wv == 0){
        const bool mine = lane < CHK;
        for (;;){ pv = mine ? aload_u64(&pbB[(size_t)(pB + lane*16) + (rr & 1)*8])
                            : ((unsigned long long)rr << 32);
                  if (__all((int)(pv >> 32) == rr)) break; __builtin_amdgcn_s_sleep(4); }
        if (lane == 0) __hip_atomic_store(&s_goB, rr, __ATOMIC_RELAXED, __HIP_MEMORY_SCOPE_WORKGROUP);
      } else {
        while (__hip_atomic_load(&s_goB, __ATOMIC_RELAXED, __HIP_MEMORY_SCOPE_WORKGROUP) < rr)
          __builtin_amdgcn_s_sleep(2);
      }
      asm volatile("" ::: "memory");
      for (int i = tid; i < NF4B; i += 1024){
        int ck = i/104, off = i - ck*104;
        int idx = ck*360 + 256 + off;
        s4[idx] = u4[idx];
      }
      if (wv == 0){
        float p = (lane < CHK) ? __uint_as_float((unsigned)pv) : 0.f;
        #pragma unroll
        for (int o2 = 1; o2 < 32; o2 <<= 1) p += __shfl_xor(p, o2);
        if (tid == 0) s_nrm = p;
      }
    }
    __syncthreads();
    const float inv_s = fin ? 1.f : 1.f/(sqrtf(s_nrm) + 1e-12f);
    float* u_ot = urb + (size_t)r*(Tt*Mn);
    float local = 0.f;
    if (m0r < r1){
      float s = 0.f;
      int i = rb0;
      for (; i < re0 && (i & 3); ++i) s += u_s[cp[i]];
      for (; i + 4 <= re0; i += 4){
        ushort4 c4 = *(const ushort4*)(cp + i);
        s += (u_s[c4.x] + u_s[c4.y]) + (u_s[c4.z] + u_s[c4.w]);
      }
      for (; i < re0; ++i) s += u_s[cp[i]];
      float uv = u_s[m0r];
      float wv2 = (float)(re0 - rb0)*uv - s;
      if (!fin){ float o = inv_s*wv2; astore_f(&u_ot[t*Mn + m0r], o); local += o*o; }
      else local += uv*wv2;
    }
    asm volatile("s_waitcnt vmcnt(0)" ::: "memory");
    __syncthreads();
    if (tid == 0) astore_i(&flagA[fS + ch*16], r);
    if (m1r < r1){
      float s = 0.f;
      int i = rb1;
      for (; i < re1 && (i & 3); ++i) s += u_s[cp[i]];
      for (; i + 4 <= re1; i += 4){
        ushort4 c4 = *(const ushort4*)(cp + i);
        s += (u_s[c4.x] + u_s[c4.y]) + (u_s[c4.z] + u_s[c4.w]);
      }
      for (; i < re1; ++i) s += u_s[cp[i]];
      float uv = u_s[m1r];
      float wv2 = (float)(re1 - rb1)*uv - s;
      if (!fin){ float o = inv_s*wv2; astore_f(&u_ot[t*Mn + m1r], o); local += o*o; }
      else local += uv*wv2;
    }
    #pragma unroll
    for (int o2 = 1; o2 < 64; o2 <<= 1) local += __shfl_xor(local, o2);
    if ((tid & 63) == 0) redw[tid >> 6] = local;
    asm volatile("s_waitcnt vmcnt(0)" ::: "memory");
    __syncthreads();
    if (tid < 64){
      float tot = (tid < 16) ? redw[tid] : 0.f;
      #pragma unroll
      for (int o2 = 1; o2 < 16; o2 <<= 1) tot += __shfl_xor(tot, o2);
      if (tid == 0){
        unsigned long long out = ((unsigned long long)r << 32)
                               | (unsigned long long)__float_as_uint(tot);
        astore_u64(&pbB[(size_t)(pB + ch*16) + (r & 1)*8], out);
      }
    }
  }
  if (ch == 0 && tid < 64){
    const bool mine = lane < CHK;
    unsigned long long pv = 0;
    for (;;){ pv = mine ? aload_u64(&pbB[(size_t)(pB + lane*16) + (NRND & 1)*8])
                        : ((unsigned long long)NRND << 32);
              if (__all((int)(pv >> 32) == NRND)) break; __builtin_amdgcn_s_sleep(4); }
    float p = mine ? __uint_as_float((unsigned)pv) : 0.f;
    #pragma unroll
    for (int o2 = 1; o2 < 32; o2 <<= 1) p += __shfl_xor(p, o2);
    if (tid == 0){
      float nn = sqrtf(s_nrm) + 1e-12f;
      float lam = p / (nn*nn);
      lamc[2*t+0] = -2.f/lam;
      lamc[2*t+1] =  2.f/lam - 1.f;
    }
  }
}

// ---------------------------------------------------------------- Chebyshev SpMM (wave per row, lane = channel, XCD-swizzled)
__global__ __launch_bounds__(256) void k_cheb(const __hip_bfloat16* __restrict__ xin,
    const __hip_bfloat16* __restrict__ xb0, __hip_bfloat16* __restrict__ outp,
    const int* __restrict__ rp, const unsigned short* __restrict__ col,
    const float* __restrict__ dinv, const float* __restrict__ lamc, float s1, float s2)
{
  const int blk = blockIdx.x;               // 90000 = 8*11250
  const int w = (blk & 7)*11250 + (blk >> 3);
  const int gw = w*4 + (threadIdx.x >> 6);
  const int lane = threadIdx.x & 63;
  int t = gw / Mn, m = gw - t*Mn;
  float coef = lamc[2*t], diag = lamc[2*t+1];
  const __hip_bfloat16* xt = xin + (size_t)t*Mn*Hh;
  const float* dv = dinv + t*Mn;
  float acc = diag * bf2f(xt[(size_t)m*Hh + lane]);
  float cdm = coef * dv[m];
  int bgn = rp[t*(Mn+1)+m], end = rp[t*(Mn+1)+m+1];
  const unsigned short* cp = col + (size_t)t*Ee;
  int i = bgn;
  for (; i < end && (i & 3); ++i){ int c = cp[i]; acc += (cdm*dv[c])*bf2f(xt[(size_t)c*Hh + lane]); }
  for (; i + 4 <= end; i += 4){
    ushort4 c4 = *(const ushort4*)(cp + i);
    float w0 = cdm*dv[c4.x], w1 = cdm*dv[c4.y], w2 = cdm*dv[c4.z], w3 = cdm*dv[c4.w];
    acc += w0*bf2f(xt[(size_t)c4.x*Hh + lane]);
    acc += w1*bf2f(xt[(size_t)c4.y*Hh + lane]);
    acc += w2*bf2f(xt[(size_t)c4.z*Hh + lane]);
    acc += w3*bf2f(xt[(size_t)c4.w*Hh + lane]);
  }
  for (; i < end; ++i){ int c = cp[i]; acc += (cdm*dv[c])*bf2f(xt[(size_t)c*Hh + lane]); }
  float o = s1*acc;
  if (s2 != 0.f) o += s2*bf2f(xb0[(size_t)gw*Hh + lane]);
  outp[(size_t)gw*Hh + lane] = f2bf(o);
}

// ---------------------------------------------------------------- fold cheb_W into conv_W
__global__ void k_ww(const float* __restrict__ chebW, const float* __restrict__ chebb,
    const float* __restrict__ convW, const float* __restrict__ convb, float* __restrict__ WW, float* __restrict__ c0)
{
  int idx = blockIdx.x*256 + threadIdx.x;
  if (idx < 3*Tt*Hh*Oo){
    int oc = idx % Oo; int j = (idx/Oo) % Hh; int t = (idx/(Oo*Hh)) % Tt; int i = idx/(Oo*Hh*Tt);
    const float* cw = chebW + ((size_t)i*Hh + j)*HC + (HC-KW);
    const float* vw = convW + ((size_t)oc*Tt + t)*KW;
    float s = 0.f;
    for (int k = 0; k < KW; ++k) s += cw[k]*vw[k];
    WW[idx] = s;
  }
  if (blockIdx.x == 0 && threadIdx.x < Oo){
    int oc = threadIdx.x;
    float s = convb[oc];
    for (int t = 0; t < Tt; ++t){
      const float* vw = convW + ((size_t)oc*Tt + t)*KW;
      for (int k = 0; k < KW; ++k) s += chebb[(HC-KW)+k]*vw[k];
    }
    c0[oc] = s;
  }
}

// ---------------------------------------------------------------- fused cheb-GEMM + temporal conv + sigmoid
__global__ __launch_bounds__(256) void k_final(const __hip_bfloat16* __restrict__ tx0,
    const __hip_bfloat16* __restrict__ tx1, const __hip_bfloat16* __restrict__ tx2,
    const float* __restrict__ WW, const float* __restrict__ c0, float* __restrict__ outp)
{
  __shared__ float xs[64][65];
  __shared__ float ww[64][12];
  const int tid = threadIdx.x;
  const int n0 = blockIdx.x*64;
  const int n = tid & 63, ob = (tid >> 6)*3;
  float acc[3] = {0.f, 0.f, 0.f};
  for (int it = 0; it < 3*Tt; ++it){
    int ii = it / Tt, t = it % Tt;
    const __hip_bfloat16* tx = (ii == 0) ? tx0 : (ii == 1) ? tx1 : tx2;
    __syncthreads();
    for (int idx = tid; idx < 64*64; idx += 256){
      int mm = idx >> 6, j = idx & 63;
      int m = n0 + mm;
      xs[mm][j] = (m < Mn) ? bf2f(tx[((size_t)t*Mn + m)*Hh + j]) : 0.f;
    }
    for (int idx = tid; idx < 64*Oo; idx += 256)
      ((float*)ww)[idx] = WW[((size_t)(ii*Tt + t)*Hh)*Oo + idx];
    __syncthreads();
    #pragma unroll 8
    for (int j = 0; j < 64; ++j){
      float x = xs[n][j];
      acc[0] += x*ww[j][ob+0];
      acc[1] += x*ww[j][ob+1];
      acc[2] += x*ww[j][ob+2];
    }
  }
  int m = n0 + n;
  if (m < Mn){
    #pragma unroll
    for (int q = 0; q < 3; ++q) outp[(size_t)m*Oo + ob + q] = sigm(acc[q] + c0[ob+q]);
  }
}

// ================================================================ host
extern "C" void kernel_launch(void* const* d_in, const int* in_sizes, int n_in,
                              void* d_out, int out_size, void* d_ws, size_t ws_size,
                              hipStream_t stream)
{
  const float* nf    = (const float*)d_in[0];
  const int*   ei    = (const int*)d_in[1];
  const float* Wih0  = (const float*)d_in[2];
  const float* Whh0  = (const float*)d_in[3];
  const float* bih0  = (const float*)d_in[4];
  const float* bhh0  = (const float*)d_in[5];
  const float* Wih1  = (const float*)d_in[6];
  const float* Whh1  = (const float*)d_in[7];
  const float* bih1  = (const float*)d_in[8];
  const float* bhh1  = (const float*)d_in[9];
  const float* lns   = (const float*)d_in[10];
  const float* lnb   = (const float*)d_in[11];
  const float* chebW = (const float*)d_in[12];
  const float* chebb = (const float*)d_in[13];
  const float* convW = (const float*)d_in[14];
  const float* convb = (const float*)d_in[15];
  float* outp = (float*)d_out;

  char* base = (char*)d_ws;
  size_t off = 0;
  auto alloc = [&](size_t bytes)->char*{ char* p = base + off; off += (bytes + 255) & ~(size_t)255; return p; };

  __hip_bfloat16* y0  = (__hip_bfloat16*)alloc((size_t)Tt*Mn*C2*2);
  __hip_bfloat16* tx1 = y0;
  __hip_bfloat16* tx2 = y0 + (size_t)Tt*Mn*Hh;
  // gi arena sized for fragment-native layout (padded segs: SEGS*32 rows)
  __hip_bfloat16* gi  = (__hip_bfloat16*)alloc((size_t)Tt*SEGS*32*Gg*2);
  unsigned* pair = (unsigned*)gi;          // overlaps gi: pair dead before k_gi1m writes gi
  float* urb = (float*)gi;                 // power-iteration round buffers: (NRND+1)*Tt*Mn*4
                                           // = 110.9 MB <= gi arena 138.3 MB (gi dead after k_gru1r)
  __hip_bfloat16* xbt = (__hip_bfloat16*)alloc((size_t)Tt*Mn*Hh*2);
  unsigned short* col16 = (unsigned short*)alloc((size_t)Tt*Ee*2);
  int*   deg  = (int*)alloc((size_t)Tt*Mn*4);
  int*   rp   = (int*)alloc((size_t)Tt*(Mn+1)*4);
  int*   bcnt = (int*)alloc((size_t)Tt*NB*4);
  int*   bfill= (int*)alloc((size_t)Tt*NB*4);
  int*   rpb  = (int*)alloc((size_t)Tt*(NB+1)*4);
  float* dinv = (float*)alloc((size_t)Tt*Mn*4);
  float* lamc = (float*)alloc((size_t)2*Tt*4);
  float* WW   = (float*)alloc((size_t)3*Tt*Hh*Oo*4);
  float* c0   = (float*)alloc((size_t)Oo*4);
  __hip_bfloat16* Wbf = (__hip_bfloat16*)alloc((size_t)Gg*C2*2);
  int*   flagA = (int*)alloc((size_t)Tt*CHK*16*4);              // phase-A epoch flags, 64B apart
  unsigned long long* pbB = (unsigned long long*)alloc((size_t)Tt*CHK*16*8); // packed {epoch,partial}
  (void)ws_size; (void)in_sizes; (void)n_in; (void)out_size;

  // CSR build: bucket histogram -> bucket scan -> partition -> per-bucket counting sort (emits rp+deg)
  k_init<<<16, 256, 0, stream>>>(bcnt, bfill, flagA, pbB);
  k_bcnt<<<Tt*BPT, 256, 0, stream>>>(ei, bcnt);
  k_bscan<<<Tt, 256, 0, stream>>>(bcnt, rpb);
  k_part2<<<Tt*BPT, 256, 0, stream>>>(ei, rpb, bfill, pair);
  k_csr2<<<Tt*NB, 256, 0, stream>>>(rpb, pair, col16, rp, deg);
  k_dinv<<<(Tt*Mn + 255)/256, 256, 0, stream>>>(deg, dinv);

  // GRU stack (MFMA engines; layer-1 forward direction is dead code -> skipped)
  k_wcvt<<<(Gg*C2 + 255)/256, 256, 0, stream>>>(Wih1 + (size_t)Gg*C2, Wbf);
  k_gru0<<<SEGS, 256, 0, stream>>>(nf, Wih0, Whh0, bih0, bhh0, y0);
  {
    int waves = Tt*SEGS;
    k_gi1m<<<(waves + 3)/4, 256, 0, stream>>>(y0, Wbf, bih1 + Gg, gi);
  }
  k_gru1r<<<SEGS, 256, 0, stream>>>(gi, Whh1 + (size_t)Gg*Hh, bhh1 + Gg, lns, lnb, xbt);

  // power iteration: 75 rounds + 1 Rayleigh round, fused into ONE kernel
  k_pitall<<<Tt*CHK, 1024, 0, stream>>>(rp, col16, urb, flagA, pbB, lamc);

  // Chebyshev: tx1 = Lhat(x), tx2 = 2*Lhat(tx1) - x
  k_cheb<<<(Tt*Mn)/4, 256, 0, stream>>>(xbt, xbt, tx1, rp, col16, dinv, lamc, 1.f, 0.f);
  k_cheb<<<(Tt*Mn)/4, 256, 0, stream>>>(tx1, xbt, tx2, rp, col16, dinv, lamc, 2.f, -1.f);

  // folded cheb-GEMM + conv + sigmoid
  k_ww<<<(3*Tt*Hh*Oo + 255)/256, 256, 0, stream>>>(chebW, chebb, convW, convb, WW, c0);
  k_final<<<(Mn + 63)/64, 256, 0, stream>>>(xbt, tx1, tx2, WW, c0, outp);
}

// Round 7
// 2482.835 us; speedup vs baseline: 1.7558x; 1.0298x over previous
//
#include <hip/hip_runtime.h>
#include <hip/hip_bf16.h>

#define DEV __device__ __forceinline__

constexpr int Mn  = 30000;   // nodes (B=1)
constexpr int Tt  = 12;
constexpr int CIN = 16;
constexpr int Hh  = 64;
constexpr int Gg  = 192;     // 3H
constexpr int C2  = 128;     // 2H
constexpr int Ee  = 960000;  // edges per timestep (bidirectional)
constexpr int HC  = 128;
constexpr int Oo  = 12;
constexpr int KW  = 128;
constexpr int SEGS= 938;     // 32-row segments per t (938*32 >= 30000)
constexpr int NB  = 235;     // 128-row buckets per t (235*128 >= 30000)
constexpr int EPB = 8192;    // edges per block for bcnt/part2
constexpr int BPT = 118;     // ceil(Ee/EPB)
constexpr int CHK = 21;      // chunks per t for power iteration (252 blocks total)
constexpr int RC  = 1440;    // rows per chunk (16B-aligned chunk base; 21*1440 >= 30000)
constexpr int NRND= 76;      // 75 power rounds + 1 Rayleigh round
constexpr int NF4A= 21*256;  // phase-A float4 count (rows [r0, r0+1024) per chunk)
constexpr int NF4B= 20*104 + 44; // phase-B float4 count (rows [r0+1024, r1) per chunk)

DEV float bf2f(__hip_bfloat16 v){ return __bfloat162float(v); }
DEV __hip_bfloat16 f2bf(float v){ return __float2bfloat16(v); }
DEV float sigm(float x){ return __builtin_amdgcn_rcpf(1.f + __expf(-x)); }
DEV float tanh_f(float x){ return 1.f - 2.f*__builtin_amdgcn_rcpf(__expf(2.f*x) + 1.f); }

// agent-scope (device-coherent, sc1) accessors for cross-XCD flags/u-stores
DEV float aload_f(const float* p){ return __hip_atomic_load(p, __ATOMIC_RELAXED, __HIP_MEMORY_SCOPE_AGENT); }
DEV void  astore_f(float* p, float v){ __hip_atomic_store(p, v, __ATOMIC_RELAXED, __HIP_MEMORY_SCOPE_AGENT); }
DEV int   aload_i(const int* p){ return __hip_atomic_load(p, __ATOMIC_RELAXED, __HIP_MEMORY_SCOPE_AGENT); }
DEV void  astore_i(int* p, int v){ __hip_atomic_store(p, v, __ATOMIC_RELAXED, __HIP_MEMORY_SCOPE_AGENT); }
DEV unsigned long long aload_u64(const unsigned long long* p){ return __hip_atomic_load(p, __ATOMIC_RELAXED, __HIP_MEMORY_SCOPE_AGENT); }
DEV void astore_u64(unsigned long long* p, unsigned long long v){ __hip_atomic_store(p, v, __ATOMIC_RELAXED, __HIP_MEMORY_SCOPE_AGENT); }

typedef short bfrag8 __attribute__((ext_vector_type(8)));
typedef float ffrag4 __attribute__((ext_vector_type(4)));

// swizzled element offset into a [32 rows][64 cols] bf16 h-tile (row = 128B ->
// 8 16B chunks; chunk ^= row&7 spreads the 16-row fragment reads over 8 banks)
DEV int off_h(int row, int col){
  return row*64 + ((((col >> 3) ^ (row & 7)) << 3) | (col & 7));
}

DEV short bfbits(float v){ __hip_bfloat16 b = f2bf(v); return *reinterpret_cast<short*>(&b); }

// ---------------------------------------------------------------- init (flags + CSR counters only)
__global__ void k_init(int* bcnt, int* bfill, int* flagA, unsigned long long* pbB){
  int i = blockIdx.x*256 + threadIdx.x;
  if (i < Tt*CHK*16){ flagA[i] = 0; pbB[i] = 0ull; }
  if (i < Tt*NB){ bcnt[i] = 0; bfill[i] = 0; }
}

// ---------------------------------------------------------------- stage 1: block-aggregated bucket histogram
__global__ __launch_bounds__(256) void k_bcnt(const int* __restrict__ ei, int* __restrict__ bcnt){
  __shared__ int h[NB];
  const int b = blockIdx.x;                 // 1416 = 8*177
  const int w = (b & 7)*177 + (b >> 3);
  const int t = w / BPT, ch = w - t*BPT;
  const int e0 = ch*EPB;
  const int tid = threadIdx.x;
  for (int i = tid; i < NB; i += 256) h[i] = 0;
  __syncthreads();
  #pragma unroll
  for (int i = 0; i < 32; ++i){
    int e = e0 + i*256 + tid;
    if (e < Ee){
      int r = ei[(size_t)(t*2)*Ee + e];
      atomicAdd(&h[r >> 7], 1);
    }
  }
  __syncthreads();
  for (int i = tid; i < NB; i += 256){
    int c = h[i];
    if (c > 0) atomicAdd(&bcnt[t*NB + i], c);
  }
}

// ---------------------------------------------------------------- stage 2: per-t exclusive scan of bucket counts
__global__ __launch_bounds__(256) void k_bscan(const int* __restrict__ bcnt, int* __restrict__ rpb){
  int t = blockIdx.x, tid = threadIdx.x;
  __shared__ int ps[256];
  int v = (tid < NB) ? bcnt[t*NB + tid] : 0;
  ps[tid] = v;
  __syncthreads();
  for (int o = 1; o < 256; o <<= 1){
    int x = (tid >= o) ? ps[tid-o] : 0;
    __syncthreads();
    ps[tid] += x;
    __syncthreads();
  }
  if (tid < NB) rpb[t*(NB+1) + tid] = ps[tid] - v;
  if (tid == 255) rpb[t*(NB+1) + NB] = ps[NB-1];
}

// ---------------------------------------------------------------- stage 3: partition edges into buckets (block-aggregated reservations)
__global__ __launch_bounds__(256) void k_part2(const int* __restrict__ ei, const int* __restrict__ rpb,
    int* __restrict__ bfill, unsigned* __restrict__ pair){
  __shared__ int hcnt[NB];
  __shared__ int hbase[NB];
  const int b = blockIdx.x;                 // 1416 = 8*177
  const int w = (b & 7)*177 + (b >> 3);
  const int t = w / BPT, ch = w - t*BPT;
  const int e0 = ch*EPB;
  const int tid = threadIdx.x;
  for (int i = tid; i < NB; i += 256) hcnt[i] = 0;
  __syncthreads();
  unsigned key[32];
  #pragma unroll
  for (int i = 0; i < 32; ++i){
    int e = e0 + i*256 + tid;
    unsigned k = 0xFFFFFFFFu;
    if (e < Ee){
      int r = ei[(size_t)(t*2)*Ee + e];
      int c = ei[(size_t)(t*2+1)*Ee + e];
      k = ((unsigned)r << 16) | (unsigned)c;
      atomicAdd(&hcnt[r >> 7], 1);
    }
    key[i] = k;
  }
  __syncthreads();
  for (int i = tid; i < NB; i += 256){
    int cnt = hcnt[i];
    int base = (cnt > 0) ? atomicAdd(&bfill[t*NB + i], cnt) : 0;
    hbase[i] = rpb[t*(NB+1) + i] + base;
  }
  __syncthreads();
  for (int i = tid; i < NB; i += 256) hcnt[i] = 0;
  __syncthreads();
  #pragma unroll
  for (int i = 0; i < 32; ++i){
    unsigned k = key[i];
    if (k != 0xFFFFFFFFu){
      int r = (int)(k >> 16);
      int bk = r >> 7;
      int pos = atomicAdd(&hcnt[bk], 1);
      pair[(size_t)t*Ee + hbase[bk] + pos] = ((unsigned)(r & 127) << 16) | (k & 0xFFFFu);
    }
  }
}

// ---------------------------------------------------------------- stage 4: per-bucket LDS counting sort -> col16, rp, dinv
__global__ __launch_bounds__(256) void k_csr2(const int* __restrict__ rpb, const unsigned* __restrict__ pair,
    unsigned short* __restrict__ col16, int* __restrict__ rp, float* __restrict__ dinv){
  __shared__ unsigned short cols_s[9216];
  __shared__ int lcnt[128], lfill[128];
  __shared__ int ps[256];
  const int blk = blockIdx.x;               // Tt*NB
  const int t = blk / NB, bk = blk - t*NB;
  const int r0 = bk << 7;
  const int nr = (r0 + 128 <= Mn) ? 128 : (Mn - r0);
  const int base = rpb[t*(NB+1) + bk];
  const int cnt  = rpb[t*(NB+1) + bk + 1] - base;
  const int tid = threadIdx.x;
  if (tid < 128) lcnt[tid] = 0;
  __syncthreads();
  for (int i = tid; i < cnt; i += 256){
    unsigned v = pair[(size_t)t*Ee + base + i];
    atomicAdd(&lcnt[v >> 16], 1);
  }
  __syncthreads();
  int v2 = (tid < 128) ? lcnt[tid] : 0;
  ps[tid] = v2;
  __syncthreads();
  for (int o = 1; o < 128; o <<= 1){
    int x = (tid >= o) ? ps[tid-o] : 0;
    __syncthreads();
    ps[tid] += x;
    __syncthreads();
  }
  if (tid < 128){
    int excl = ps[tid] - v2;
    lfill[tid] = excl;
    if (tid < nr){
      rp[t*(Mn+1) + r0 + tid] = base + excl;
      dinv[t*Mn + r0 + tid] = (v2 > 0) ? rsqrtf((float)v2) : 0.f;  // folded k_dinv
    }
  }
  if (bk == NB-1 && tid == 0) rp[t*(Mn+1) + Mn] = base + cnt;
  __syncthreads();
  for (int i = tid; i < cnt; i += 256){
    unsigned v = pair[(size_t)t*Ee + base + i];
    int pos = atomicAdd(&lfill[v >> 16], 1);
    cols_s[pos] = (unsigned short)(v & 0xFFFFu);
  }
  __syncthreads();
  for (int i = tid; i < cnt; i += 256)
    col16[(size_t)t*Ee + base + i] = cols_s[i];
}

// ---------------------------------------------------------------- GRU layer 0 (both dirs) via MFMA, writes y0 (T,M,128) bf16
__global__ __launch_bounds__(256) void k_gru0(
    const float* __restrict__ nf, const float* __restrict__ Wih, const float* __restrict__ Whh,
    const float* __restrict__ bih, const float* __restrict__ bhh, __hip_bfloat16* __restrict__ y0)
{
  __shared__ __hip_bfloat16 xp[Tt*32*32];   // [t][row][k]: cols 0-15 x_hi, 16-31 x_lo (24.6 KB)
  __shared__ __hip_bfloat16 h_hi[32*64];    // swizzled (4 KB)
  __shared__ __hip_bfloat16 h_lo[32*64];    // swizzled (4 KB)
  const int tid = threadIdx.x;
  const int m0  = blockIdx.x*32;
  const int lane = tid & 63, wv = tid >> 6;
  const int lr = lane & 15, lq = lane >> 4;
  for (int idx = tid; idx < Tt*32*CIN; idx += 256){
    int t = idx >> 9; int row = (idx >> 4) & 31; int k = idx & 15;
    int m = m0 + row;
    float v = (m < Mn) ? nf[((size_t)t*Mn + m)*CIN + k] : 0.f;
    __hip_bfloat16 hi = f2bf(v);
    xp[(t*32 + row)*32 + k]      = hi;
    xp[(t*32 + row)*32 + 16 + k] = f2bf(v - bf2f(hi));
  }
  for (int d = 0; d < 2; ++d){
    bfrag8 Bh[3][2], Bx[3];
    float b_r, b_z, b_in, b_hn;
    {
      const float* Wh = Whh + (size_t)d*Gg*Hh;
      const float* Wx = Wih + (size_t)d*Gg*CIN;
      #pragma unroll
      for (int c = 0; c < 3; ++c){
        int g = (wv + 4*c)*16 + lr;
        #pragma unroll
        for (int ks = 0; ks < 2; ++ks){
          bfrag8 f;
          #pragma unroll
          for (int r = 0; r < 8; ++r) f[r] = bfbits(Wh[(size_t)g*Hh + ks*32 + lq*8 + r]);
          Bh[c][ks] = f;
        }
        bfrag8 fx;
        #pragma unroll
        for (int r = 0; r < 8; ++r) fx[r] = bfbits(Wx[(size_t)g*CIN + ((lq*8 + r) & 15)]);
        Bx[c] = fx;
      }
      int j = wv*16 + lr;
      b_r  = bih[d*Gg + j]        + bhh[d*Gg + j];
      b_z  = bih[d*Gg + Hh + j]   + bhh[d*Gg + Hh + j];
      b_in = bih[d*Gg + 2*Hh + j];
      b_hn = bhh[d*Gg + 2*Hh + j];
    }
    float hreg[8];
    #pragma unroll
    for (int q = 0; q < 8; ++q) hreg[q] = 0.f;
    for (int i = tid; i < 32*64; i += 256){ h_hi[i] = f2bf(0.f); h_lo[i] = f2bf(0.f); }
    __syncthreads();
    for (int step = 0; step < Tt; ++step){
      int t = d ? (Tt-1-step) : step;
      bfrag8 xa[2], hhf[2][2], hlf[2][2];
      #pragma unroll
      for (int rt = 0; rt < 2; ++rt){
        int row = rt*16 + lr;
        xa[rt] = *(const bfrag8*)&xp[(t*32 + row)*32 + lq*8];
        #pragma unroll
        for (int ks = 0; ks < 2; ++ks){
          int e = off_h(row, ks*32 + lq*8);
          hhf[rt][ks] = *(const bfrag8*)&h_hi[e];
          hlf[rt][ks] = *(const bfrag8*)&h_lo[e];
        }
      }
      ffrag4 Cr[2], Cz[2], Cai[2], Cah[2];
      #pragma unroll
      for (int rt = 0; rt < 2; ++rt){
        ffrag4 z4 = (ffrag4){0.f,0.f,0.f,0.f};
        Cr[rt]  = __builtin_amdgcn_mfma_f32_16x16x32_bf16(xa[rt], Bx[0], z4, 0,0,0);
        Cz[rt]  = __builtin_amdgcn_mfma_f32_16x16x32_bf16(xa[rt], Bx[1], z4, 0,0,0);
        Cai[rt] = __builtin_amdgcn_mfma_f32_16x16x32_bf16(xa[rt], Bx[2], z4, 0,0,0);
        Cah[rt] = z4;
        #pragma unroll
        for (int ks = 0; ks < 2; ++ks){
          Cr[rt]  = __builtin_amdgcn_mfma_f32_16x16x32_bf16(hhf[rt][ks], Bh[0][ks], Cr[rt], 0,0,0);
          Cr[rt]  = __builtin_amdgcn_mfma_f32_16x16x32_bf16(hlf[rt][ks], Bh[0][ks], Cr[rt], 0,0,0);
          Cz[rt]  = __builtin_amdgcn_mfma_f32_16x16x32_bf16(hhf[rt][ks], Bh[1][ks], Cz[rt], 0,0,0);
          Cz[rt]  = __builtin_amdgcn_mfma_f32_16x16x32_bf16(hlf[rt][ks], Bh[1][ks], Cz[rt], 0,0,0);
          Cah[rt] = __builtin_amdgcn_mfma_f32_16x16x32_bf16(hhf[rt][ks], Bh[2][ks], Cah[rt], 0,0,0);
          Cah[rt] = __builtin_amdgcn_mfma_f32_16x16x32_bf16(hlf[rt][ks], Bh[2][ks], Cah[rt], 0,0,0);
        }
      }
      __syncthreads();
      #pragma unroll
      for (int rt = 0; rt < 2; ++rt){
        #pragma unroll
        for (int q = 0; q < 4; ++q){
          float r = sigm(Cr[rt][q] + b_r);
          float z = sigm(Cz[rt][q] + b_z);
          float n = tanh_f((Cai[rt][q] + b_in) + r*(Cah[rt][q] + b_hn));
          float h = (1.f - z)*n + z*hreg[rt*4+q];
          hreg[rt*4+q] = h;
          __hip_bfloat16 hi = f2bf(h);
          int e = off_h(rt*16 + lq*4 + q, wv*16 + lr);
          h_hi[e] = hi;
          h_lo[e] = f2bf(h - bf2f(hi));
        }
      }
      __syncthreads();
      {
        int row = tid >> 3, cg = tid & 7;
        int m = m0 + row;
        if (m < Mn){
          float4 v = *(const float4*)&h_hi[off_h(row, cg*8)];
          *(float4*)&y0[((size_t)t*Mn + m)*C2 + d*Hh + cg*8] = v;
        }
      }
    }
    __syncthreads();
  }
}

// ---------------------------------------------------------------- convert layer-1 reverse Wih to bf16
__global__ void k_wcvt(const float* __restrict__ W, __hip_bfloat16* __restrict__ Wbf){
  int i = blockIdx.x*256 + threadIdx.x;
  if (i < Gg*C2) Wbf[i] = f2bf(W[i]);
}

// ---------------------------------------------------------------- GRU layer 1 (reverse) via MFMA with FUSED input projection
// (was k_gi1m + k_gru1r). Per wave, only its own 3 gate-column tiles
// {wv, wv+4, wv+8} are projected: 24 projection MFMAs/step (y0 bf16 x Wbf
// bf16, K=128) whose D-fragment layout is IDENTICAL to the recurrence C
// layout -> the projection accumulator directly initializes the gate C.
// Removes the 138MB gi intermediate (write+read) and one bf16 rounding
// (gi was stored bf16; now the projection stays f32 -> closer to reference).
__global__ __launch_bounds__(256) void k_gru1r(const __hip_bfloat16* __restrict__ y0,
    const __hip_bfloat16* __restrict__ Wbf, const float* __restrict__ Whh,
    const float* __restrict__ bih, const float* __restrict__ bhh,
    const float* __restrict__ lns, const float* __restrict__ lnb,
    __hip_bfloat16* __restrict__ xbt)
{
  __shared__ __hip_bfloat16 h_hi[32*64];    // swizzled (4 KB)
  __shared__ __hip_bfloat16 h_lo[32*64];
  __shared__ float h_f32[32*72];            // exact f32 h for LayerNorm (9.2 KB)
  __shared__ float sc[Hh], bs[Hh];
  const int tid = threadIdx.x;
  const int seg = blockIdx.x;
  const int m0  = seg*32;
  const int lane = tid & 63, wv = tid >> 6;
  const int lr = lane & 15, lq = lane >> 4;
  // recurrence weight fragments (bf16 from f32 Whh)
  bfrag8 Bh[3][2];
  #pragma unroll
  for (int c = 0; c < 3; ++c){
    int g = (wv + 4*c)*16 + lr;
    #pragma unroll
    for (int ks = 0; ks < 2; ++ks){
      bfrag8 f;
      #pragma unroll
      for (int r = 0; r < 8; ++r) f[r] = bfbits(Whh[(size_t)g*Hh + ks*32 + lq*8 + r]);
      Bh[c][ks] = f;
    }
  }
  // projection weight fragments (step-invariant, held in VGPRs; K=128 -> 4 ks)
  bfrag8 Bp[3][4];
  #pragma unroll
  for (int c = 0; c < 3; ++c){
    int g = (wv + 4*c)*16 + lr;
    #pragma unroll
    for (int ks = 0; ks < 4; ++ks)
      Bp[c][ks] = *(const bfrag8*)(Wbf + (size_t)g*C2 + ks*32 + lq*8);
  }
  float b_r, b_z, b_in, b_hn;
  {
    int j = wv*16 + lr;
    b_r  = bih[j]      + bhh[j];
    b_z  = bih[Hh+j]   + bhh[Hh+j];
    b_in = bih[2*Hh+j];
    b_hn = bhh[2*Hh+j];
  }
  if (tid < Hh){ sc[tid] = lns[tid]; bs[tid] = lnb[tid]; }
  float hreg[8];
  #pragma unroll
  for (int q = 0; q < 8; ++q) hreg[q] = 0.f;
  for (int i = tid; i < 32*64; i += 256){ h_hi[i] = f2bf(0.f); h_lo[i] = f2bf(0.f); }
  __syncthreads();
  for (int step = 0; step < Tt; ++step){
    int t = Tt-1-step;
    const __hip_bfloat16* yb = y0 + (size_t)t*Mn*C2;
    // input projection: C init = y0[rows] @ Wih1r^T (f32 accum, bias in gates)
    ffrag4 Cr[2], Cz[2], Cai[2], Cah[2];
    #pragma unroll
    for (int rt = 0; rt < 2; ++rt){
      ffrag4 z4 = (ffrag4){0.f,0.f,0.f,0.f};
      Cr[rt] = z4; Cz[rt] = z4; Cai[rt] = z4; Cah[rt] = z4;
    }
    #pragma unroll
    for (int ks = 0; ks < 4; ++ks){
      const int ko = ks*32 + lq*8;
      bfrag8 a0 = *(const bfrag8*)(yb + (size_t)(m0 + lr     )*C2 + ko);
      bfrag8 a1 = *(const bfrag8*)(yb + (size_t)(m0 + 16 + lr)*C2 + ko);
      Cr[0]  = __builtin_amdgcn_mfma_f32_16x16x32_bf16(a0, Bp[0][ks], Cr[0], 0,0,0);
      Cr[1]  = __builtin_amdgcn_mfma_f32_16x16x32_bf16(a1, Bp[0][ks], Cr[1], 0,0,0);
      Cz[0]  = __builtin_amdgcn_mfma_f32_16x16x32_bf16(a0, Bp[1][ks], Cz[0], 0,0,0);
      Cz[1]  = __builtin_amdgcn_mfma_f32_16x16x32_bf16(a1, Bp[1][ks], Cz[1], 0,0,0);
      Cai[0] = __builtin_amdgcn_mfma_f32_16x16x32_bf16(a0, Bp[2][ks], Cai[0], 0,0,0);
      Cai[1] = __builtin_amdgcn_mfma_f32_16x16x32_bf16(a1, Bp[2][ks], Cai[1], 0,0,0);
    }
    // recurrent MFMAs (hi+lo)
    bfrag8 hhf[2][2], hlf[2][2];
    #pragma unroll
    for (int rt = 0; rt < 2; ++rt){
      int row = rt*16 + lr;
      #pragma unroll
      for (int ks = 0; ks < 2; ++ks){
        int e = off_h(row, ks*32 + lq*8);
        hhf[rt][ks] = *(const bfrag8*)&h_hi[e];
        hlf[rt][ks] = *(const bfrag8*)&h_lo[e];
      }
    }
    #pragma unroll
    for (int rt = 0; rt < 2; ++rt){
      #pragma unroll
      for (int ks = 0; ks < 2; ++ks){
        Cr[rt]  = __builtin_amdgcn_mfma_f32_16x16x32_bf16(hhf[rt][ks], Bh[0][ks], Cr[rt], 0,0,0);
        Cr[rt]  = __builtin_amdgcn_mfma_f32_16x16x32_bf16(hlf[rt][ks], Bh[0][ks], Cr[rt], 0,0,0);
        Cz[rt]  = __builtin_amdgcn_mfma_f32_16x16x32_bf16(hhf[rt][ks], Bh[1][ks], Cz[rt], 0,0,0);
        Cz[rt]  = __builtin_amdgcn_mfma_f32_16x16x32_bf16(hlf[rt][ks], Bh[1][ks], Cz[rt], 0,0,0);
        Cah[rt] = __builtin_amdgcn_mfma_f32_16x16x32_bf16(hhf[rt][ks], Bh[2][ks], Cah[rt], 0,0,0);
        Cah[rt] = __builtin_amdgcn_mfma_f32_16x16x32_bf16(hlf[rt][ks], Bh[2][ks], Cah[rt], 0,0,0);
      }
    }
    __syncthreads();
    // gates
    #pragma unroll
    for (int rt = 0; rt < 2; ++rt){
      #pragma unroll
      for (int q = 0; q < 4; ++q){
        float r = sigm(Cr[rt][q] + b_r);
        float z = sigm(Cz[rt][q] + b_z);
        float n = tanh_f((Cai[rt][q] + b_in) + r*(Cah[rt][q] + b_hn));
        float h = (1.f - z)*n + z*hreg[rt*4+q];
        hreg[rt*4+q] = h;
        __hip_bfloat16 hi = f2bf(h);
        int row = rt*16 + lq*4 + q;
        int e = off_h(row, wv*16 + lr);
        h_hi[e] = hi;
        h_lo[e] = f2bf(h - bf2f(hi));
        h_f32[row*72 + wv*16 + lr] = h;
      }
    }
    __syncthreads();
    // fused LayerNorm on exact f32 h -> xbt
    {
      int row = tid >> 3, l = tid & 7;
      float4 v0 = *(const float4*)&h_f32[row*72 + l*8];
      float4 v1 = *(const float4*)&h_f32[row*72 + l*8 + 4];
      float vals[8] = {v0.x, v0.y, v0.z, v0.w, v1.x, v1.y, v1.z, v1.w};
      float s1 = 0.f, s2 = 0.f;
      #pragma unroll
      for (int q = 0; q < 8; ++q){ s1 += vals[q]; s2 += vals[q]*vals[q]; }
      #pragma unroll
      for (int off = 1; off <= 4; off <<= 1){ s1 += __shfl_xor(s1, off); s2 += __shfl_xor(s2, off); }
      float mu  = s1 * (1.f/64.f);
      float var = s2 * (1.f/64.f) - mu*mu;
      float rs  = rsqrtf(var + 1e-5f);
      int m = m0 + row;
      if (m < Mn){
        __hip_bfloat16 ob[8];
        #pragma unroll
        for (int q = 0; q < 8; ++q){ int j = l*8 + q; ob[q] = f2bf((vals[q]-mu)*rs*sc[j] + bs[j]); }
        *(float4*)&xbt[((size_t)t*Mn + m)*Hh + l*8] = *(float4*)ob;
      }
    }
    __syncthreads();
  }
}

// ---------------------------------------------------------------- fused power iteration (R5 structure, validated)
__global__ __launch_bounds__(1024) void k_pitall(const int* __restrict__ rp,
    const unsigned short* __restrict__ col, float* __restrict__ urb,
    int* __restrict__ flagA, unsigned long long* __restrict__ pbB,
    float* __restrict__ lamc)
{
  __shared__ alignas(16) float u_s[Mn];     // 120000 B
  __shared__ float redw[16];
  __shared__ float s_nrm;
  __shared__ int s_goA, s_goB;
  const int b = blockIdx.x;                 // Tt*CHK = 252
  const int t = b / CHK, ch = b - t*CHK;
  const int r0 = ch*RC;
  const int r1 = (r0 + RC < Mn) ? r0 + RC : Mn;
  const int tid = threadIdx.x;
  const int lane = tid & 63;
  const int wv   = tid >> 6;                // wave id 0..15
  const unsigned short* cp = col + (size_t)t*Ee;
  const int fS = t*CHK*16;                  // flagA slots: u32, 64B apart
  const int pB = t*CHK*16;                  // pbB slots: u64, per block 2 parity x 64B
  const int m0r = r0 + tid;                 // phase-A row
  const int m1r = m0r + 1024;               // phase-B row
  int rb0 = 0, re0 = 0, rb1 = 0, re1 = 0;
  {
    const int* rpt = rp + t*(Mn+1);
    if (m0r < r1){ rb0 = rpt[m0r]; re0 = rpt[m0r+1]; }
    if (m1r < r1){ rb1 = rpt[m1r]; re1 = rpt[m1r+1]; }
  }
  if (tid == 0){ s_nrm = 1.0f; s_goA = 0; s_goB = 0; }
  __syncthreads();
  for (int r = 1; r <= NRND; ++r){
    const int fin = (r == NRND);
    if (r == 1){
      for (int i = tid; i < Mn; i += 1024) u_s[i] = 0.005773502691896258f;
    } else {
      const int rr = r - 1;
      const float4* u4 = (const float4*)(urb + (size_t)rr*(Tt*Mn) + (size_t)t*Mn);
      float4* s4 = (float4*)u_s;
      if (wv == 0){
        const bool mine = lane < CHK;
        for (;;){ int v = mine ? aload_i(&flagA[fS + lane*16]) : 0x7FFFFFFF;
                  if (__all(v >= rr)) break; __builtin_amdgcn_s_sleep(4); }
        if (lane == 0) __hip_atomic_store(&s_goA, rr, __ATOMIC_RELAXED, __HIP_MEMORY_SCOPE_WORKGROUP);
      } else {
        while (__hip_atomic_load(&s_goA, __ATOMIC_RELAXED, __HIP_MEMORY_SCOPE_WORKGROUP) < rr)
          __builtin_amdgcn_s_sleep(2);
      }
      asm volatile("" ::: "memory");
      for (int i = tid; i < NF4A; i += 1024){
        int idx = (i >> 8)*360 + (i & 255);
        s4[idx] = u4[idx];
      }
      unsigned long long pv = 0;
      if (wv == 0){
        const bool mine = lane < CHK;
        for (;;){ pv = mine ? aload_u64(&pbB[(size_t)(pB + lane*16) + (rr & 1)*8])
                            : ((unsigned long long)rr << 32);
                  if (__all((int)(pv >> 32) == rr)) break; __builtin_amdgcn_s_sleep(4); }
        if (lane == 0) __hip_atomic_store(&s_goB, rr, __ATOMIC_RELAXED, __HIP_MEMORY_SCOPE_WORKGROUP);
      } else {
        while (__hip_atomic_load(&s_goB, __ATOMIC_RELAXED, __HIP_MEMORY_SCOPE_WORKGROUP) < rr)
          __builtin_amdgcn_s_sleep(2);
      }
      asm volatile("" ::: "memory");
      for (int i = tid; i < NF4B; i += 1024){
        int ck = i/104, off = i - ck*104;
        int idx = ck*360 + 256 + off;
        s4[idx] = u4[idx];
      }
      if (wv == 0){
        float p = (lane < CHK) ? __uint_as_float((unsigned)pv) : 0.f;
        #pragma unroll
        for (int o2 = 1; o2 < 32; o2 <<= 1) p += __shfl_xor(p, o2);
        if (tid == 0) s_nrm = p;
      }
    }
    __syncthreads();
    const float inv_s = fin ? 1.f : 1.f/(sqrtf(s_nrm) + 1e-12f);
    float* u_ot = urb + (size_t)r*(Tt*Mn);
    float local = 0.f;
    if (m0r < r1){
      float s = 0.f;
      int i = rb0;
      for (; i < re0 && (i & 3); ++i) s += u_s[cp[i]];
      for (; i + 4 <= re0; i += 4){
        ushort4 c4 = *(const ushort4*)(cp + i);
        s += (u_s[c4.x] + u_s[c4.y]) + (u_s[c4.z] + u_s[c4.w]);
      }
      for (; i < re0; ++i) s += u_s[cp[i]];
      float uv = u_s[m0r];
      float wv2 = (float)(re0 - rb0)*uv - s;
      if (!fin){ float o = inv_s*wv2; astore_f(&u_ot[t*Mn + m0r], o); local += o*o; }
      else local += uv*wv2;
    }
    asm volatile("s_waitcnt vmcnt(0)" ::: "memory");
    __syncthreads();
    if (tid == 0) astore_i(&flagA[fS + ch*16], r);
    if (m1r < r1){
      float s = 0.f;
      int i = rb1;
      for (; i < re1 && (i & 3); ++i) s += u_s[cp[i]];
      for (; i + 4 <= re1; i += 4){
        ushort4 c4 = *(const ushort4*)(cp + i);
        s += (u_s[c4.x] + u_s[c4.y]) + (u_s[c4.z] + u_s[c4.w]);
      }
      for (; i < re1; ++i) s += u_s[cp[i]];
      float uv = u_s[m1r];
      float wv2 = (float)(re1 - rb1)*uv - s;
      if (!fin){ float o = inv_s*wv2; astore_f(&u_ot[t*Mn + m1r], o); local += o*o; }
      else local += uv*wv2;
    }
    #pragma unroll
    for (int o2 = 1; o2 < 64; o2 <<= 1) local += __shfl_xor(local, o2);
    if ((tid & 63) == 0) redw[tid >> 6] = local;
    asm volatile("s_waitcnt vmcnt(0)" ::: "memory");
    __syncthreads();
    if (tid < 64){
      float tot = (tid < 16) ? redw[tid] : 0.f;
      #pragma unroll
      for (int o2 = 1; o2 < 16; o2 <<= 1) tot += __shfl_xor(tot, o2);
      if (tid == 0){
        unsigned long long out = ((unsigned long long)r << 32)
                               | (unsigned long long)__float_as_uint(tot);
        astore_u64(&pbB[(size_t)(pB + ch*16) + (r & 1)*8], out);
      }
    }
  }
  if (ch == 0 && tid < 64){
    const bool mine = lane < CHK;
    unsigned long long pv = 0;
    for (;;){ pv = mine ? aload_u64(&pbB[(size_t)(pB + lane*16) + (NRND & 1)*8])
                        : ((unsigned long long)NRND << 32);
              if (__all((int)(pv >> 32) == NRND)) break; __builtin_amdgcn_s_sleep(4); }
    float p = mine ? __uint_as_float((unsigned)pv) : 0.f;
    #pragma unroll
    for (int o2 = 1; o2 < 32; o2 <<= 1) p += __shfl_xor(p, o2);
    if (tid == 0){
      float nn = sqrtf(s_nrm) + 1e-12f;
      float lam = p / (nn*nn);
      lamc[2*t+0] = -2.f/lam;
      lamc[2*t+1] =  2.f/lam - 1.f;
    }
  }
}

// ---------------------------------------------------------------- Chebyshev SpMM (wave per row, lane = channel, XCD-swizzled)
__global__ __launch_bounds__(256) void k_cheb(const __hip_bfloat16* __restrict__ xin,
    const __hip_bfloat16* __restrict__ xb0, __hip_bfloat16* __restrict__ outp,
    const int* __restrict__ rp, const unsigned short* __restrict__ col,
    const float* __restrict__ dinv, const float* __restrict__ lamc, float s1, float s2)
{
  const int blk = blockIdx.x;               // 90000 = 8*11250
  const int w = (blk & 7)*11250 + (blk >> 3);
  const int gw = w*4 + (threadIdx.x >> 6);
  const int lane = threadIdx.x & 63;
  int t = gw / Mn, m = gw - t*Mn;
  float coef = lamc[2*t], diag = lamc[2*t+1];
  const __hip_bfloat16* xt = xin + (size_t)t*Mn*Hh;
  const float* dv = dinv + t*Mn;
  float acc = diag * bf2f(xt[(size_t)m*Hh + lane]);
  float cdm = coef * dv[m];
  int bgn = rp[t*(Mn+1)+m], end = rp[t*(Mn+1)+m+1];
  const unsigned short* cp = col + (size_t)t*Ee;
  int i = bgn;
  for (; i < end && (i & 3); ++i){ int c = cp[i]; acc += (cdm*dv[c])*bf2f(xt[(size_t)c*Hh + lane]); }
  for (; i + 4 <= end; i += 4){
    ushort4 c4 = *(const ushort4*)(cp + i);
    float w0 = cdm*dv[c4.x], w1 = cdm*dv[c4.y], w2 = cdm*dv[c4.z], w3 = cdm*dv[c4.w];
    acc += w0*bf2f(xt[(size_t)c4.x*Hh + lane]);
    acc += w1*bf2f(xt[(size_t)c4.y*Hh + lane]);
    acc += w2*bf2f(xt[(size_t)c4.z*Hh + lane]);
    acc += w3*bf2f(xt[(size_t)c4.w*Hh + lane]);
  }
  for (; i < end; ++i){ int c = cp[i]; acc += (cdm*dv[c])*bf2f(xt[(size_t)c*Hh + lane]); }
  float o = s1*acc;
  if (s2 != 0.f) o += s2*bf2f(xb0[(size_t)gw*Hh + lane]);
  outp[(size_t)gw*Hh + lane] = f2bf(o);
}

// ---------------------------------------------------------------- fold cheb_W into conv_W
__global__ void k_ww(const float* __restrict__ chebW, const float* __restrict__ chebb,
    const float* __restrict__ convW, const float* __restrict__ convb, float* __restrict__ WW, float* __restrict__ c0)
{
  int idx = blockIdx.x*256 + threadIdx.x;
  if (idx < 3*Tt*Hh*Oo){
    int oc = idx % Oo; int j = (idx/Oo) % Hh; int t = (idx/(Oo*Hh)) % Tt; int i = idx/(Oo*Hh*Tt);
    const float* cw = chebW + ((size_t)i*Hh + j)*HC + (HC-KW);
    const float* vw = convW + ((size_t)oc*Tt + t)*KW;
    float s = 0.f;
    for (int k = 0; k < KW; ++k) s += cw[k]*vw[k];
    WW[idx] = s;
  }
  if (blockIdx.x == 0 && threadIdx.x < Oo){
    int oc = threadIdx.x;
    float s = convb[oc];
    for (int t = 0; t < Tt; ++t){
      const float* vw = convW + ((size_t)oc*Tt + t)*KW;
      for (int k = 0; k < KW; ++k) s += chebb[(HC-KW)+k]*vw[k];
    }
    c0[oc] = s;
  }
}

// ---------------------------------------------------------------- fused cheb-GEMM + temporal conv + sigmoid
__global__ __launch_bounds__(256) void k_final(const __hip_bfloat16* __restrict__ tx0,
    const __hip_bfloat16* __restrict__ tx1, const __hip_bfloat16* __restrict__ tx2,
    const float* __restrict__ WW, const float* __restrict__ c0, float* __restrict__ outp)
{
  __shared__ float xs[64][65];
  __shared__ float ww[64][12];
  const int tid = threadIdx.x;
  const int n0 = blockIdx.x*64;
  const int n = tid & 63, ob = (tid >> 6)*3;
  float acc[3] = {0.f, 0.f, 0.f};
  for (int it = 0; it < 3*Tt; ++it){
    int ii = it / Tt, t = it % Tt;
    const __hip_bfloat16* tx = (ii == 0) ? tx0 : (ii == 1) ? tx1 : tx2;
    __syncthreads();
    for (int idx = tid; idx < 64*64; idx += 256){
      int mm = idx >> 6, j = idx & 63;
      int m = n0 + mm;
      xs[mm][j] = (m < Mn) ? bf2f(tx[((size_t)t*Mn + m)*Hh + j]) : 0.f;
    }
    for (int idx = tid; idx < 64*Oo; idx += 256)
      ((float*)ww)[idx] = WW[((size_t)(ii*Tt + t)*Hh)*Oo + idx];
    __syncthreads();
    #pragma unroll 8
    for (int j = 0; j < 64; ++j){
      float x = xs[n][j];
      acc[0] += x*ww[j][ob+0];
      acc[1] += x*ww[j][ob+1];
      acc[2] += x*ww[j][ob+2];
    }
  }
  int m = n0 + n;
  if (m < Mn){
    #pragma unroll
    for (int q = 0; q < 3; ++q) outp[(size_t)m*Oo + ob + q] = sigm(acc[q] + c0[ob+q]);
  }
}

// ================================================================ host
extern "C" void kernel_launch(void* const* d_in, const int* in_sizes, int n_in,
                              void* d_out, int out_size, void* d_ws, size_t ws_size,
                              hipStream_t stream)
{
  const float* nf    = (const float*)d_in[0];
  const int*   ei    = (const int*)d_in[1];
  const float* Wih0  = (const float*)d_in[2];
  const float* Whh0  = (const float*)d_in[3];
  const float* bih0  = (const float*)d_in[4];
  const float* bhh0  = (const float*)d_in[5];
  const float* Wih1  = (const float*)d_in[6];
  const float* Whh1  = (const float*)d_in[7];
  const float* bih1  = (const float*)d_in[8];
  const float* bhh1  = (const float*)d_in[9];
  const float* lns   = (const float*)d_in[10];
  const float* lnb   = (const float*)d_in[11];
  const float* chebW = (const float*)d_in[12];
  const float* chebb = (const float*)d_in[13];
  const float* convW = (const float*)d_in[14];
  const float* convb = (const float*)d_in[15];
  float* outp = (float*)d_out;

  char* base = (char*)d_ws;
  size_t off = 0;
  auto alloc = [&](size_t bytes)->char*{ char* p = base + off; off += (bytes + 255) & ~(size_t)255; return p; };

  __hip_bfloat16* y0  = (__hip_bfloat16*)alloc((size_t)Tt*Mn*C2*2);
  __hip_bfloat16* tx1 = y0;
  __hip_bfloat16* tx2 = y0 + (size_t)Tt*Mn*Hh;
  // shared arena: pair (46.1 MB, dead after k_csr2) then urb (110.9 MB)
  char* arena = alloc((size_t)(NRND+1)*Tt*Mn*4);
  unsigned* pair = (unsigned*)arena;
  float*    urb  = (float*)arena;
  __hip_bfloat16* xbt = (__hip_bfloat16*)alloc((size_t)Tt*Mn*Hh*2);
  unsigned short* col16 = (unsigned short*)alloc((size_t)Tt*Ee*2);
  int*   rp   = (int*)alloc((size_t)Tt*(Mn+1)*4);
  int*   bcnt = (int*)alloc((size_t)Tt*NB*4);
  int*   bfill= (int*)alloc((size_t)Tt*NB*4);
  int*   rpb  = (int*)alloc((size_t)Tt*(NB+1)*4);
  float* dinv = (float*)alloc((size_t)Tt*Mn*4);
  float* lamc = (float*)alloc((size_t)2*Tt*4);
  float* WW   = (float*)alloc((size_t)3*Tt*Hh*Oo*4);
  float* c0   = (float*)alloc((size_t)Oo*4);
  __hip_bfloat16* Wbf = (__hip_bfloat16*)alloc((size_t)Gg*C2*2);
  int*   flagA = (int*)alloc((size_t)Tt*CHK*16*4);              // phase-A epoch flags, 64B apart
  unsigned long long* pbB = (unsigned long long*)alloc((size_t)Tt*CHK*16*8); // packed {epoch,partial}
  (void)ws_size; (void)in_sizes; (void)n_in; (void)out_size;

  // CSR build: bucket histogram -> bucket scan -> partition -> per-bucket counting sort (emits rp+dinv)
  k_init<<<16, 256, 0, stream>>>(bcnt, bfill, flagA, pbB);
  k_bcnt<<<Tt*BPT, 256, 0, stream>>>(ei, bcnt);
  k_bscan<<<Tt, 256, 0, stream>>>(bcnt, rpb);
  k_part2<<<Tt*BPT, 256, 0, stream>>>(ei, rpb, bfill, pair);
  k_csr2<<<Tt*NB, 256, 0, stream>>>(rpb, pair, col16, rp, dinv);

  // GRU stack (MFMA; gi intermediate eliminated -- projection fused into gru1r)
  k_wcvt<<<(Gg*C2 + 255)/256, 256, 0, stream>>>(Wih1 + (size_t)Gg*C2, Wbf);
  k_gru0<<<SEGS, 256, 0, stream>>>(nf, Wih0, Whh0, bih0, bhh0, y0);
  k_gru1r<<<SEGS, 256, 0, stream>>>(y0, Wbf, Whh1 + (size_t)Gg*Hh,
                                    bih1 + Gg, bhh1 + Gg, lns, lnb, xbt);

  // power iteration: 75 rounds + 1 Rayleigh round, fused into ONE kernel
  k_pitall<<<Tt*CHK, 1024, 0, stream>>>(rp, col16, urb, flagA, pbB, lamc);

  // Chebyshev: tx1 = Lhat(x), tx2 = 2*Lhat(tx1) - x
  k_cheb<<<(Tt*Mn)/4, 256, 0, stream>>>(xbt, xbt, tx1, rp, col16, dinv, lamc, 1.f, 0.f);
  k_cheb<<<(Tt*Mn)/4, 256, 0, stream>>>(tx1, xbt, tx2, rp, col16, dinv, lamc, 2.f, -1.f);

  // folded cheb-GEMM + conv + sigmoid
  k_ww<<<(3*Tt*Hh*Oo + 255)/256, 256, 0, stream>>>(chebW, chebb, convW, convb, WW, c0);
  k_final<<<(Mn + 63)/64, 256, 0, stream>>>(xbt, tx1, tx2, WW, c0, outp);
}